// Round 4
// baseline (767.395 us; speedup 1.0000x reference)
//
#include <hip/hip_runtime.h>
#include <hip/hip_bf16.h>
#include <stdint.h>

// ---------------- problem constants ----------------
#define B_    2
#define S_    2048
#define DIM_  2048
#define H_    16
#define QL_   1536
#define KVL_  512
#define DN_   128
#define DR_   64
#define DV_   128
#define DQK_  192
#define NKV_  576     // KVL_ + DR_
#define NKVP_ 640     // padded to multiple of 128
#define BS_   (B_*S_)
#define SCALE_ 0.07216878364870322f   // 192^-0.5

typedef __hip_bfloat16 bf16;
typedef float f32x4 __attribute__((ext_vector_type(4)));
typedef short bf16x8 __attribute__((ext_vector_type(8)));   // 8 bf16 (4 VGPRs)

// ---------------- GEMM (C = A @ B^T), 128x128, dbuf minimum-2-phase --------
// 256 threads = 4 waves (2x2), per-wave 64x64 output (acc[4][4]).
// K-loop: { stage(next tile, other buffer) -> ds_read+MFMA(cur) ->
// __syncthreads (one vmcnt/lgkm drain per tile) }. The next tile's
// global_load_lds stay in flight under the whole compute phase (T3's
// "minimum 2-phase" recipe, m230/m248v2: ~92% of full 8-phase).
#define BMT 128
#define BNT 128
#define BKT 64

__device__ __forceinline__ void gload_lds16(const void* g, void* l) {
#if __has_builtin(__builtin_amdgcn_global_load_lds)
  __builtin_amdgcn_global_load_lds(
      (const __attribute__((address_space(1))) void*)g,
      (__attribute__((address_space(3))) void*)l, 16, 0, 0);
#else
  *(uint4*)l = *(const uint4*)g;
#endif
}

// A: M x K (row-major, LDA), B: N x K (row-major, LDB) -> C: M x N (LDC)
// FLAGS: 1 = fp32 C, 8 = bf16 C scaled by SCALE_, else bf16 C;
//        2 = causal block skip (scores), 4 = causal K-limit (PV).
template <int K, int LDA, int LDB, int LDC, int FLAGS>
__global__ __launch_bounds__(256, 2) void gemm_t(
    const bf16* __restrict__ A, long saz,
    const bf16* __restrict__ Bm, long sbz,
    void* __restrict__ Cv, long scz)
{
  int z = blockIdx.z;
  A  += (long)z * saz;
  Bm += (long)z * sbz;
  long coff = (long)z * scz;

  // XCD-aware chunked swizzle (every grid here has nwg % 8 == 0)
  int gx = gridDim.x;
  int lin = blockIdx.y * gx + blockIdx.x;
  int nwg = gx * gridDim.y;
  int wg = (lin & 7) * (nwg >> 3) + (lin >> 3);
  int row0 = (wg / gx) * BMT, col0 = (wg % gx) * BNT;

  if (FLAGS & 2) { if (col0 > row0 + (BMT - 1)) return; }   // fully masked block
  int kend = K;
  if (FLAGS & 4) { int lim = row0 + BMT; if (lim < kend) kend = lim; }
  const int nt = kend >> 6;                                  // K-tiles of 64

  // LDS: per buffer [128 rows][8 x 16B chunks], chunk slot jx holds column
  // chunk j = jx ^ (row&7): staging stays lane-contiguous (wave-uniform
  // base + lane*16) and ds_read_b128 sees <=2-way conflicts (free, m136).
  __shared__ __align__(16) bf16 Asm[2][BMT * BKT];   // 2 x 16 KiB
  __shared__ __align__(16) bf16 Bsm[2][BNT * BKT];   // 2 x 16 KiB

  int tid = threadIdx.x, lane = tid & 63, wave = tid >> 6;
  int wm = (wave >> 1) * 64, wn = (wave & 1) * 64;
  int quad = lane >> 4, l16 = lane & 15;

  auto stage = [&](int buf, int k0) {
#pragma unroll
    for (int t = 0; t < 4; ++t) {
      int c = (wave * 4 + t) * 64 + lane;        // 16B chunk id 0..1023
      int m = c >> 3, jx = c & 7, j = jx ^ (m & 7);
      gload_lds16(A  + (long)((row0 + m) * LDA + k0 + j * 8), &Asm[buf][c * 8]);
      gload_lds16(Bm + (long)((col0 + m) * LDB + k0 + j * 8), &Bsm[buf][c * 8]);
    }
  };

  f32x4 acc[4][4] = {};

  // prologue: tile 0 into buf 0, full drain once
  stage(0, 0);
  __syncthreads();

  int cur = 0;
  for (int t = 0; t < nt; ++t) {
    // issue next tile's loads FIRST -- they fly under this tile's compute
    if (t + 1 < nt) stage(cur ^ 1, (t + 1) * BKT);

    const bf16* Ab = &Asm[cur][0];
    const bf16* Bb = &Bsm[cur][0];
#pragma unroll
    for (int kk = 0; kk < BKT; kk += 32) {
      int jl = (kk >> 3) + quad;
      bf16x8 af[4], bfv[4];
#pragma unroll
      for (int i = 0; i < 4; ++i) {
        int m = wm + i * 16 + l16;
        af[i]  = *(const bf16x8*)(Ab + m * 64 + ((jl ^ (m & 7)) * 8));
        int n = wn + i * 16 + l16;
        bfv[i] = *(const bf16x8*)(Bb + n * 64 + ((jl ^ (n & 7)) * 8));
      }
#pragma unroll
      for (int i = 0; i < 4; ++i)
#pragma unroll
        for (int jn = 0; jn < 4; ++jn)
          acc[i][jn] = __builtin_amdgcn_mfma_f32_16x16x32_bf16(af[i], bfv[jn], acc[i][jn], 0, 0, 0);
    }

    // one drain per tile: vmcnt(0)+lgkmcnt(0)+s_barrier (=__syncthreads).
    // Ensures next tile landed in LDS and all reads of cur are complete
    // before cur's buffer is overwritten next iteration.
    __syncthreads();
    cur ^= 1;
  }

  // epilogue: C/D layout col=lane&15, row=quad*4+reg (m89/m91 verified)
  if (FLAGS & 1) {
    float* C = (float*)Cv + coff;
#pragma unroll
    for (int i = 0; i < 4; ++i)
#pragma unroll
      for (int jn = 0; jn < 4; ++jn)
#pragma unroll
        for (int r = 0; r < 4; ++r) {
          int rr = row0 + wm + i * 16 + quad * 4 + r;
          int cc = col0 + wn + jn * 16 + l16;
          C[(long)rr * LDC + cc] = acc[i][jn][r];
        }
  } else if (FLAGS & 8) {
    bf16* C = (bf16*)Cv + coff;
#pragma unroll
    for (int i = 0; i < 4; ++i)
#pragma unroll
      for (int jn = 0; jn < 4; ++jn)
#pragma unroll
        for (int r = 0; r < 4; ++r) {
          int rr = row0 + wm + i * 16 + quad * 4 + r;
          int cc = col0 + wn + jn * 16 + l16;
          C[(long)rr * LDC + cc] = __float2bfloat16(acc[i][jn][r] * SCALE_);
        }
  } else {
    bf16* C = (bf16*)Cv + coff;
#pragma unroll
    for (int i = 0; i < 4; ++i)
#pragma unroll
      for (int jn = 0; jn < 4; ++jn)
#pragma unroll
        for (int r = 0; r < 4; ++r) {
          int rr = row0 + wm + i * 16 + quad * 4 + r;
          int cc = col0 + wn + jn * 16 + l16;
          C[(long)rr * LDC + cc] = __float2bfloat16(acc[i][jn][r]);
        }
  }
}

template <int K, int LDA, int LDB, int LDC, int FLAGS>
static inline void G(hipStream_t st, const bf16* A, long saz, const bf16* Bp, long sbz,
                     void* C, long scz, int M, int N, int Z) {
  dim3 g(N / BNT, M / BMT, Z);
  gemm_t<K, LDA, LDB, LDC, FLAGS><<<g, 256, 0, st>>>(A, saz, Bp, sbz, C, scz);
}

// ---------------- helpers ----------------
__device__ __forceinline__ float wsum(float v) {
#pragma unroll
  for (int o = 32; o > 0; o >>= 1) v += __shfl_down(v, o, 64);
  return v;
}

// fused fp32->bf16 conversion pass, vectorized
#define CVT_N0  8388608L    // x -> xb            (4096*2048)
#define CVT_N1 11534336L    // wq_a -> wqab       (+1536*2048)
#define CVT_N2 16252928L    // wq_b -> wqbb       (+3072*1536)
#define CVT_N3 18350080L    // wkv_b -> wkvbb     (+4096*512)
#define CVT_N4 22544384L    // wo -> wob          (+2048*2048)
#define CVT_N5 23855104L    // wkv_a pad -> wkvab (+640*2048, valid 1179648)
__device__ __forceinline__ void cvt8(const float* __restrict__ s, bf16* __restrict__ d) {
  float4 a = ((const float4*)s)[0], b = ((const float4*)s)[1];
  __align__(16) bf16 t[8];
  t[0] = __float2bfloat16(a.x); t[1] = __float2bfloat16(a.y);
  t[2] = __float2bfloat16(a.z); t[3] = __float2bfloat16(a.w);
  t[4] = __float2bfloat16(b.x); t[5] = __float2bfloat16(b.y);
  t[6] = __float2bfloat16(b.z); t[7] = __float2bfloat16(b.w);
  *(uint4*)d = *(const uint4*)t;
}
__global__ __launch_bounds__(256) void cvt_all(
    const float* __restrict__ x, const float* __restrict__ wq_a,
    const float* __restrict__ wq_b, const float* __restrict__ wkv_b,
    const float* __restrict__ wo, const float* __restrict__ wkv_a,
    bf16* __restrict__ xb, bf16* __restrict__ wqab, bf16* __restrict__ wqbb,
    bf16* __restrict__ wkvbb, bf16* __restrict__ wob, bf16* __restrict__ wkvab)
{
  const long ngrp = CVT_N5 / 8;
  for (long v = (long)blockIdx.x * 256 + threadIdx.x; v < ngrp; v += (long)gridDim.x * 256) {
    long i = v * 8;
    if (i < CVT_N0) {
      cvt8(x + i, xb + i);
    } else if (i < CVT_N1) {
      long j = i - CVT_N0; cvt8(wq_a + j, wqab + j);
    } else if (i < CVT_N2) {
      long j = i - CVT_N1; cvt8(wq_b + j, wqbb + j);
    } else if (i < CVT_N3) {
      long j = i - CVT_N2; cvt8(wkv_b + j, wkvbb + j);
    } else if (i < CVT_N4) {
      long j = i - CVT_N3; cvt8(wo + j, wob + j);
    } else {
      long j = i - CVT_N4;
      if (j < (long)NKV_ * DIM_) cvt8(wkv_a + j, wkvab + j);
      else { __align__(16) bf16 t[8] = {}; *(uint4*)(wkvab + j) = *(const uint4*)t; }
    }
  }
}

// in-place RMSNorm of qa rows (1536), bf16
__global__ __launch_bounds__(256) void rmsnorm_qa(bf16* __restrict__ qa, const float* __restrict__ w) {
  long row = blockIdx.x;
  bf16* pr = qa + row * QL_;
  int tid = threadIdx.x, lane = tid & 63, wave = tid >> 6;
  float v[6]; float ss = 0.f;
#pragma unroll
  for (int k = 0; k < 6; ++k) { int c = tid + k * 256; v[k] = __bfloat162float(pr[c]); ss += v[k] * v[k]; }
  ss = wsum(ss);
  __shared__ float sred[4];
  if (lane == 0) sred[wave] = ss;
  __syncthreads();
  float tot = sred[0] + sred[1] + sred[2] + sred[3];
  float scl = rsqrtf(tot / (float)QL_ + 1e-6f);
#pragma unroll
  for (int k = 0; k < 6; ++k) { int c = tid + k * 256; pr[c] = __float2bfloat16(v[k] * scl * w[c]); }
}

// kv row postproc: RMSNorm(kv_c)*w -> k_full[0:512], rope(k_pe) -> k_full[512:576]
__global__ __launch_bounds__(256) void kv_post(const float* __restrict__ kvraw, const float* __restrict__ kvw,
                                               const float* __restrict__ cosb, const float* __restrict__ sinb,
                                               bf16* __restrict__ kfull) {
  int bs = blockIdx.x;
  int s = bs & (S_ - 1);
  const float* rowp = kvraw + (long)bs * NKVP_;
  bf16* outp = kfull + (long)bs * NKV_;
  int tid = threadIdx.x, lane = tid & 63, wave = tid >> 6;
  float v0 = rowp[tid], v1 = rowp[tid + 256];
  float ss = v0 * v0 + v1 * v1;
  ss = wsum(ss);
  __shared__ float sred[4];
  if (lane == 0) sred[wave] = ss;
  __syncthreads();
  float tot = sred[0] + sred[1] + sred[2] + sred[3];
  float scl = rsqrtf(tot / (float)KVL_ + 1e-6f);
  outp[tid]       = __float2bfloat16(v0 * scl * kvw[tid]);
  outp[tid + 256] = __float2bfloat16(v1 * scl * kvw[tid + 256]);
  if (tid < 32) {
    float x0 = rowp[KVL_ + 2 * tid], x1 = rowp[KVL_ + 2 * tid + 1];
    float c = cosb[s * 32 + tid], sn = sinb[s * 32 + tid];
    outp[KVL_ + 2 * tid]     = __float2bfloat16(x0 * c - x1 * sn);
    outp[KVL_ + 2 * tid + 1] = __float2bfloat16(x0 * sn + x1 * c);
  }
}

// rope(q_pe) applied in place on qb[bs][h*192+128 .. +191], all heads/rows.
__global__ __launch_bounds__(256) void rope_q(bf16* __restrict__ qb,
                                              const float* __restrict__ cosb,
                                              const float* __restrict__ sinb) {
  int tx = threadIdx.x & 31, ty = threadIdx.x >> 5;
  long row = (long)blockIdx.x * 8 + ty;     // 0..BS_*H_-1
  long bs = row >> 4; int h = (int)(row & 15); int s = (int)(bs & (S_ - 1));
  bf16* p = qb + bs * (H_ * DQK_) + h * DQK_ + DN_;
  float x0 = __bfloat162float(p[2 * tx]), x1 = __bfloat162float(p[2 * tx + 1]);
  float c = cosb[s * 32 + tx], sn = sinb[s * 32 + tx];
  p[2 * tx]     = __float2bfloat16(x0 * c - x1 * sn);
  p[2 * tx + 1] = __float2bfloat16(x0 * sn + x1 * c);
}

// kvabs[b,h,t,128:192] = kfull[b,t,512:576] (k_pe, already roped)
__global__ __launch_bounds__(256) void kpe_fill(const bf16* __restrict__ kfull, bf16* __restrict__ kvabs) {
  const long n = (long)B_ * H_ * S_ * 64;
  for (long i = (long)blockIdx.x * 256 + threadIdx.x; i < n; i += (long)gridDim.x * 256) {
    int d = (int)(i & 63);
    long t = (i >> 6) & (S_ - 1);
    int h = (int)((i >> 17) & 15);
    int b = (int)(i >> 21);
    kvabs[(((long)(b * H_ + h) * S_) + t) * DQK_ + DN_ + d] =
        kfull[((long)b * S_ + t) * NKV_ + KVL_ + d];
  }
}

// kv_cT[b][c][s] = k_full[b][s][c]  (c < 512)
__global__ __launch_bounds__(256) void transpose_kv(const bf16* __restrict__ kfull, bf16* __restrict__ kvT) {
  __shared__ bf16 tile[32][33];
  int b = blockIdx.z;
  int s0 = blockIdx.x * 32, c0 = blockIdx.y * 32;
  int tx = threadIdx.x & 31, ty = threadIdx.x >> 5;
#pragma unroll
  for (int r = 0; r < 4; ++r) {
    int s = s0 + ty + r * 8;
    tile[ty + r * 8][tx] = kfull[((long)b * S_ + s) * NKV_ + c0 + tx];
  }
  __syncthreads();
#pragma unroll
  for (int r = 0; r < 4; ++r) {
    int c = c0 + ty + r * 8;
    kvT[(long)b * KVL_ * S_ + (long)c * S_ + s0 + tx] = tile[tx][ty + r * 8];
  }
}

// causal softmax over one row of head-z, in place on bf16 scores (already
// scaled by SCALE_ in the scores-GEMM epilogue). Block-uniform chunk skip;
// zero-pads to the 128-block causal edge wlen=(r&~127)+128 (PV stages
// k < row0+128 <= wlen).
__global__ __launch_bounds__(256) void softmax_causal(bf16* __restrict__ sc) {
  int r = blockIdx.x, z = blockIdx.y;
  int tid = threadIdx.x, lane = tid & 63, wave = tid >> 6;
  bf16* row = sc + ((long)z * S_ + r) * S_;
  int wlen = (r & ~127) + 128;
  float v[8] = {};
  float mx = -3.0e38f;
#pragma unroll
  for (int k = 0; k < 8; ++k) {
    if (k * 256 <= r) {               // block-uniform
      int t = tid + k * 256;
      v[k] = (t <= r) ? __bfloat162float(row[t]) : -3.0e38f;
      mx = fmaxf(mx, v[k]);
    }
  }
  __shared__ float smx[4];
#pragma unroll
  for (int o = 32; o > 0; o >>= 1) mx = fmaxf(mx, __shfl_down(mx, o, 64));
  if (lane == 0) smx[wave] = mx;
  __syncthreads();   // all reads of `row` complete before in-place writes
  mx = fmaxf(fmaxf(smx[0], smx[1]), fmaxf(smx[2], smx[3]));
  float s = 0.f;
#pragma unroll
  for (int k = 0; k < 8; ++k) {
    if (k * 256 <= r) {
      int t = tid + k * 256;
      v[k] = (t <= r) ? __expf(v[k] - mx) : 0.f;
      s += v[k];
    }
  }
  s = wsum(s);
  __shared__ float ssm[4];
  if (lane == 0) ssm[wave] = s;
  __syncthreads();
  float inv = 1.f / (ssm[0] + ssm[1] + ssm[2] + ssm[3]);
#pragma unroll
  for (int k = 0; k < 8; ++k) {
    int t = tid + k * 256;
    if (t < wlen) row[t] = __float2bfloat16(v[k] * inv);
  }
}

// ---------------- attention loop (HC = heads per chunk, compile-time) -------
// scores = [q_nope | roped q_pe] @ [kv_abs | k_pe]^T  (K = 192, k-side absorbed)
template <int HC>
static void attn_loop(hipStream_t stream, const bf16* qb, const bf16* kvabs,
                      const bf16* kvT, const bf16* wkvbb,
                      bf16* ovb, bf16* scores_c, bf16* ob_c) {
  const int nch = B_ * (H_ / HC);
  for (int ch = 0; ch < nch; ++ch) {
    int b = ch / (H_ / HC), hq = ch % (H_ / HC), h0 = hq * HC;

    // scores (bf16 out scaled by SCALE_, causal block skip), all HC heads in z
    G<DQK_, H_ * DQK_, DQK_, S_, 8 | 2>(stream,
        qb + (long)b * S_ * (H_ * DQK_) + (long)h0 * DQK_, DQK_,
        kvabs + (long)(b * H_ + h0) * S_ * DQK_, (long)S_ * DQK_,
        scores_c, (long)S_ * S_, S_, S_, HC);
    // softmax (in-place bf16)
    softmax_causal<<<dim3(S_, HC), 256, 0, stream>>>(scores_c);
    // PV: ob_c = P @ kv_cT^T  (causal K-limit)
    G<S_, S_, S_, HC * KVL_, 4>(stream,
        scores_c, (long)S_ * S_, kvT + (long)b * KVL_ * S_, 0,
        ob_c, KVL_, S_, KVL_, HC);
    // o @ w_v^T -> ovb rows/cols of this chunk
    G<KVL_, HC * KVL_, KVL_, H_ * DV_, 0>(stream,
        ob_c, KVL_, wkvbb + ((long)h0 * 256 + DN_) * KVL_, (long)256 * KVL_,
        ovb + (long)b * S_ * (H_ * DV_) + (long)h0 * DV_, DV_, S_, DV_, HC);
  }
}

// ---------------- host ----------------
extern "C" void kernel_launch(void* const* d_in, const int* in_sizes, int n_in,
                              void* d_out, int out_size, void* d_ws, size_t ws_size,
                              hipStream_t stream) {
  const float* x     = (const float*)d_in[0];
  const float* wq_a  = (const float*)d_in[1];
  const float* qnw   = (const float*)d_in[2];
  const float* wq_b  = (const float*)d_in[3];
  const float* wkv_a = (const float*)d_in[4];
  const float* kvnw  = (const float*)d_in[5];
  const float* wkv_b = (const float*)d_in[6];
  const float* wo    = (const float*)d_in[7];
  const float* cosb  = (const float*)d_in[8];
  const float* sinb  = (const float*)d_in[9];
  float* out = (float*)d_out;
  (void)in_sizes; (void)n_in; (void)out_size;

  int hc;
  if      (ws_size >= 256376832UL) hc = 16;
  else if (ws_size >= 172490752UL) hc = 8;
  else                             hc = 4;

  char* base = (char*)d_ws;
  long off = 0;
  auto at = [&](long bytes) { char* r = base + off; off += bytes; return r; };

  // P region (persistent across the whole call)
  bf16* qb    = (bf16*)at(25165824L);   // 4096x3072 bf16
  bf16* ovb   = (bf16*)at(16777216L);   // 4096x2048 bf16
  bf16* kfull = (bf16*)at(4718592L);    // 4096x576  bf16
  bf16* kvT   = (bf16*)at(4194304L);    // 2x512x2048 bf16
  bf16* wkvbb = (bf16*)at(4194304L);    // 4096x512  bf16
  bf16* wob   = (bf16*)at(8388608L);    // 2048x2048 bf16
  bf16* kvabs = (bf16*)at(25165824L);   // 2x16x2048x192 bf16 [kv_abs | k_pe]
  char* ov = base + off;                // overlay region

  // E overlay (early phase; all dead before the attention loop)
  bf16*  xb    = (bf16*) (ov);                 // 4096x2048 bf16
  bf16*  wqab  = (bf16*) (ov + 16777216L);     // 1536x2048 bf16
  bf16*  wqbb  = (bf16*) (ov + 23068672L);     // 3072x1536 bf16
  bf16*  qa    = (bf16*) (ov + 32505856L);     // 4096x1536 bf16
  float* kvraw = (float*)qa;                   // overlay on qa, qa dead first

  // loop overlay (attention phase)
  bf16* scores_c = (bf16*)ov;                          // hc x 2048x2048 bf16
  bf16* ob_c     = (bf16*)(ov + (long)hc * 8388608L);  // 2048 x hc x 512 bf16

  bf16* wkvab = kvT;   // wkv_a bf16 (640x2048) lives in kvT until transpose_kv

  cvt_all<<<4096, 256, 0, stream>>>(x, wq_a, wq_b, wkv_b, wo, wkv_a,
                                    xb, wqab, wqbb, wkvbb, wob, wkvab);

  // q path: qa = x@wq_a^T -> rmsnorm -> qb = qa@wq_b^T -> rope q_pe in place
  G<DIM_, DIM_, DIM_, QL_, 0>(stream, xb, 0, wqab, 0, qa, 0, BS_, QL_, 1);
  rmsnorm_qa<<<BS_, 256, 0, stream>>>(qa, qnw);
  G<QL_, QL_, QL_, H_ * DQK_, 0>(stream, qa, 0, wqbb, 0, qb, 0, BS_, H_ * DQK_, 1);
  rope_q<<<BS_ * H_ / 8, 256, 0, stream>>>(qb, cosb, sinb);

  // kv path: kvraw = x@wkv_a^T (padded, fp32) -> norm+rope -> kfull, kvT
  G<DIM_, DIM_, DIM_, NKVP_, 1>(stream, xb, 0, wkvab, 0, kvraw, 0, BS_, NKVP_, 1);
  kv_post<<<BS_, 256, 0, stream>>>(kvraw, kvnw, cosb, sinb, kfull);
  transpose_kv<<<dim3(S_ / 32, KVL_ / 32, B_), 256, 0, stream>>>(kfull, kvT);

  // k-side absorption: kvabs[b,h,t,0:128] = kv_c[b,t,:] @ w_nope[h]^T
  for (int b = 0; b < B_; ++b)
    G<KVL_, NKV_, KVL_, DQK_, 0>(stream,
        kfull + (long)b * S_ * NKV_, 0, wkvbb, (long)256 * KVL_,
        kvabs + (long)b * H_ * S_ * DQK_, (long)S_ * DQK_, S_, DN_, H_);
  // kvabs[b,h,t,128:192] = k_pe (roped, shared across heads)
  kpe_fill<<<8192, 256, 0, stream>>>(kfull, kvabs);

  // attention chunks
  if (hc == 16)
    attn_loop<16>(stream, qb, kvabs, kvT, wkvbb, ovb, scores_c, ob_c);
  else if (hc == 8)
    attn_loop<8>(stream, qb, kvabs, kvT, wkvbb, ovb, scores_c, ob_c);
  else
    attn_loop<4>(stream, qb, kvabs, kvT, wkvbb, ovb, scores_c, ob_c);

  // final projection: out = ovb @ wo^T (fp32 out)
  G<H_ * DV_, H_ * DV_, H_ * DV_, DIM_, 1>(stream, ovb, 0, wob, 0, out, 0, BS_, DIM_, 1);
}

// Round 5
// 696.994 us; speedup vs baseline: 1.1010x; 1.1010x over previous
//
#include <hip/hip_runtime.h>
#include <hip/hip_bf16.h>
#include <stdint.h>

// ---------------- problem constants ----------------
#define B_    2
#define S_    2048
#define DIM_  2048
#define H_    16
#define QL_   1536
#define KVL_  512
#define DN_   128
#define DR_   64
#define DV_   128
#define DQK_  192
#define NKV_  576     // KVL_ + DR_
#define NKVP_ 640     // padded to multiple of 128
#define BS_   (B_*S_)
#define SCALE_ 0.07216878364870322f   // 192^-0.5

typedef __hip_bfloat16 bf16;
typedef float f32x4 __attribute__((ext_vector_type(4)));
typedef short bf16x8 __attribute__((ext_vector_type(8)));   // 8 bf16 (4 VGPRs)

// ---------------- GEMM (C = A @ B^T), 128x128, 8-wave + dbuf ---------------
// 512 threads = 8 waves (2Mx4N), per-wave 64x32 output (acc[4][2]).
// R1 (8 waves, sync-stage-sync)   = 66 us/big-dispatch, occ 29%  [best]
// R4 (4 waves, dbuf stage-early)  = 77 us, occ 10%  [TLP loss dominated]
// This: R1 layout + dbuf stage-early only. K-loop:
//   { stage(next tile -> other buffer) -> ds_read+MFMA(cur) -> one sync }.
// Staging loads fly under the compute phase; one barrier/tile instead of 2.
// LDS 64 KiB -> 2 blocks/CU -> 16 waves/CU (4/SIMD).
#define BMT 128
#define BNT 128
#define BKT 64

__device__ __forceinline__ void gload_lds16(const void* g, void* l) {
#if __has_builtin(__builtin_amdgcn_global_load_lds)
  __builtin_amdgcn_global_load_lds(
      (const __attribute__((address_space(1))) void*)g,
      (__attribute__((address_space(3))) void*)l, 16, 0, 0);
#else
  *(uint4*)l = *(const uint4*)g;
#endif
}

// A: M x K (row-major, LDA), B: N x K (row-major, LDB) -> C: M x N (LDC)
// FLAGS: 1 = fp32 C, 8 = bf16 C scaled by SCALE_, else bf16 C;
//        2 = causal block skip (scores), 4 = causal K-limit (PV).
// __launch_bounds__(512,4): 4 waves/EU = 2 blocks/CU; caps VGPR at 128
// (est ~90) so the LDS-permitted 2 blocks/CU is not lost to registers.
template <int K, int LDA, int LDB, int LDC, int FLAGS>
__global__ __launch_bounds__(512, 4) void gemm_t(
    const bf16* __restrict__ A, long saz,
    const bf16* __restrict__ Bm, long sbz,
    void* __restrict__ Cv, long scz)
{
  int z = blockIdx.z;
  A  += (long)z * saz;
  Bm += (long)z * sbz;
  long coff = (long)z * scz;

  // XCD-aware chunked swizzle (every grid here has nwg % 8 == 0)
  int gx = gridDim.x;
  int lin = blockIdx.y * gx + blockIdx.x;
  int nwg = gx * gridDim.y;
  int wg = (lin & 7) * (nwg >> 3) + (lin >> 3);
  int row0 = (wg / gx) * BMT, col0 = (wg % gx) * BNT;

  if (FLAGS & 2) { if (col0 > row0 + (BMT - 1)) return; }   // fully masked block
  int kend = K;
  if (FLAGS & 4) { int lim = row0 + BMT; if (lim < kend) kend = lim; }
  const int nt = kend >> 6;                                  // K-tiles of 64

  // LDS: per buffer [128 rows][8 x 16B chunks], chunk slot jx holds column
  // chunk j = jx ^ (row&7): staging stays lane-contiguous (wave-uniform
  // base + lane*16) and ds_read_b128 sees <=2-way conflicts (free, m136).
  __shared__ __align__(16) bf16 Asm[2][BMT * BKT];   // 2 x 16 KiB
  __shared__ __align__(16) bf16 Bsm[2][BNT * BKT];   // 2 x 16 KiB

  int tid = threadIdx.x, lane = tid & 63, wave = tid >> 6;
  int wm = (wave >> 2) * 64, wn = (wave & 3) * 32;
  int quad = lane >> 4, l16 = lane & 15;

  auto stage = [&](int buf, int k0) {
#pragma unroll
    for (int t = 0; t < 2; ++t) {
      int c = (wave * 2 + t) * 64 + lane;        // 16B chunk id 0..1023
      int m = c >> 3, jx = c & 7, j = jx ^ (m & 7);
      gload_lds16(A  + (long)((row0 + m) * LDA + k0 + j * 8), &Asm[buf][c * 8]);
      gload_lds16(Bm + (long)((col0 + m) * LDB + k0 + j * 8), &Bsm[buf][c * 8]);
    }
  };

  f32x4 acc[4][2] = {};

  // prologue: tile 0 into buf 0, drain once
  stage(0, 0);
  __syncthreads();

  int cur = 0;
  for (int t = 0; t < nt; ++t) {
    // issue next tile's loads FIRST -- they fly under this tile's compute
    if (t + 1 < nt) stage(cur ^ 1, (t + 1) * BKT);

    const bf16* Ab = &Asm[cur][0];
    const bf16* Bb = &Bsm[cur][0];
#pragma unroll
    for (int kk = 0; kk < BKT; kk += 32) {
      int jl = (kk >> 3) + quad;
      bf16x8 af[4], bfv[2];
#pragma unroll
      for (int i = 0; i < 4; ++i) {
        int m = wm + i * 16 + l16;
        af[i]  = *(const bf16x8*)(Ab + m * 64 + ((jl ^ (m & 7)) * 8));
      }
#pragma unroll
      for (int jn = 0; jn < 2; ++jn) {
        int n = wn + jn * 16 + l16;
        bfv[jn] = *(const bf16x8*)(Bb + n * 64 + ((jl ^ (n & 7)) * 8));
      }
#pragma unroll
      for (int i = 0; i < 4; ++i)
#pragma unroll
        for (int jn = 0; jn < 2; ++jn)
          acc[i][jn] = __builtin_amdgcn_mfma_f32_16x16x32_bf16(af[i], bfv[jn], acc[i][jn], 0, 0, 0);
    }

    // one drain per tile: vmcnt(0)+lgkmcnt(0)+s_barrier (=__syncthreads).
    // Ensures next tile landed in LDS and all reads of cur are complete
    // before cur's buffer is overwritten next iteration.
    __syncthreads();
    cur ^= 1;
  }

  // epilogue: C/D layout col=lane&15, row=quad*4+reg (m89/m91 verified)
  if (FLAGS & 1) {
    float* C = (float*)Cv + coff;
#pragma unroll
    for (int i = 0; i < 4; ++i)
#pragma unroll
      for (int jn = 0; jn < 2; ++jn)
#pragma unroll
        for (int r = 0; r < 4; ++r) {
          int rr = row0 + wm + i * 16 + quad * 4 + r;
          int cc = col0 + wn + jn * 16 + l16;
          C[(long)rr * LDC + cc] = acc[i][jn][r];
        }
  } else if (FLAGS & 8) {
    bf16* C = (bf16*)Cv + coff;
#pragma unroll
    for (int i = 0; i < 4; ++i)
#pragma unroll
      for (int jn = 0; jn < 2; ++jn)
#pragma unroll
        for (int r = 0; r < 4; ++r) {
          int rr = row0 + wm + i * 16 + quad * 4 + r;
          int cc = col0 + wn + jn * 16 + l16;
          C[(long)rr * LDC + cc] = __float2bfloat16(acc[i][jn][r] * SCALE_);
        }
  } else {
    bf16* C = (bf16*)Cv + coff;
#pragma unroll
    for (int i = 0; i < 4; ++i)
#pragma unroll
      for (int jn = 0; jn < 2; ++jn)
#pragma unroll
        for (int r = 0; r < 4; ++r) {
          int rr = row0 + wm + i * 16 + quad * 4 + r;
          int cc = col0 + wn + jn * 16 + l16;
          C[(long)rr * LDC + cc] = __float2bfloat16(acc[i][jn][r]);
        }
  }
}

template <int K, int LDA, int LDB, int LDC, int FLAGS>
static inline void G(hipStream_t st, const bf16* A, long saz, const bf16* Bp, long sbz,
                     void* C, long scz, int M, int N, int Z) {
  dim3 g(N / BNT, M / BMT, Z);
  gemm_t<K, LDA, LDB, LDC, FLAGS><<<g, 512, 0, st>>>(A, saz, Bp, sbz, C, scz);
}

// ---------------- helpers ----------------
__device__ __forceinline__ float wsum(float v) {
#pragma unroll
  for (int o = 32; o > 0; o >>= 1) v += __shfl_down(v, o, 64);
  return v;
}

// fused fp32->bf16 conversion pass, vectorized
#define CVT_N0  8388608L    // x -> xb            (4096*2048)
#define CVT_N1 11534336L    // wq_a -> wqab       (+1536*2048)
#define CVT_N2 16252928L    // wq_b -> wqbb       (+3072*1536)
#define CVT_N3 18350080L    // wkv_b -> wkvbb     (+4096*512)
#define CVT_N4 22544384L    // wo -> wob          (+2048*2048)
#define CVT_N5 23855104L    // wkv_a pad -> wkvab (+640*2048, valid 1179648)
__device__ __forceinline__ void cvt8(const float* __restrict__ s, bf16* __restrict__ d) {
  float4 a = ((const float4*)s)[0], b = ((const float4*)s)[1];
  __align__(16) bf16 t[8];
  t[0] = __float2bfloat16(a.x); t[1] = __float2bfloat16(a.y);
  t[2] = __float2bfloat16(a.z); t[3] = __float2bfloat16(a.w);
  t[4] = __float2bfloat16(b.x); t[5] = __float2bfloat16(b.y);
  t[6] = __float2bfloat16(b.z); t[7] = __float2bfloat16(b.w);
  *(uint4*)d = *(const uint4*)t;
}
__global__ __launch_bounds__(256) void cvt_all(
    const float* __restrict__ x, const float* __restrict__ wq_a,
    const float* __restrict__ wq_b, const float* __restrict__ wkv_b,
    const float* __restrict__ wo, const float* __restrict__ wkv_a,
    bf16* __restrict__ xb, bf16* __restrict__ wqab, bf16* __restrict__ wqbb,
    bf16* __restrict__ wkvbb, bf16* __restrict__ wob, bf16* __restrict__ wkvab)
{
  const long ngrp = CVT_N5 / 8;
  for (long v = (long)blockIdx.x * 256 + threadIdx.x; v < ngrp; v += (long)gridDim.x * 256) {
    long i = v * 8;
    if (i < CVT_N0) {
      cvt8(x + i, xb + i);
    } else if (i < CVT_N1) {
      long j = i - CVT_N0; cvt8(wq_a + j, wqab + j);
    } else if (i < CVT_N2) {
      long j = i - CVT_N1; cvt8(wq_b + j, wqbb + j);
    } else if (i < CVT_N3) {
      long j = i - CVT_N2; cvt8(wkv_b + j, wkvbb + j);
    } else if (i < CVT_N4) {
      long j = i - CVT_N3; cvt8(wo + j, wob + j);
    } else {
      long j = i - CVT_N4;
      if (j < (long)NKV_ * DIM_) cvt8(wkv_a + j, wkvab + j);
      else { __align__(16) bf16 t[8] = {}; *(uint4*)(wkvab + j) = *(const uint4*)t; }
    }
  }
}

// in-place RMSNorm of qa rows (1536), bf16
__global__ __launch_bounds__(256) void rmsnorm_qa(bf16* __restrict__ qa, const float* __restrict__ w) {
  long row = blockIdx.x;
  bf16* pr = qa + row * QL_;
  int tid = threadIdx.x, lane = tid & 63, wave = tid >> 6;
  float v[6]; float ss = 0.f;
#pragma unroll
  for (int k = 0; k < 6; ++k) { int c = tid + k * 256; v[k] = __bfloat162float(pr[c]); ss += v[k] * v[k]; }
  ss = wsum(ss);
  __shared__ float sred[4];
  if (lane == 0) sred[wave] = ss;
  __syncthreads();
  float tot = sred[0] + sred[1] + sred[2] + sred[3];
  float scl = rsqrtf(tot / (float)QL_ + 1e-6f);
#pragma unroll
  for (int k = 0; k < 6; ++k) { int c = tid + k * 256; pr[c] = __float2bfloat16(v[k] * scl * w[c]); }
}

// kv row postproc: RMSNorm(kv_c)*w -> k_full[0:512], rope(k_pe) -> k_full[512:576]
__global__ __launch_bounds__(256) void kv_post(const float* __restrict__ kvraw, const float* __restrict__ kvw,
                                               const float* __restrict__ cosb, const float* __restrict__ sinb,
                                               bf16* __restrict__ kfull) {
  int bs = blockIdx.x;
  int s = bs & (S_ - 1);
  const float* rowp = kvraw + (long)bs * NKVP_;
  bf16* outp = kfull + (long)bs * NKV_;
  int tid = threadIdx.x, lane = tid & 63, wave = tid >> 6;
  float v0 = rowp[tid], v1 = rowp[tid + 256];
  float ss = v0 * v0 + v1 * v1;
  ss = wsum(ss);
  __shared__ float sred[4];
  if (lane == 0) sred[wave] = ss;
  __syncthreads();
  float tot = sred[0] + sred[1] + sred[2] + sred[3];
  float scl = rsqrtf(tot / (float)KVL_ + 1e-6f);
  outp[tid]       = __float2bfloat16(v0 * scl * kvw[tid]);
  outp[tid + 256] = __float2bfloat16(v1 * scl * kvw[tid + 256]);
  if (tid < 32) {
    float x0 = rowp[KVL_ + 2 * tid], x1 = rowp[KVL_ + 2 * tid + 1];
    float c = cosb[s * 32 + tid], sn = sinb[s * 32 + tid];
    outp[KVL_ + 2 * tid]     = __float2bfloat16(x0 * c - x1 * sn);
    outp[KVL_ + 2 * tid + 1] = __float2bfloat16(x0 * sn + x1 * c);
  }
}

// rope(q_pe) applied in place on qb[bs][h*192+128 .. +191], all heads/rows.
__global__ __launch_bounds__(256) void rope_q(bf16* __restrict__ qb,
                                              const float* __restrict__ cosb,
                                              const float* __restrict__ sinb) {
  int tx = threadIdx.x & 31, ty = threadIdx.x >> 5;
  long row = (long)blockIdx.x * 8 + ty;     // 0..BS_*H_-1
  long bs = row >> 4; int h = (int)(row & 15); int s = (int)(bs & (S_ - 1));
  bf16* p = qb + bs * (H_ * DQK_) + h * DQK_ + DN_;
  float x0 = __bfloat162float(p[2 * tx]), x1 = __bfloat162float(p[2 * tx + 1]);
  float c = cosb[s * 32 + tx], sn = sinb[s * 32 + tx];
  p[2 * tx]     = __float2bfloat16(x0 * c - x1 * sn);
  p[2 * tx + 1] = __float2bfloat16(x0 * sn + x1 * c);
}

// kvabs[b,h,t,128:192] = kfull[b,t,512:576] (k_pe, already roped)
__global__ __launch_bounds__(256) void kpe_fill(const bf16* __restrict__ kfull, bf16* __restrict__ kvabs) {
  const long n = (long)B_ * H_ * S_ * 64;
  for (long i = (long)blockIdx.x * 256 + threadIdx.x; i < n; i += (long)gridDim.x * 256) {
    int d = (int)(i & 63);
    long t = (i >> 6) & (S_ - 1);
    int h = (int)((i >> 17) & 15);
    int b = (int)(i >> 21);
    kvabs[(((long)(b * H_ + h) * S_) + t) * DQK_ + DN_ + d] =
        kfull[((long)b * S_ + t) * NKV_ + KVL_ + d];
  }
}

// kv_cT[b][c][s] = k_full[b][s][c]  (c < 512)
__global__ __launch_bounds__(256) void transpose_kv(const bf16* __restrict__ kfull, bf16* __restrict__ kvT) {
  __shared__ bf16 tile[32][33];
  int b = blockIdx.z;
  int s0 = blockIdx.x * 32, c0 = blockIdx.y * 32;
  int tx = threadIdx.x & 31, ty = threadIdx.x >> 5;
#pragma unroll
  for (int r = 0; r < 4; ++r) {
    int s = s0 + ty + r * 8;
    tile[ty + r * 8][tx] = kfull[((long)b * S_ + s) * NKV_ + c0 + tx];
  }
  __syncthreads();
#pragma unroll
  for (int r = 0; r < 4; ++r) {
    int c = c0 + ty + r * 8;
    kvT[(long)b * KVL_ * S_ + (long)c * S_ + s0 + tx] = tile[tx][ty + r * 8];
  }
}

// causal softmax over one row of head-z, in place on bf16 scores (already
// scaled by SCALE_ in the scores-GEMM epilogue). Block-uniform chunk skip;
// zero-pads to the 128-block causal edge wlen=(r&~127)+128 (PV stages
// k < row0+128 <= wlen).
__global__ __launch_bounds__(256) void softmax_causal(bf16* __restrict__ sc) {
  int r = blockIdx.x, z = blockIdx.y;
  int tid = threadIdx.x, lane = tid & 63, wave = tid >> 6;
  bf16* row = sc + ((long)z * S_ + r) * S_;
  int wlen = (r & ~127) + 128;
  float v[8] = {};
  float mx = -3.0e38f;
#pragma unroll
  for (int k = 0; k < 8; ++k) {
    if (k * 256 <= r) {               // block-uniform
      int t = tid + k * 256;
      v[k] = (t <= r) ? __bfloat162float(row[t]) : -3.0e38f;
      mx = fmaxf(mx, v[k]);
    }
  }
  __shared__ float smx[4];
#pragma unroll
  for (int o = 32; o > 0; o >>= 1) mx = fmaxf(mx, __shfl_down(mx, o, 64));
  if (lane == 0) smx[wave] = mx;
  __syncthreads();   // all reads of `row` complete before in-place writes
  mx = fmaxf(fmaxf(smx[0], smx[1]), fmaxf(smx[2], smx[3]));
  float s = 0.f;
#pragma unroll
  for (int k = 0; k < 8; ++k) {
    if (k * 256 <= r) {
      int t = tid + k * 256;
      v[k] = (t <= r) ? __expf(v[k] - mx) : 0.f;
      s += v[k];
    }
  }
  s = wsum(s);
  __shared__ float ssm[4];
  if (lane == 0) ssm[wave] = s;
  __syncthreads();
  float inv = 1.f / (ssm[0] + ssm[1] + ssm[2] + ssm[3]);
#pragma unroll
  for (int k = 0; k < 8; ++k) {
    int t = tid + k * 256;
    if (t < wlen) row[t] = __float2bfloat16(v[k] * inv);
  }
}

// ---------------- attention loop (HC = heads per chunk, compile-time) -------
// scores = [q_nope | roped q_pe] @ [kv_abs | k_pe]^T  (K = 192, k-side absorbed)
template <int HC>
static void attn_loop(hipStream_t stream, const bf16* qb, const bf16* kvabs,
                      const bf16* kvT, const bf16* wkvbb,
                      bf16* ovb, bf16* scores_c, bf16* ob_c) {
  const int nch = B_ * (H_ / HC);
  for (int ch = 0; ch < nch; ++ch) {
    int b = ch / (H_ / HC), hq = ch % (H_ / HC), h0 = hq * HC;

    // scores (bf16 out scaled by SCALE_, causal block skip), all HC heads in z
    G<DQK_, H_ * DQK_, DQK_, S_, 8 | 2>(stream,
        qb + (long)b * S_ * (H_ * DQK_) + (long)h0 * DQK_, DQK_,
        kvabs + (long)(b * H_ + h0) * S_ * DQK_, (long)S_ * DQK_,
        scores_c, (long)S_ * S_, S_, S_, HC);
    // softmax (in-place bf16)
    softmax_causal<<<dim3(S_, HC), 256, 0, stream>>>(scores_c);
    // PV: ob_c = P @ kv_cT^T  (causal K-limit)
    G<S_, S_, S_, HC * KVL_, 4>(stream,
        scores_c, (long)S_ * S_, kvT + (long)b * KVL_ * S_, 0,
        ob_c, KVL_, S_, KVL_, HC);
    // o @ w_v^T -> ovb rows/cols of this chunk
    G<KVL_, HC * KVL_, KVL_, H_ * DV_, 0>(stream,
        ob_c, KVL_, wkvbb + ((long)h0 * 256 + DN_) * KVL_, (long)256 * KVL_,
        ovb + (long)b * S_ * (H_ * DV_) + (long)h0 * DV_, DV_, S_, DV_, HC);
  }
}

// ---------------- host ----------------
extern "C" void kernel_launch(void* const* d_in, const int* in_sizes, int n_in,
                              void* d_out, int out_size, void* d_ws, size_t ws_size,
                              hipStream_t stream) {
  const float* x     = (const float*)d_in[0];
  const float* wq_a  = (const float*)d_in[1];
  const float* qnw   = (const float*)d_in[2];
  const float* wq_b  = (const float*)d_in[3];
  const float* wkv_a = (const float*)d_in[4];
  const float* kvnw  = (const float*)d_in[5];
  const float* wkv_b = (const float*)d_in[6];
  const float* wo    = (const float*)d_in[7];
  const float* cosb  = (const float*)d_in[8];
  const float* sinb  = (const float*)d_in[9];
  float* out = (float*)d_out;
  (void)in_sizes; (void)n_in; (void)out_size;

  int hc;
  if      (ws_size >= 256376832UL) hc = 16;
  else if (ws_size >= 172490752UL) hc = 8;
  else                             hc = 4;

  char* base = (char*)d_ws;
  long off = 0;
  auto at = [&](long bytes) { char* r = base + off; off += bytes; return r; };

  // P region (persistent across the whole call)
  bf16* qb    = (bf16*)at(25165824L);   // 4096x3072 bf16
  bf16* ovb   = (bf16*)at(16777216L);   // 4096x2048 bf16
  bf16* kfull = (bf16*)at(4718592L);    // 4096x576  bf16
  bf16* kvT   = (bf16*)at(4194304L);    // 2x512x2048 bf16
  bf16* wkvbb = (bf16*)at(4194304L);    // 4096x512  bf16
  bf16* wob   = (bf16*)at(8388608L);    // 2048x2048 bf16
  bf16* kvabs = (bf16*)at(25165824L);   // 2x16x2048x192 bf16 [kv_abs | k_pe]
  char* ov = base + off;                // overlay region

  // E overlay (early phase; all dead before the attention loop)
  bf16*  xb    = (bf16*) (ov);                 // 4096x2048 bf16
  bf16*  wqab  = (bf16*) (ov + 16777216L);     // 1536x2048 bf16
  bf16*  wqbb  = (bf16*) (ov + 23068672L);     // 3072x1536 bf16
  bf16*  qa    = (bf16*) (ov + 32505856L);     // 4096x1536 bf16
  float* kvraw = (float*)qa;                   // overlay on qa, qa dead first

  // loop overlay (attention phase)
  bf16* scores_c = (bf16*)ov;                          // hc x 2048x2048 bf16
  bf16* ob_c     = (bf16*)(ov + (long)hc * 8388608L);  // 2048 x hc x 512 bf16

  bf16* wkvab = kvT;   // wkv_a bf16 (640x2048) lives in kvT until transpose_kv

  cvt_all<<<4096, 256, 0, stream>>>(x, wq_a, wq_b, wkv_b, wo, wkv_a,
                                    xb, wqab, wqbb, wkvbb, wob, wkvab);

  // q path: qa = x@wq_a^T -> rmsnorm -> qb = qa@wq_b^T -> rope q_pe in place
  G<DIM_, DIM_, DIM_, QL_, 0>(stream, xb, 0, wqab, 0, qa, 0, BS_, QL_, 1);
  rmsnorm_qa<<<BS_, 256, 0, stream>>>(qa, qnw);
  G<QL_, QL_, QL_, H_ * DQK_, 0>(stream, qa, 0, wqbb, 0, qb, 0, BS_, H_ * DQK_, 1);
  rope_q<<<BS_ * H_ / 8, 256, 0, stream>>>(qb, cosb, sinb);

  // kv path: kvraw = x@wkv_a^T (padded, fp32) -> norm+rope -> kfull, kvT
  G<DIM_, DIM_, DIM_, NKVP_, 1>(stream, xb, 0, wkvab, 0, kvraw, 0, BS_, NKVP_, 1);
  kv_post<<<BS_, 256, 0, stream>>>(kvraw, kvnw, cosb, sinb, kfull);
  transpose_kv<<<dim3(S_ / 32, KVL_ / 32, B_), 256, 0, stream>>>(kfull, kvT);

  // k-side absorption: kvabs[b,h,t,0:128] = kv_c[b,t,:] @ w_nope[h]^T
  for (int b = 0; b < B_; ++b)
    G<KVL_, NKV_, KVL_, DQK_, 0>(stream,
        kfull + (long)b * S_ * NKV_, 0, wkvbb, (long)256 * KVL_,
        kvabs + (long)b * H_ * S_ * DQK_, (long)S_ * DQK_, S_, DN_, H_);
  // kvabs[b,h,t,128:192] = k_pe (roped, shared across heads)
  kpe_fill<<<8192, 256, 0, stream>>>(kfull, kvabs);

  // attention chunks
  if (hc == 16)
    attn_loop<16>(stream, qb, kvabs, kvT, wkvbb, ovb, scores_c, ob_c);
  else if (hc == 8)
    attn_loop<8>(stream, qb, kvabs, kvT, wkvbb, ovb, scores_c, ob_c);
  else
    attn_loop<4>(stream, qb, kvabs, kvT, wkvbb, ovb, scores_c, ob_c);

  // final projection: out = ovb @ wo^T (fp32 out)
  G<H_ * DV_, H_ * DV_, H_ * DV_, DIM_, 1>(stream, ovb, 0, wob, 0, out, 0, BS_, DIM_, 1);
}

// Round 6
// 619.485 us; speedup vs baseline: 1.2388x; 1.1251x over previous
//
#include <hip/hip_runtime.h>
#include <hip/hip_bf16.h>
#include <stdint.h>

// ---------------- problem constants ----------------
#define B_    2
#define S_    2048
#define DIM_  2048
#define H_    16
#define QL_   1536
#define KVL_  512
#define DN_   128
#define DR_   64
#define DV_   128
#define DQK_  192
#define NKV_  576     // KVL_ + DR_
#define NKVP_ 640     // padded to multiple of 128
#define BS_   (B_*S_)
#define SCALE_ 0.07216878364870322f   // 192^-0.5

typedef __hip_bfloat16 bf16;
typedef float f32x4 __attribute__((ext_vector_type(4)));
typedef short bf16x8 __attribute__((ext_vector_type(8)));   // 8 bf16 (4 VGPRs)

// ---------------- GEMM (C = A @ B^T), r1 structure (measured best) ---------
// 512 threads = 8 waves (2Mx4N), per-wave 64x32 (acc[4][2]), 32 KiB LDS,
// sync-stage-sync 2-barrier K-loop. R3(8-phase)/R4(4w dbuf)/R5(8w dbuf)
// all regressed vs this; do not re-pipeline without ablation evidence.
#define BMT 128
#define BNT 128
#define BKT 64

__device__ __forceinline__ void gload_lds16(const void* g, void* l) {
#if __has_builtin(__builtin_amdgcn_global_load_lds)
  __builtin_amdgcn_global_load_lds(
      (const __attribute__((address_space(1))) void*)g,
      (__attribute__((address_space(3))) void*)l, 16, 0, 0);
#else
  *(uint4*)l = *(const uint4*)g;
#endif
}

// A: M x K (row-major, LDA), B: N x K (row-major, LDB) -> C: M x N (LDC)
// FLAGS: 1 = fp32 C, 8 = bf16 C scaled by SCALE_, else bf16 C;
//        2 = causal block skip (scores), 4 = causal K-limit (PV),
//        16 = row-pair balancing: grid.y is halved; block processes
//             row-tiles ry and (2*gridDim.y-1-ry) sequentially. With
//             causal K-limit (4|16) the pair's work is uniform across
//             blocks, fixing the same-tile-per-CU imbalance (a CU's 4
//             resident blocks are the same (x,y) in 4 z-planes, so
//             without pairing the row-15 CUs run ~1.9x the average).
template <int K, int LDA, int LDB, int LDC, int FLAGS>
__global__ __launch_bounds__(512, 4) void gemm_t(
    const bf16* __restrict__ A, long saz,
    const bf16* __restrict__ Bm, long sbz,
    void* __restrict__ Cv, long scz)
{
  int z = blockIdx.z;
  A  += (long)z * saz;
  Bm += (long)z * sbz;
  long coff = (long)z * scz;

  // XCD-aware chunked swizzle (every grid here has nwg % 8 == 0)
  int gx = gridDim.x;
  int lin = blockIdx.y * gx + blockIdx.x;
  int nwg = gx * gridDim.y;
  int wg = (lin & 7) * (nwg >> 3) + (lin >> 3);
  int ry = wg / gx, col0 = (wg % gx) * BNT;

  int tid = threadIdx.x, lane = tid & 63, wave = tid >> 6;
  int wm = (wave >> 2) * 64, wn = (wave & 3) * 32;
  int quad = lane >> 4, l16 = lane & 15;

  __shared__ __align__(16) bf16 Asm[BMT * BKT];
  __shared__ __align__(16) bf16 Bsm[BNT * BKT];

  const int npass = (FLAGS & 16) ? 2 : 1;
  const int nty = gridDim.y * ((FLAGS & 16) ? 2 : 1);

  for (int p = 0; p < npass; ++p) {
    int rt = (p == 0) ? ry : (nty - 1 - ry);
    int row0 = rt * BMT;

    if (FLAGS & 2) { if (col0 > row0 + (BMT - 1)) continue; }  // fully masked
    int kend = K;
    if (FLAGS & 4) { int lim = row0 + BMT; if (lim < kend) kend = lim; }

    f32x4 acc[4][2] = {};

    for (int k0 = 0; k0 < kend; k0 += BKT) {
      __syncthreads();
#pragma unroll
      for (int t = 0; t < 2; ++t) {
        int c = (wave * 2 + t) * 64 + lane;      // 16B chunk id 0..1023
        int m = c >> 3, jx = c & 7, j = jx ^ (m & 7);
        gload_lds16(A  + (long)((row0 + m) * LDA + k0 + j * 8), Asm + c * 8);
        gload_lds16(Bm + (long)((col0 + m) * LDB + k0 + j * 8), Bsm + c * 8);
      }
      __syncthreads();
#pragma unroll
      for (int kk = 0; kk < BKT; kk += 32) {
        int jl = (kk >> 3) + quad;
        bf16x8 af[4], bfv[2];
#pragma unroll
        for (int i = 0; i < 4; ++i) {
          int m = wm + i * 16 + l16;
          af[i]  = *(const bf16x8*)(Asm + m * 64 + ((jl ^ (m & 7)) * 8));
        }
#pragma unroll
        for (int jn = 0; jn < 2; ++jn) {
          int n = wn + jn * 16 + l16;
          bfv[jn] = *(const bf16x8*)(Bsm + n * 64 + ((jl ^ (n & 7)) * 8));
        }
#pragma unroll
        for (int i = 0; i < 4; ++i)
#pragma unroll
          for (int jn = 0; jn < 2; ++jn)
            acc[i][jn] = __builtin_amdgcn_mfma_f32_16x16x32_bf16(af[i], bfv[jn], acc[i][jn], 0, 0, 0);
      }
    }
    // NOTE: pass 2's first __syncthreads protects LDS reuse (all reads of
    // this pass complete before pass 2's staging overwrites Asm/Bsm).

    // epilogue: C/D layout col=lane&15, row=quad*4+reg (m89/m91 verified)
    if (FLAGS & 1) {
      float* C = (float*)Cv + coff;
#pragma unroll
      for (int i = 0; i < 4; ++i)
#pragma unroll
        for (int jn = 0; jn < 2; ++jn)
#pragma unroll
          for (int r = 0; r < 4; ++r) {
            int rr = row0 + wm + i * 16 + quad * 4 + r;
            int cc = col0 + wn + jn * 16 + l16;
            C[(long)rr * LDC + cc] = acc[i][jn][r];
          }
    } else if (FLAGS & 8) {
      bf16* C = (bf16*)Cv + coff;
#pragma unroll
      for (int i = 0; i < 4; ++i)
#pragma unroll
        for (int jn = 0; jn < 2; ++jn)
#pragma unroll
          for (int r = 0; r < 4; ++r) {
            int rr = row0 + wm + i * 16 + quad * 4 + r;
            int cc = col0 + wn + jn * 16 + l16;
            C[(long)rr * LDC + cc] = __float2bfloat16(acc[i][jn][r] * SCALE_);
          }
    } else {
      bf16* C = (bf16*)Cv + coff;
#pragma unroll
      for (int i = 0; i < 4; ++i)
#pragma unroll
        for (int jn = 0; jn < 2; ++jn)
#pragma unroll
          for (int r = 0; r < 4; ++r) {
            int rr = row0 + wm + i * 16 + quad * 4 + r;
            int cc = col0 + wn + jn * 16 + l16;
            C[(long)rr * LDC + cc] = __float2bfloat16(acc[i][jn][r]);
          }
    }
  }
}

template <int K, int LDA, int LDB, int LDC, int FLAGS>
static inline void G(hipStream_t st, const bf16* A, long saz, const bf16* Bp, long sbz,
                     void* C, long scz, int M, int N, int Z) {
  int gy = M / BMT;
  if (FLAGS & 16) gy >>= 1;           // row-pair balancing: half the y-grid
  dim3 g(N / BNT, gy, Z);
  gemm_t<K, LDA, LDB, LDC, FLAGS><<<g, 512, 0, st>>>(A, saz, Bp, sbz, C, scz);
}

// ---------------- helpers ----------------
__device__ __forceinline__ float wsum(float v) {
#pragma unroll
  for (int o = 32; o > 0; o >>= 1) v += __shfl_down(v, o, 64);
  return v;
}

// fused fp32->bf16 conversion pass, vectorized
#define CVT_N0  8388608L    // x -> xb            (4096*2048)
#define CVT_N1 11534336L    // wq_a -> wqab       (+1536*2048)
#define CVT_N2 16252928L    // wq_b -> wqbb       (+3072*1536)
#define CVT_N3 18350080L    // wkv_b -> wkvbb     (+4096*512)
#define CVT_N4 22544384L    // wo -> wob          (+2048*2048)
#define CVT_N5 23855104L    // wkv_a pad -> wkvab (+640*2048, valid 1179648)
__device__ __forceinline__ void cvt8(const float* __restrict__ s, bf16* __restrict__ d) {
  float4 a = ((const float4*)s)[0], b = ((const float4*)s)[1];
  __align__(16) bf16 t[8];
  t[0] = __float2bfloat16(a.x); t[1] = __float2bfloat16(a.y);
  t[2] = __float2bfloat16(a.z); t[3] = __float2bfloat16(a.w);
  t[4] = __float2bfloat16(b.x); t[5] = __float2bfloat16(b.y);
  t[6] = __float2bfloat16(b.z); t[7] = __float2bfloat16(b.w);
  *(uint4*)d = *(const uint4*)t;
}
__global__ __launch_bounds__(256) void cvt_all(
    const float* __restrict__ x, const float* __restrict__ wq_a,
    const float* __restrict__ wq_b, const float* __restrict__ wkv_b,
    const float* __restrict__ wo, const float* __restrict__ wkv_a,
    bf16* __restrict__ xb, bf16* __restrict__ wqab, bf16* __restrict__ wqbb,
    bf16* __restrict__ wkvbb, bf16* __restrict__ wob, bf16* __restrict__ wkvab)
{
  const long ngrp = CVT_N5 / 8;
  for (long v = (long)blockIdx.x * 256 + threadIdx.x; v < ngrp; v += (long)gridDim.x * 256) {
    long i = v * 8;
    if (i < CVT_N0) {
      cvt8(x + i, xb + i);
    } else if (i < CVT_N1) {
      long j = i - CVT_N0; cvt8(wq_a + j, wqab + j);
    } else if (i < CVT_N2) {
      long j = i - CVT_N1; cvt8(wq_b + j, wqbb + j);
    } else if (i < CVT_N3) {
      long j = i - CVT_N2; cvt8(wkv_b + j, wkvbb + j);
    } else if (i < CVT_N4) {
      long j = i - CVT_N3; cvt8(wo + j, wob + j);
    } else {
      long j = i - CVT_N4;
      if (j < (long)NKV_ * DIM_) cvt8(wkv_a + j, wkvab + j);
      else { __align__(16) bf16 t[8] = {}; *(uint4*)(wkvab + j) = *(const uint4*)t; }
    }
  }
}

// in-place RMSNorm of qa rows (1536), bf16
__global__ __launch_bounds__(256) void rmsnorm_qa(bf16* __restrict__ qa, const float* __restrict__ w) {
  long row = blockIdx.x;
  bf16* pr = qa + row * QL_;
  int tid = threadIdx.x, lane = tid & 63, wave = tid >> 6;
  float v[6]; float ss = 0.f;
#pragma unroll
  for (int k = 0; k < 6; ++k) { int c = tid + k * 256; v[k] = __bfloat162float(pr[c]); ss += v[k] * v[k]; }
  ss = wsum(ss);
  __shared__ float sred[4];
  if (lane == 0) sred[wave] = ss;
  __syncthreads();
  float tot = sred[0] + sred[1] + sred[2] + sred[3];
  float scl = rsqrtf(tot / (float)QL_ + 1e-6f);
#pragma unroll
  for (int k = 0; k < 6; ++k) { int c = tid + k * 256; pr[c] = __float2bfloat16(v[k] * scl * w[c]); }
}

// kv row postproc: RMSNorm(kv_c)*w -> k_full[0:512], rope(k_pe) -> k_full[512:576]
__global__ __launch_bounds__(256) void kv_post(const float* __restrict__ kvraw, const float* __restrict__ kvw,
                                               const float* __restrict__ cosb, const float* __restrict__ sinb,
                                               bf16* __restrict__ kfull) {
  int bs = blockIdx.x;
  int s = bs & (S_ - 1);
  const float* rowp = kvraw + (long)bs * NKVP_;
  bf16* outp = kfull + (long)bs * NKV_;
  int tid = threadIdx.x, lane = tid & 63, wave = tid >> 6;
  float v0 = rowp[tid], v1 = rowp[tid + 256];
  float ss = v0 * v0 + v1 * v1;
  ss = wsum(ss);
  __shared__ float sred[4];
  if (lane == 0) sred[wave] = ss;
  __syncthreads();
  float tot = sred[0] + sred[1] + sred[2] + sred[3];
  float scl = rsqrtf(tot / (float)KVL_ + 1e-6f);
  outp[tid]       = __float2bfloat16(v0 * scl * kvw[tid]);
  outp[tid + 256] = __float2bfloat16(v1 * scl * kvw[tid + 256]);
  if (tid < 32) {
    float x0 = rowp[KVL_ + 2 * tid], x1 = rowp[KVL_ + 2 * tid + 1];
    float c = cosb[s * 32 + tid], sn = sinb[s * 32 + tid];
    outp[KVL_ + 2 * tid]     = __float2bfloat16(x0 * c - x1 * sn);
    outp[KVL_ + 2 * tid + 1] = __float2bfloat16(x0 * sn + x1 * c);
  }
}

// rope(q_pe) applied in place on qb[bs][h*192+128 .. +191], all heads/rows.
__global__ __launch_bounds__(256) void rope_q(bf16* __restrict__ qb,
                                              const float* __restrict__ cosb,
                                              const float* __restrict__ sinb) {
  int tx = threadIdx.x & 31, ty = threadIdx.x >> 5;
  long row = (long)blockIdx.x * 8 + ty;     // 0..BS_*H_-1
  long bs = row >> 4; int h = (int)(row & 15); int s = (int)(bs & (S_ - 1));
  bf16* p = qb + bs * (H_ * DQK_) + h * DQK_ + DN_;
  float x0 = __bfloat162float(p[2 * tx]), x1 = __bfloat162float(p[2 * tx + 1]);
  float c = cosb[s * 32 + tx], sn = sinb[s * 32 + tx];
  p[2 * tx]     = __float2bfloat16(x0 * c - x1 * sn);
  p[2 * tx + 1] = __float2bfloat16(x0 * sn + x1 * c);
}

// kvabs[b,h,t,128:192] = kfull[b,t,512:576] (k_pe, already roped)
__global__ __launch_bounds__(256) void kpe_fill(const bf16* __restrict__ kfull, bf16* __restrict__ kvabs) {
  const long n = (long)B_ * H_ * S_ * 64;
  for (long i = (long)blockIdx.x * 256 + threadIdx.x; i < n; i += (long)gridDim.x * 256) {
    int d = (int)(i & 63);
    long t = (i >> 6) & (S_ - 1);
    int h = (int)((i >> 17) & 15);
    int b = (int)(i >> 21);
    kvabs[(((long)(b * H_ + h) * S_) + t) * DQK_ + DN_ + d] =
        kfull[((long)b * S_ + t) * NKV_ + KVL_ + d];
  }
}

// kv_cT[b][c][s] = k_full[b][s][c]  (c < 512)
__global__ __launch_bounds__(256) void transpose_kv(const bf16* __restrict__ kfull, bf16* __restrict__ kvT) {
  __shared__ bf16 tile[32][33];
  int b = blockIdx.z;
  int s0 = blockIdx.x * 32, c0 = blockIdx.y * 32;
  int tx = threadIdx.x & 31, ty = threadIdx.x >> 5;
#pragma unroll
  for (int r = 0; r < 4; ++r) {
    int s = s0 + ty + r * 8;
    tile[ty + r * 8][tx] = kfull[((long)b * S_ + s) * NKV_ + c0 + tx];
  }
  __syncthreads();
#pragma unroll
  for (int r = 0; r < 4; ++r) {
    int c = c0 + ty + r * 8;
    kvT[(long)b * KVL_ * S_ + (long)c * S_ + s0 + tx] = tile[tx][ty + r * 8];
  }
}

// causal softmax over one row of head-z, in place on bf16 scores (already
// scaled by SCALE_ in the scores-GEMM epilogue). Block-uniform chunk skip;
// zero-pads to the 128-block causal edge wlen=(r&~127)+128 (PV stages
// k < row0+128 <= wlen).
__global__ __launch_bounds__(256) void softmax_causal(bf16* __restrict__ sc) {
  int r = blockIdx.x, z = blockIdx.y;
  int tid = threadIdx.x, lane = tid & 63, wave = tid >> 6;
  bf16* row = sc + ((long)z * S_ + r) * S_;
  int wlen = (r & ~127) + 128;
  float v[8] = {};
  float mx = -3.0e38f;
#pragma unroll
  for (int k = 0; k < 8; ++k) {
    if (k * 256 <= r) {               // block-uniform
      int t = tid + k * 256;
      v[k] = (t <= r) ? __bfloat162float(row[t]) : -3.0e38f;
      mx = fmaxf(mx, v[k]);
    }
  }
  __shared__ float smx[4];
#pragma unroll
  for (int o = 32; o > 0; o >>= 1) mx = fmaxf(mx, __shfl_down(mx, o, 64));
  if (lane == 0) smx[wave] = mx;
  __syncthreads();   // all reads of `row` complete before in-place writes
  mx = fmaxf(fmaxf(smx[0], smx[1]), fmaxf(smx[2], smx[3]));
  float s = 0.f;
#pragma unroll
  for (int k = 0; k < 8; ++k) {
    if (k * 256 <= r) {
      int t = tid + k * 256;
      v[k] = (t <= r) ? __expf(v[k] - mx) : 0.f;
      s += v[k];
    }
  }
  s = wsum(s);
  __shared__ float ssm[4];
  if (lane == 0) ssm[wave] = s;
  __syncthreads();
  float inv = 1.f / (ssm[0] + ssm[1] + ssm[2] + ssm[3]);
#pragma unroll
  for (int k = 0; k < 8; ++k) {
    int t = tid + k * 256;
    if (t < wlen) row[t] = __float2bfloat16(v[k] * inv);
  }
}

// ---------------- attention loop (HC = heads per chunk, compile-time) -------
// scores = [q_nope | roped q_pe] @ [kv_abs | k_pe]^T  (K = 192, k-side absorbed)
template <int HC>
static void attn_loop(hipStream_t stream, const bf16* qb, const bf16* kvabs,
                      const bf16* kvT, const bf16* wkvbb,
                      bf16* ovb, bf16* scores_c, bf16* ob_c) {
  const int nch = B_ * (H_ / HC);
  for (int ch = 0; ch < nch; ++ch) {
    int b = ch / (H_ / HC), hq = ch % (H_ / HC), h0 = hq * HC;

    // scores (bf16 out scaled by SCALE_, causal block skip), all HC heads in z
    G<DQK_, H_ * DQK_, DQK_, S_, 8 | 2>(stream,
        qb + (long)b * S_ * (H_ * DQK_) + (long)h0 * DQK_, DQK_,
        kvabs + (long)(b * H_ + h0) * S_ * DQK_, (long)S_ * DQK_,
        scores_c, (long)S_ * S_, S_, S_, HC);
    // softmax (in-place bf16)
    softmax_causal<<<dim3(S_, HC), 256, 0, stream>>>(scores_c);
    // PV: ob_c = P @ kv_cT^T  (causal K-limit + row-pair balancing)
    G<S_, S_, S_, HC * KVL_, 4 | 16>(stream,
        scores_c, (long)S_ * S_, kvT + (long)b * KVL_ * S_, 0,
        ob_c, KVL_, S_, KVL_, HC);
    // o @ w_v^T -> ovb rows/cols of this chunk
    G<KVL_, HC * KVL_, KVL_, H_ * DV_, 0>(stream,
        ob_c, KVL_, wkvbb + ((long)h0 * 256 + DN_) * KVL_, (long)256 * KVL_,
        ovb + (long)b * S_ * (H_ * DV_) + (long)h0 * DV_, DV_, S_, DV_, HC);
  }
}

// ---------------- host ----------------
extern "C" void kernel_launch(void* const* d_in, const int* in_sizes, int n_in,
                              void* d_out, int out_size, void* d_ws, size_t ws_size,
                              hipStream_t stream) {
  const float* x     = (const float*)d_in[0];
  const float* wq_a  = (const float*)d_in[1];
  const float* qnw   = (const float*)d_in[2];
  const float* wq_b  = (const float*)d_in[3];
  const float* wkv_a = (const float*)d_in[4];
  const float* kvnw  = (const float*)d_in[5];
  const float* wkv_b = (const float*)d_in[6];
  const float* wo    = (const float*)d_in[7];
  const float* cosb  = (const float*)d_in[8];
  const float* sinb  = (const float*)d_in[9];
  float* out = (float*)d_out;
  (void)in_sizes; (void)n_in; (void)out_size;

  int hc;
  if      (ws_size >= 256376832UL) hc = 16;
  else if (ws_size >= 172490752UL) hc = 8;
  else                             hc = 4;

  char* base = (char*)d_ws;
  long off = 0;
  auto at = [&](long bytes) { char* r = base + off; off += bytes; return r; };

  // P region (persistent across the whole call)
  bf16* qb    = (bf16*)at(25165824L);   // 4096x3072 bf16
  bf16* ovb   = (bf16*)at(16777216L);   // 4096x2048 bf16
  bf16* kfull = (bf16*)at(4718592L);    // 4096x576  bf16
  bf16* kvT   = (bf16*)at(4194304L);    // 2x512x2048 bf16
  bf16* wkvbb = (bf16*)at(4194304L);    // 4096x512  bf16
  bf16* wob   = (bf16*)at(8388608L);    // 2048x2048 bf16
  bf16* kvabs = (bf16*)at(25165824L);   // 2x16x2048x192 bf16 [kv_abs | k_pe]
  char* ov = base + off;                // overlay region

  // E overlay (early phase; all dead before the attention loop)
  bf16*  xb    = (bf16*) (ov);                 // 4096x2048 bf16
  bf16*  wqab  = (bf16*) (ov + 16777216L);     // 1536x2048 bf16
  bf16*  wqbb  = (bf16*) (ov + 23068672L);     // 3072x1536 bf16
  bf16*  qa    = (bf16*) (ov + 32505856L);     // 4096x1536 bf16
  float* kvraw = (float*)qa;                   // overlay on qa, qa dead first

  // loop overlay (attention phase)
  bf16* scores_c = (bf16*)ov;                          // hc x 2048x2048 bf16
  bf16* ob_c     = (bf16*)(ov + (long)hc * 8388608L);  // 2048 x hc x 512 bf16

  bf16* wkvab = kvT;   // wkv_a bf16 (640x2048) lives in kvT until transpose_kv

  cvt_all<<<4096, 256, 0, stream>>>(x, wq_a, wq_b, wkv_b, wo, wkv_a,
                                    xb, wqab, wqbb, wkvbb, wob, wkvab);

  // q path: qa = x@wq_a^T -> rmsnorm -> qb = qa@wq_b^T -> rope q_pe in place
  G<DIM_, DIM_, DIM_, QL_, 0>(stream, xb, 0, wqab, 0, qa, 0, BS_, QL_, 1);
  rmsnorm_qa<<<BS_, 256, 0, stream>>>(qa, qnw);
  G<QL_, QL_, QL_, H_ * DQK_, 0>(stream, qa, 0, wqbb, 0, qb, 0, BS_, H_ * DQK_, 1);
  rope_q<<<BS_ * H_ / 8, 256, 0, stream>>>(qb, cosb, sinb);

  // kv path: kvraw = x@wkv_a^T (padded, fp32) -> norm+rope -> kfull, kvT
  G<DIM_, DIM_, DIM_, NKVP_, 1>(stream, xb, 0, wkvab, 0, kvraw, 0, BS_, NKVP_, 1);
  kv_post<<<BS_, 256, 0, stream>>>(kvraw, kvnw, cosb, sinb, kfull);
  transpose_kv<<<dim3(S_ / 32, KVL_ / 32, B_), 256, 0, stream>>>(kfull, kvT);

  // k-side absorption: kvabs[b,h,t,0:128] = kv_c[b,t,:] @ w_nope[h]^T
  for (int b = 0; b < B_; ++b)
    G<KVL_, NKV_, KVL_, DQK_, 0>(stream,
        kfull + (long)b * S_ * NKV_, 0, wkvbb, (long)256 * KVL_,
        kvabs + (long)b * H_ * S_ * DQK_, (long)S_ * DQK_, S_, DN_, H_);
  // kvabs[b,h,t,128:192] = k_pe (roped, shared across heads)
  kpe_fill<<<8192, 256, 0, stream>>>(kfull, kvabs);

  // attention chunks
  if (hc == 16)
    attn_loop<16>(stream, qb, kvabs, kvT, wkvbb, ovb, scores_c, ob_c);
  else if (hc == 8)
    attn_loop<8>(stream, qb, kvabs, kvT, wkvbb, ovb, scores_c, ob_c);
  else
    attn_loop<4>(stream, qb, kvabs, kvT, wkvbb, ovb, scores_c, ob_c);

  // final projection: out = ovb @ wo^T (fp32 out)
  G<H_ * DV_, H_ * DV_, H_ * DV_, DIM_, 1>(stream, ovb, 0, wob, 0, out, 0, BS_, DIM_, 1);
}

// Round 7
// 588.879 us; speedup vs baseline: 1.3031x; 1.0520x over previous
//
#include <hip/hip_runtime.h>
#include <hip/hip_bf16.h>
#include <stdint.h>

// ---------------- problem constants ----------------
#define B_    2
#define S_    2048
#define DIM_  2048
#define H_    16
#define QL_   1536
#define KVL_  512
#define DN_   128
#define DR_   64
#define DV_   128
#define DQK_  192
#define NKV_  576     // KVL_ + DR_
#define NKVP_ 640     // padded to multiple of 128
#define BS_   (B_*S_)
#define SCALE_ 0.07216878364870322f   // 192^-0.5

typedef __hip_bfloat16 bf16;
typedef float f32x4 __attribute__((ext_vector_type(4)));
typedef short bf16x8 __attribute__((ext_vector_type(8)));   // 8 bf16 (4 VGPRs)

// ---------------- GEMM (C = A @ B^T), r1 structure (measured best) ---------
// 512 threads = 8 waves (2Mx4N), per-wave 64x32 (acc[4][2]), 32 KiB LDS,
// sync-stage-sync 2-barrier K-loop. R3(8-phase)/R4(4w dbuf)/R5(8w dbuf)
// all regressed vs this; do not re-pipeline without ablation evidence.
#define BMT 128
#define BNT 128
#define BKT 64

__device__ __forceinline__ void gload_lds16(const void* g, void* l) {
#if __has_builtin(__builtin_amdgcn_global_load_lds)
  __builtin_amdgcn_global_load_lds(
      (const __attribute__((address_space(1))) void*)g,
      (__attribute__((address_space(3))) void*)l, 16, 0, 0);
#else
  *(uint4*)l = *(const uint4*)g;
#endif
}

// A: M x K (row-major, LDA), B: N x K (row-major, LDB) -> C: M x N (LDC)
// FLAGS: 1 = fp32 C, 8 = bf16 C scaled by SCALE_, else bf16 C;
//        2 = causal block skip (scores), 4 = causal K-limit (PV),
//        16 = row-pair balancing: grid.y halved; block processes row-tiles
//             ry and (2*gridDim.y-1-ry) sequentially (uniform causal work
//             per block; fixed the same-tile-per-CU imbalance, R6: -54us).
template <int K, int LDA, int LDB, int LDC, int FLAGS>
__global__ __launch_bounds__(512, 4) void gemm_t(
    const bf16* __restrict__ A, long saz,
    const bf16* __restrict__ Bm, long sbz,
    void* __restrict__ Cv, long scz)
{
  int z = blockIdx.z;
  A  += (long)z * saz;
  Bm += (long)z * sbz;
  long coff = (long)z * scz;

  // XCD-aware chunked swizzle (every grid here has nwg % 8 == 0)
  int gx = gridDim.x;
  int lin = blockIdx.y * gx + blockIdx.x;
  int nwg = gx * gridDim.y;
  int wg = (lin & 7) * (nwg >> 3) + (lin >> 3);
  int ry = wg / gx, col0 = (wg % gx) * BNT;

  int tid = threadIdx.x, lane = tid & 63, wave = tid >> 6;
  int wm = (wave >> 2) * 64, wn = (wave & 3) * 32;
  int quad = lane >> 4, l16 = lane & 15;

  __shared__ __align__(16) bf16 Asm[BMT * BKT];
  __shared__ __align__(16) bf16 Bsm[BNT * BKT];

  const int npass = (FLAGS & 16) ? 2 : 1;
  const int nty = gridDim.y * ((FLAGS & 16) ? 2 : 1);

  for (int p = 0; p < npass; ++p) {
    int rt = (p == 0) ? ry : (nty - 1 - ry);
    int row0 = rt * BMT;

    if (FLAGS & 2) { if (col0 > row0 + (BMT - 1)) continue; }  // fully masked
    int kend = K;
    if (FLAGS & 4) { int lim = row0 + BMT; if (lim < kend) kend = lim; }

    f32x4 acc[4][2] = {};

    for (int k0 = 0; k0 < kend; k0 += BKT) {
      __syncthreads();
#pragma unroll
      for (int t = 0; t < 2; ++t) {
        int c = (wave * 2 + t) * 64 + lane;      // 16B chunk id 0..1023
        int m = c >> 3, jx = c & 7, j = jx ^ (m & 7);
        gload_lds16(A  + (long)((row0 + m) * LDA + k0 + j * 8), Asm + c * 8);
        gload_lds16(Bm + (long)((col0 + m) * LDB + k0 + j * 8), Bsm + c * 8);
      }
      __syncthreads();
#pragma unroll
      for (int kk = 0; kk < BKT; kk += 32) {
        int jl = (kk >> 3) + quad;
        bf16x8 af[4], bfv[2];
#pragma unroll
        for (int i = 0; i < 4; ++i) {
          int m = wm + i * 16 + l16;
          af[i]  = *(const bf16x8*)(Asm + m * 64 + ((jl ^ (m & 7)) * 8));
        }
#pragma unroll
        for (int jn = 0; jn < 2; ++jn) {
          int n = wn + jn * 16 + l16;
          bfv[jn] = *(const bf16x8*)(Bsm + n * 64 + ((jl ^ (n & 7)) * 8));
        }
#pragma unroll
        for (int i = 0; i < 4; ++i)
#pragma unroll
          for (int jn = 0; jn < 2; ++jn)
            acc[i][jn] = __builtin_amdgcn_mfma_f32_16x16x32_bf16(af[i], bfv[jn], acc[i][jn], 0, 0, 0);
      }
    }
    // pass 2's first __syncthreads protects LDS reuse across passes.

    // epilogue: C/D layout col=lane&15, row=quad*4+reg (m89/m91 verified)
    if (FLAGS & 1) {
      float* C = (float*)Cv + coff;
#pragma unroll
      for (int i = 0; i < 4; ++i)
#pragma unroll
        for (int jn = 0; jn < 2; ++jn)
#pragma unroll
          for (int r = 0; r < 4; ++r) {
            int rr = row0 + wm + i * 16 + quad * 4 + r;
            int cc = col0 + wn + jn * 16 + l16;
            C[(long)rr * LDC + cc] = acc[i][jn][r];
          }
    } else if (FLAGS & 8) {
      bf16* C = (bf16*)Cv + coff;
#pragma unroll
      for (int i = 0; i < 4; ++i)
#pragma unroll
        for (int jn = 0; jn < 2; ++jn)
#pragma unroll
          for (int r = 0; r < 4; ++r) {
            int rr = row0 + wm + i * 16 + quad * 4 + r;
            int cc = col0 + wn + jn * 16 + l16;
            C[(long)rr * LDC + cc] = __float2bfloat16(acc[i][jn][r] * SCALE_);
          }
    } else {
      bf16* C = (bf16*)Cv + coff;
#pragma unroll
      for (int i = 0; i < 4; ++i)
#pragma unroll
        for (int jn = 0; jn < 2; ++jn)
#pragma unroll
          for (int r = 0; r < 4; ++r) {
            int rr = row0 + wm + i * 16 + quad * 4 + r;
            int cc = col0 + wn + jn * 16 + l16;
            C[(long)rr * LDC + cc] = __float2bfloat16(acc[i][jn][r]);
          }
    }
  }
}

template <int K, int LDA, int LDB, int LDC, int FLAGS>
static inline void G(hipStream_t st, const bf16* A, long saz, const bf16* Bp, long sbz,
                     void* C, long scz, int M, int N, int Z) {
  int gy = M / BMT;
  if (FLAGS & 16) gy >>= 1;           // row-pair balancing: half the y-grid
  dim3 g(N / BNT, gy, Z);
  gemm_t<K, LDA, LDB, LDC, FLAGS><<<g, 512, 0, st>>>(A, saz, Bp, sbz, C, scz);
}

// ---------------- helpers ----------------
__device__ __forceinline__ float wsum(float v) {
#pragma unroll
  for (int o = 32; o > 0; o >>= 1) v += __shfl_down(v, o, 64);
  return v;
}

// fused fp32->bf16 conversion pass, vectorized
#define CVT_N0  8388608L    // x -> xb            (4096*2048)
#define CVT_N1 11534336L    // wq_a -> wqab       (+1536*2048)
#define CVT_N2 16252928L    // wq_b -> wqbb       (+3072*1536)
#define CVT_N3 18350080L    // wkv_b -> wkvbb     (+4096*512)
#define CVT_N4 22544384L    // wo -> wob          (+2048*2048)
#define CVT_N5 23855104L    // wkv_a pad -> wkvab (+640*2048, valid 1179648)
__device__ __forceinline__ void cvt8(const float* __restrict__ s, bf16* __restrict__ d) {
  float4 a = ((const float4*)s)[0], b = ((const float4*)s)[1];
  __align__(16) bf16 t[8];
  t[0] = __float2bfloat16(a.x); t[1] = __float2bfloat16(a.y);
  t[2] = __float2bfloat16(a.z); t[3] = __float2bfloat16(a.w);
  t[4] = __float2bfloat16(b.x); t[5] = __float2bfloat16(b.y);
  t[6] = __float2bfloat16(b.z); t[7] = __float2bfloat16(b.w);
  *(uint4*)d = *(const uint4*)t;
}
__global__ __launch_bounds__(256) void cvt_all(
    const float* __restrict__ x, const float* __restrict__ wq_a,
    const float* __restrict__ wq_b, const float* __restrict__ wkv_b,
    const float* __restrict__ wo, const float* __restrict__ wkv_a,
    bf16* __restrict__ xb, bf16* __restrict__ wqab, bf16* __restrict__ wqbb,
    bf16* __restrict__ wkvbb, bf16* __restrict__ wob, bf16* __restrict__ wkvab)
{
  const long ngrp = CVT_N5 / 8;
  for (long v = (long)blockIdx.x * 256 + threadIdx.x; v < ngrp; v += (long)gridDim.x * 256) {
    long i = v * 8;
    if (i < CVT_N0) {
      cvt8(x + i, xb + i);
    } else if (i < CVT_N1) {
      long j = i - CVT_N0; cvt8(wq_a + j, wqab + j);
    } else if (i < CVT_N2) {
      long j = i - CVT_N1; cvt8(wq_b + j, wqbb + j);
    } else if (i < CVT_N3) {
      long j = i - CVT_N2; cvt8(wkv_b + j, wkvbb + j);
    } else if (i < CVT_N4) {
      long j = i - CVT_N3; cvt8(wo + j, wob + j);
    } else {
      long j = i - CVT_N4;
      if (j < (long)NKV_ * DIM_) cvt8(wkv_a + j, wkvab + j);
      else { __align__(16) bf16 t[8] = {}; *(uint4*)(wkvab + j) = *(const uint4*)t; }
    }
  }
}

// in-place RMSNorm of qa rows (1536), bf16
__global__ __launch_bounds__(256) void rmsnorm_qa(bf16* __restrict__ qa, const float* __restrict__ w) {
  long row = blockIdx.x;
  bf16* pr = qa + row * QL_;
  int tid = threadIdx.x, lane = tid & 63, wave = tid >> 6;
  float v[6]; float ss = 0.f;
#pragma unroll
  for (int k = 0; k < 6; ++k) { int c = tid + k * 256; v[k] = __bfloat162float(pr[c]); ss += v[k] * v[k]; }
  ss = wsum(ss);
  __shared__ float sred[4];
  if (lane == 0) sred[wave] = ss;
  __syncthreads();
  float tot = sred[0] + sred[1] + sred[2] + sred[3];
  float scl = rsqrtf(tot / (float)QL_ + 1e-6f);
#pragma unroll
  for (int k = 0; k < 6; ++k) { int c = tid + k * 256; pr[c] = __float2bfloat16(v[k] * scl * w[c]); }
}

// kv row postproc: RMSNorm(kv_c)*w -> k_full[0:512], rope(k_pe) -> k_full[512:576]
__global__ __launch_bounds__(256) void kv_post(const float* __restrict__ kvraw, const float* __restrict__ kvw,
                                               const float* __restrict__ cosb, const float* __restrict__ sinb,
                                               bf16* __restrict__ kfull) {
  int bs = blockIdx.x;
  int s = bs & (S_ - 1);
  const float* rowp = kvraw + (long)bs * NKVP_;
  bf16* outp = kfull + (long)bs * NKV_;
  int tid = threadIdx.x, lane = tid & 63, wave = tid >> 6;
  float v0 = rowp[tid], v1 = rowp[tid + 256];
  float ss = v0 * v0 + v1 * v1;
  ss = wsum(ss);
  __shared__ float sred[4];
  if (lane == 0) sred[wave] = ss;
  __syncthreads();
  float tot = sred[0] + sred[1] + sred[2] + sred[3];
  float scl = rsqrtf(tot / (float)KVL_ + 1e-6f);
  outp[tid]       = __float2bfloat16(v0 * scl * kvw[tid]);
  outp[tid + 256] = __float2bfloat16(v1 * scl * kvw[tid + 256]);
  if (tid < 32) {
    float x0 = rowp[KVL_ + 2 * tid], x1 = rowp[KVL_ + 2 * tid + 1];
    float c = cosb[s * 32 + tid], sn = sinb[s * 32 + tid];
    outp[KVL_ + 2 * tid]     = __float2bfloat16(x0 * c - x1 * sn);
    outp[KVL_ + 2 * tid + 1] = __float2bfloat16(x0 * sn + x1 * c);
  }
}

// rope(q_pe) applied in place on qb[bs][h*192+128 .. +191], all heads/rows.
__global__ __launch_bounds__(256) void rope_q(bf16* __restrict__ qb,
                                              const float* __restrict__ cosb,
                                              const float* __restrict__ sinb) {
  int tx = threadIdx.x & 31, ty = threadIdx.x >> 5;
  long row = (long)blockIdx.x * 8 + ty;     // 0..BS_*H_-1
  long bs = row >> 4; int h = (int)(row & 15); int s = (int)(bs & (S_ - 1));
  bf16* p = qb + bs * (H_ * DQK_) + h * DQK_ + DN_;
  float x0 = __bfloat162float(p[2 * tx]), x1 = __bfloat162float(p[2 * tx + 1]);
  float c = cosb[s * 32 + tx], sn = sinb[s * 32 + tx];
  p[2 * tx]     = __float2bfloat16(x0 * c - x1 * sn);
  p[2 * tx + 1] = __float2bfloat16(x0 * sn + x1 * c);
}

// kvabs[b,h,t,128:192] = kfull[b,t,512:576] (k_pe, already roped)
__global__ __launch_bounds__(256) void kpe_fill(const bf16* __restrict__ kfull, bf16* __restrict__ kvabs) {
  const long n = (long)B_ * H_ * S_ * 64;
  for (long i = (long)blockIdx.x * 256 + threadIdx.x; i < n; i += (long)gridDim.x * 256) {
    int d = (int)(i & 63);
    long t = (i >> 6) & (S_ - 1);
    int h = (int)((i >> 17) & 15);
    int b = (int)(i >> 21);
    kvabs[(((long)(b * H_ + h) * S_) + t) * DQK_ + DN_ + d] =
        kfull[((long)b * S_ + t) * NKV_ + KVL_ + d];
  }
}

// kv_cT[b][c][s] = k_full[b][s][c]  (c < 512)
__global__ __launch_bounds__(256) void transpose_kv(const bf16* __restrict__ kfull, bf16* __restrict__ kvT) {
  __shared__ bf16 tile[32][33];
  int b = blockIdx.z;
  int s0 = blockIdx.x * 32, c0 = blockIdx.y * 32;
  int tx = threadIdx.x & 31, ty = threadIdx.x >> 5;
#pragma unroll
  for (int r = 0; r < 4; ++r) {
    int s = s0 + ty + r * 8;
    tile[ty + r * 8][tx] = kfull[((long)b * S_ + s) * NKV_ + c0 + tx];
  }
  __syncthreads();
#pragma unroll
  for (int r = 0; r < 4; ++r) {
    int c = c0 + ty + r * 8;
    kvT[(long)b * KVL_ * S_ + (long)c * S_ + s0 + tx] = tile[tx][ty + r * 8];
  }
}

// causal softmax, wave-per-row (R7 rewrite: old block-per-row version was
// VALU-issue-bound at 53.5us -- scalar bf16 loads, per-element masks, 2
// block barriers + LDS reduces). Here: 4 waves/block, each wave owns one
// row; bf16x8 16B loads/stores; no LDS, no __syncthreads; 6-step
// __shfl_xor butterfly reduces; per-element masking only in the single
// partial 512-chunk (wave-uniform branch keeps full chunks mask-free).
// Zero-pads to wlen=(r&~127)+128 (always inside the partial chunk since
// wlen <= chunkend), preserving the PV K-limit read contract.
__global__ __launch_bounds__(256) void softmax_causal(bf16* __restrict__ sc) {
  int wave = threadIdx.x >> 6, lane = threadIdx.x & 63;
  int r = blockIdx.x * 4 + wave, z = blockIdx.y;
  bf16* row = sc + ((long)z * S_ + r) * S_;
  int wlen = (r & ~127) + 128;
  int base0 = lane * 8;

  float v[4][8];
  float mx = -3.0e38f;
#pragma unroll
  for (int c = 0; c < 4; ++c) {
    int cb = c * 512;
    if (cb <= r) {                               // wave-uniform chunk skip
      int base = cb + base0;
      __align__(16) bf16 t8[8];
      *(bf16x8*)t8 = *(const bf16x8*)(row + base);
      if (cb + 511 <= r) {                       // full chunk: no masks
#pragma unroll
        for (int j = 0; j < 8; ++j) {
          float f = __bfloat162float(t8[j]);
          v[c][j] = f; mx = fmaxf(mx, f);
        }
      } else {                                   // partial chunk (has diag)
#pragma unroll
        for (int j = 0; j < 8; ++j) {
          float f = (base + j <= r) ? __bfloat162float(t8[j]) : -3.0e38f;
          v[c][j] = f; mx = fmaxf(mx, f);
        }
      }
    }
  }
#pragma unroll
  for (int o = 32; o > 0; o >>= 1) mx = fmaxf(mx, __shfl_xor(mx, o, 64));

  float s = 0.f;
#pragma unroll
  for (int c = 0; c < 4; ++c) {
    if (c * 512 <= r) {
#pragma unroll
      for (int j = 0; j < 8; ++j) {
        float e = __expf(v[c][j] - mx);          // masked -3e38 -> 0
        v[c][j] = e; s += e;
      }
    }
  }
#pragma unroll
  for (int o = 32; o > 0; o >>= 1) s += __shfl_xor(s, o, 64);
  float inv = 1.f / s;

#pragma unroll
  for (int c = 0; c < 4; ++c) {
    int base = c * 512 + base0;
    if (c * 512 <= r && base < wlen) {           // covers [0, wlen) exactly
      __align__(16) bf16 t8[8];
#pragma unroll
      for (int j = 0; j < 8; ++j) t8[j] = __float2bfloat16(v[c][j] * inv);
      *(bf16x8*)(row + base) = *(const bf16x8*)t8;
    }
  }
}

// ---------------- attention loop (HC = heads per chunk, compile-time) -------
// scores = [q_nope | roped q_pe] @ [kv_abs | k_pe]^T  (K = 192, k-side absorbed)
template <int HC>
static void attn_loop(hipStream_t stream, const bf16* qb, const bf16* kvabs,
                      const bf16* kvT, const bf16* wkvbb,
                      bf16* ovb, bf16* scores_c, bf16* ob_c) {
  const int nch = B_ * (H_ / HC);
  for (int ch = 0; ch < nch; ++ch) {
    int b = ch / (H_ / HC), hq = ch % (H_ / HC), h0 = hq * HC;

    // scores (bf16 out scaled by SCALE_, causal block skip), all HC heads in z
    G<DQK_, H_ * DQK_, DQK_, S_, 8 | 2>(stream,
        qb + (long)b * S_ * (H_ * DQK_) + (long)h0 * DQK_, DQK_,
        kvabs + (long)(b * H_ + h0) * S_ * DQK_, (long)S_ * DQK_,
        scores_c, (long)S_ * S_, S_, S_, HC);
    // softmax (in-place bf16, wave-per-row)
    softmax_causal<<<dim3(S_ / 4, HC), 256, 0, stream>>>(scores_c);
    // PV: ob_c = P @ kv_cT^T  (causal K-limit + row-pair balancing)
    G<S_, S_, S_, HC * KVL_, 4 | 16>(stream,
        scores_c, (long)S_ * S_, kvT + (long)b * KVL_ * S_, 0,
        ob_c, KVL_, S_, KVL_, HC);
    // o @ w_v^T -> ovb rows/cols of this chunk
    G<KVL_, HC * KVL_, KVL_, H_ * DV_, 0>(stream,
        ob_c, KVL_, wkvbb + ((long)h0 * 256 + DN_) * KVL_, (long)256 * KVL_,
        ovb + (long)b * S_ * (H_ * DV_) + (long)h0 * DV_, DV_, S_, DV_, HC);
  }
}

// ---------------- host ----------------
extern "C" void kernel_launch(void* const* d_in, const int* in_sizes, int n_in,
                              void* d_out, int out_size, void* d_ws, size_t ws_size,
                              hipStream_t stream) {
  const float* x     = (const float*)d_in[0];
  const float* wq_a  = (const float*)d_in[1];
  const float* qnw   = (const float*)d_in[2];
  const float* wq_b  = (const float*)d_in[3];
  const float* wkv_a = (const float*)d_in[4];
  const float* kvnw  = (const float*)d_in[5];
  const float* wkv_b = (const float*)d_in[6];
  const float* wo    = (const float*)d_in[7];
  const float* cosb  = (const float*)d_in[8];
  const float* sinb  = (const float*)d_in[9];
  float* out = (float*)d_out;
  (void)in_sizes; (void)n_in; (void)out_size;

  int hc;
  if      (ws_size >= 256376832UL) hc = 16;
  else if (ws_size >= 172490752UL) hc = 8;
  else                             hc = 4;

  char* base = (char*)d_ws;
  long off = 0;
  auto at = [&](long bytes) { char* r = base + off; off += bytes; return r; };

  // P region (persistent across the whole call)
  bf16* qb    = (bf16*)at(25165824L);   // 4096x3072 bf16
  bf16* ovb   = (bf16*)at(16777216L);   // 4096x2048 bf16
  bf16* kfull = (bf16*)at(4718592L);    // 4096x576  bf16
  bf16* kvT   = (bf16*)at(4194304L);    // 2x512x2048 bf16
  bf16* wkvbb = (bf16*)at(4194304L);    // 4096x512  bf16
  bf16* wob   = (bf16*)at(8388608L);    // 2048x2048 bf16
  bf16* kvabs = (bf16*)at(25165824L);   // 2x16x2048x192 bf16 [kv_abs | k_pe]
  char* ov = base + off;                // overlay region

  // E overlay (early phase; all dead before the attention loop)
  bf16*  xb    = (bf16*) (ov);                 // 4096x2048 bf16
  bf16*  wqab  = (bf16*) (ov + 16777216L);     // 1536x2048 bf16
  bf16*  wqbb  = (bf16*) (ov + 23068672L);     // 3072x1536 bf16
  bf16*  qa    = (bf16*) (ov + 32505856L);     // 4096x1536 bf16
  float* kvraw = (float*)qa;                   // overlay on qa, qa dead first

  // loop overlay (attention phase)
  bf16* scores_c = (bf16*)ov;                          // hc x 2048x2048 bf16
  bf16* ob_c     = (bf16*)(ov + (long)hc * 8388608L);  // 2048 x hc x 512 bf16

  bf16* wkvab = kvT;   // wkv_a bf16 (640x2048) lives in kvT until transpose_kv

  cvt_all<<<4096, 256, 0, stream>>>(x, wq_a, wq_b, wkv_b, wo, wkv_a,
                                    xb, wqab, wqbb, wkvbb, wob, wkvab);

  // q path: qa = x@wq_a^T -> rmsnorm -> qb = qa@wq_b^T -> rope q_pe in place
  G<DIM_, DIM_, DIM_, QL_, 0>(stream, xb, 0, wqab, 0, qa, 0, BS_, QL_, 1);
  rmsnorm_qa<<<BS_, 256, 0, stream>>>(qa, qnw);
  G<QL_, QL_, QL_, H_ * DQK_, 0>(stream, qa, 0, wqbb, 0, qb, 0, BS_, H_ * DQK_, 1);
  rope_q<<<BS_ * H_ / 8, 256, 0, stream>>>(qb, cosb, sinb);

  // kv path: kvraw = x@wkv_a^T (padded, fp32) -> norm+rope -> kfull, kvT
  G<DIM_, DIM_, DIM_, NKVP_, 1>(stream, xb, 0, wkvab, 0, kvraw, 0, BS_, NKVP_, 1);
  kv_post<<<BS_, 256, 0, stream>>>(kvraw, kvnw, cosb, sinb, kfull);
  transpose_kv<<<dim3(S_ / 32, KVL_ / 32, B_), 256, 0, stream>>>(kfull, kvT);

  // k-side absorption: kvabs[b,h,t,0:128] = kv_c[b,t,:] @ w_nope[h]^T
  for (int b = 0; b < B_; ++b)
    G<KVL_, NKV_, KVL_, DQK_, 0>(stream,
        kfull + (long)b * S_ * NKV_, 0, wkvbb, (long)256 * KVL_,
        kvabs + (long)b * H_ * S_ * DQK_, (long)S_ * DQK_, S_, DN_, H_);
  // kvabs[b,h,t,128:192] = k_pe (roped, shared across heads)
  kpe_fill<<<8192, 256, 0, stream>>>(kfull, kvabs);

  // attention chunks
  if (hc == 16)
    attn_loop<16>(stream, qb, kvabs, kvT, wkvbb, ovb, scores_c, ob_c);
  else if (hc == 8)
    attn_loop<8>(stream, qb, kvabs, kvT, wkvbb, ovb, scores_c, ob_c);
  else
    attn_loop<4>(stream, qb, kvabs, kvT, wkvbb, ovb, scores_c, ob_c);

  // final projection: out = ovb @ wo^T (fp32 out)
  G<H_ * DV_, H_ * DV_, H_ * DV_, DIM_, 1>(stream, ovb, 0, wob, 0, out, 0, BS_, DIM_, 1);
}

// Round 9
// 543.544 us; speedup vs baseline: 1.4118x; 1.0834x over previous
//
#include <hip/hip_runtime.h>
#include <hip/hip_bf16.h>
#include <stdint.h>

// ---------------- problem constants ----------------
#define B_    2
#define S_    2048
#define DIM_  2048
#define H_    16
#define QL_   1536
#define KVL_  512
#define DN_   128
#define DR_   64
#define DV_   128
#define DQK_  192
#define NKV_  576     // KVL_ + DR_
#define NKVP_ 640     // padded to multiple of 128
#define BS_   (B_*S_)
#define SCALE_ 0.07216878364870322f   // 192^-0.5

typedef __hip_bfloat16 bf16;
typedef float f32x4 __attribute__((ext_vector_type(4)));
typedef short bf16x8 __attribute__((ext_vector_type(8)));   // 8 bf16 (4 VGPRs)

// ---------------- GEMM (C = A @ B^T), r1 structure (measured best) ---------
// 512 threads = 8 waves (2Mx4N), per-wave 64x32 (acc[4][2]), 32 KiB LDS,
// sync-stage-sync 2-barrier K-loop. R3(8-phase)/R4(4w dbuf)/R5(8w dbuf)
// all regressed vs this; do not re-pipeline without ablation evidence.
#define BMT 128
#define BNT 128
#define BKT 64

__device__ __forceinline__ void gload_lds16(const void* g, void* l) {
#if __has_builtin(__builtin_amdgcn_global_load_lds)
  __builtin_amdgcn_global_load_lds(
      (const __attribute__((address_space(1))) void*)g,
      (__attribute__((address_space(3))) void*)l, 16, 0, 0);
#else
  *(uint4*)l = *(const uint4*)g;
#endif
}

// A: M x K (row-major, LDA), B: N x K (row-major, LDB) -> C: M x N (LDC)
// FLAGS: 1 = fp32 C, 8 = bf16 C scaled by SCALE_, else bf16 C;
//        2 = causal block skip (scores), 4 = causal K-limit (PV),
//        16 = row-pair balancing: grid.y halved; block processes row-tiles
//             ry and (2*gridDim.y-1-ry) sequentially (uniform causal work
//             per block; fixed the same-tile-per-CU imbalance, R6: -54us),
//        32 = B head-strided: B row n lives at Bm + ((n>>7)*256+128)*LDB
//             + (n&127)*LDB  (w_v rows of head n>>7 inside stacked wkv_b),
//        64 = transposed bf16 C write: C[cc*LDC + rr], packed as one 8B
//             short4 store per acc quad (rr..rr+3 contiguous).
template <int K, int LDA, int LDB, int LDC, int FLAGS>
__global__ __launch_bounds__(512, 4) void gemm_t(
    const bf16* __restrict__ A, long saz,
    const bf16* __restrict__ Bm, long sbz,
    void* __restrict__ Cv, long scz)
{
  int z = blockIdx.z;
  A  += (long)z * saz;
  Bm += (long)z * sbz;
  long coff = (long)z * scz;

  // XCD-aware chunked swizzle (every grid here has nwg % 8 == 0)
  int gx = gridDim.x;
  int lin = blockIdx.y * gx + blockIdx.x;
  int nwg = gx * gridDim.y;
  int wg = (lin & 7) * (nwg >> 3) + (lin >> 3);
  int ry = wg / gx, col0 = (wg % gx) * BNT;

  // B-side base row offset (FLAG 32: head-strided rows inside wkv_b)
  const long bbase = (FLAGS & 32)
      ? (((long)(col0 >> 7) * 256 + 128) * (long)LDB)
      : ((long)col0 * (long)LDB);

  int tid = threadIdx.x, lane = tid & 63, wave = tid >> 6;
  int wm = (wave >> 2) * 64, wn = (wave & 3) * 32;
  int quad = lane >> 4, l16 = lane & 15;

  __shared__ __align__(16) bf16 Asm[BMT * BKT];
  __shared__ __align__(16) bf16 Bsm[BNT * BKT];

  const int npass = (FLAGS & 16) ? 2 : 1;
  const int nty = gridDim.y * ((FLAGS & 16) ? 2 : 1);

  for (int p = 0; p < npass; ++p) {
    int rt = (p == 0) ? ry : (nty - 1 - ry);
    int row0 = rt * BMT;

    if (FLAGS & 2) { if (col0 > row0 + (BMT - 1)) continue; }  // fully masked
    int kend = K;
    if (FLAGS & 4) { int lim = row0 + BMT; if (lim < kend) kend = lim; }

    f32x4 acc[4][2] = {};

    for (int k0 = 0; k0 < kend; k0 += BKT) {
      __syncthreads();
#pragma unroll
      for (int t = 0; t < 2; ++t) {
        int c = (wave * 2 + t) * 64 + lane;      // 16B chunk id 0..1023
        int m = c >> 3, jx = c & 7, j = jx ^ (m & 7);
        gload_lds16(A  + (long)((row0 + m) * LDA + k0 + j * 8), Asm + c * 8);
        gload_lds16(Bm + bbase + (long)m * LDB + k0 + j * 8, Bsm + c * 8);
      }
      __syncthreads();
#pragma unroll
      for (int kk = 0; kk < BKT; kk += 32) {
        int jl = (kk >> 3) + quad;
        bf16x8 af[4], bfv[2];
#pragma unroll
        for (int i = 0; i < 4; ++i) {
          int m = wm + i * 16 + l16;
          af[i]  = *(const bf16x8*)(Asm + m * 64 + ((jl ^ (m & 7)) * 8));
        }
#pragma unroll
        for (int jn = 0; jn < 2; ++jn) {
          int n = wn + jn * 16 + l16;
          bfv[jn] = *(const bf16x8*)(Bsm + n * 64 + ((jl ^ (n & 7)) * 8));
        }
#pragma unroll
        for (int i = 0; i < 4; ++i)
#pragma unroll
          for (int jn = 0; jn < 2; ++jn)
            acc[i][jn] = __builtin_amdgcn_mfma_f32_16x16x32_bf16(af[i], bfv[jn], acc[i][jn], 0, 0, 0);
      }
    }
    // pass 2's first __syncthreads protects LDS reuse across passes.

    // epilogue: C/D layout col=lane&15, row=quad*4+reg (m89/m91 verified)
    if (FLAGS & 1) {
      float* C = (float*)Cv + coff;
#pragma unroll
      for (int i = 0; i < 4; ++i)
#pragma unroll
        for (int jn = 0; jn < 2; ++jn)
#pragma unroll
          for (int r = 0; r < 4; ++r) {
            int rr = row0 + wm + i * 16 + quad * 4 + r;
            int cc = col0 + wn + jn * 16 + l16;
            C[(long)rr * LDC + cc] = acc[i][jn][r];
          }
    } else if (FLAGS & 8) {
      bf16* C = (bf16*)Cv + coff;
#pragma unroll
      for (int i = 0; i < 4; ++i)
#pragma unroll
        for (int jn = 0; jn < 2; ++jn)
#pragma unroll
          for (int r = 0; r < 4; ++r) {
            int rr = row0 + wm + i * 16 + quad * 4 + r;
            int cc = col0 + wn + jn * 16 + l16;
            C[(long)rr * LDC + cc] = __float2bfloat16(acc[i][jn][r] * SCALE_);
          }
    } else if (FLAGS & 64) {
      bf16* C = (bf16*)Cv + coff;      // transposed: C^T[cc][rr..rr+3], 8B store
#pragma unroll
      for (int i = 0; i < 4; ++i)
#pragma unroll
        for (int jn = 0; jn < 2; ++jn) {
          int rr = row0 + wm + i * 16 + quad * 4;
          int cc = col0 + wn + jn * 16 + l16;
          __align__(8) bf16 t4[4];
#pragma unroll
          for (int r = 0; r < 4; ++r) t4[r] = __float2bfloat16(acc[i][jn][r]);
          *(short4*)(C + (long)cc * LDC + rr) = *(const short4*)t4;
        }
    } else {
      bf16* C = (bf16*)Cv + coff;
#pragma unroll
      for (int i = 0; i < 4; ++i)
#pragma unroll
        for (int jn = 0; jn < 2; ++jn)
#pragma unroll
          for (int r = 0; r < 4; ++r) {
            int rr = row0 + wm + i * 16 + quad * 4 + r;
            int cc = col0 + wn + jn * 16 + l16;
            C[(long)rr * LDC + cc] = __float2bfloat16(acc[i][jn][r]);
          }
    }
  }
}

template <int K, int LDA, int LDB, int LDC, int FLAGS>
static inline void G(hipStream_t st, const bf16* A, long saz, const bf16* Bp, long sbz,
                     void* C, long scz, int M, int N, int Z) {
  int gy = M / BMT;
  if (FLAGS & 16) gy >>= 1;           // row-pair balancing: half the y-grid
  dim3 g(N / BNT, gy, Z);
  gemm_t<K, LDA, LDB, LDC, FLAGS><<<g, 512, 0, st>>>(A, saz, Bp, sbz, C, scz);
}

// ---------------- helpers ----------------
__device__ __forceinline__ float wsum(float v) {
#pragma unroll
  for (int o = 32; o > 0; o >>= 1) v += __shfl_down(v, o, 64);
  return v;
}

// fused fp32->bf16 conversion pass, vectorized
#define CVT_N0  8388608L    // x -> xb            (4096*2048)
#define CVT_N1 11534336L    // wq_a -> wqab       (+1536*2048)
#define CVT_N2 16252928L    // wq_b -> wqbb       (+3072*1536)
#define CVT_N3 18350080L    // wkv_b -> wkvbb     (+4096*512)
#define CVT_N4 22544384L    // wo -> wob          (+2048*2048)
#define CVT_N5 23855104L    // wkv_a pad -> wkvab (+640*2048, valid 1179648)
__device__ __forceinline__ void cvt8(const float* __restrict__ s, bf16* __restrict__ d) {
  float4 a = ((const float4*)s)[0], b = ((const float4*)s)[1];
  __align__(16) bf16 t[8];
  t[0] = __float2bfloat16(a.x); t[1] = __float2bfloat16(a.y);
  t[2] = __float2bfloat16(a.z); t[3] = __float2bfloat16(a.w);
  t[4] = __float2bfloat16(b.x); t[5] = __float2bfloat16(b.y);
  t[6] = __float2bfloat16(b.z); t[7] = __float2bfloat16(b.w);
  *(uint4*)d = *(const uint4*)t;
}
__global__ __launch_bounds__(256) void cvt_all(
    const float* __restrict__ x, const float* __restrict__ wq_a,
    const float* __restrict__ wq_b, const float* __restrict__ wkv_b,
    const float* __restrict__ wo, const float* __restrict__ wkv_a,
    bf16* __restrict__ xb, bf16* __restrict__ wqab, bf16* __restrict__ wqbb,
    bf16* __restrict__ wkvbb, bf16* __restrict__ wob, bf16* __restrict__ wkvab)
{
  const long ngrp = CVT_N5 / 8;
  for (long v = (long)blockIdx.x * 256 + threadIdx.x; v < ngrp; v += (long)gridDim.x * 256) {
    long i = v * 8;
    if (i < CVT_N0) {
      cvt8(x + i, xb + i);
    } else if (i < CVT_N1) {
      long j = i - CVT_N0; cvt8(wq_a + j, wqab + j);
    } else if (i < CVT_N2) {
      long j = i - CVT_N1; cvt8(wq_b + j, wqbb + j);
    } else if (i < CVT_N3) {
      long j = i - CVT_N2; cvt8(wkv_b + j, wkvbb + j);
    } else if (i < CVT_N4) {
      long j = i - CVT_N3; cvt8(wo + j, wob + j);
    } else {
      long j = i - CVT_N4;
      if (j < (long)NKV_ * DIM_) cvt8(wkv_a + j, wkvab + j);
      else { __align__(16) bf16 t[8] = {}; *(uint4*)(wkvab + j) = *(const uint4*)t; }
    }
  }
}

// in-place RMSNorm of qa rows (1536), bf16
__global__ __launch_bounds__(256) void rmsnorm_qa(bf16* __restrict__ qa, const float* __restrict__ w) {
  long row = blockIdx.x;
  bf16* pr = qa + row * QL_;
  int tid = threadIdx.x, lane = tid & 63, wave = tid >> 6;
  float v[6]; float ss = 0.f;
#pragma unroll
  for (int k = 0; k < 6; ++k) { int c = tid + k * 256; v[k] = __bfloat162float(pr[c]); ss += v[k] * v[k]; }
  ss = wsum(ss);
  __shared__ float sred[4];
  if (lane == 0) sred[wave] = ss;
  __syncthreads();
  float tot = sred[0] + sred[1] + sred[2] + sred[3];
  float scl = rsqrtf(tot / (float)QL_ + 1e-6f);
#pragma unroll
  for (int k = 0; k < 6; ++k) { int c = tid + k * 256; pr[c] = __float2bfloat16(v[k] * scl * w[c]); }
}

// kv row postproc: RMSNorm(kv_c)*w -> k_full[0:512], rope(k_pe) -> k_full[512:576]
__global__ __launch_bounds__(256) void kv_post(const float* __restrict__ kvraw, const float* __restrict__ kvw,
                                               const float* __restrict__ cosb, const float* __restrict__ sinb,
                                               bf16* __restrict__ kfull) {
  int bs = blockIdx.x;
  int s = bs & (S_ - 1);
  const float* rowp = kvraw + (long)bs * NKVP_;
  bf16* outp = kfull + (long)bs * NKV_;
  int tid = threadIdx.x, lane = tid & 63, wave = tid >> 6;
  float v0 = rowp[tid], v1 = rowp[tid + 256];
  float ss = v0 * v0 + v1 * v1;
  ss = wsum(ss);
  __shared__ float sred[4];
  if (lane == 0) sred[wave] = ss;
  __syncthreads();
  float tot = sred[0] + sred[1] + sred[2] + sred[3];
  float scl = rsqrtf(tot / (float)KVL_ + 1e-6f);
  outp[tid]       = __float2bfloat16(v0 * scl * kvw[tid]);
  outp[tid + 256] = __float2bfloat16(v1 * scl * kvw[tid + 256]);
  if (tid < 32) {
    float x0 = rowp[KVL_ + 2 * tid], x1 = rowp[KVL_ + 2 * tid + 1];
    float c = cosb[s * 32 + tid], sn = sinb[s * 32 + tid];
    outp[KVL_ + 2 * tid]     = __float2bfloat16(x0 * c - x1 * sn);
    outp[KVL_ + 2 * tid + 1] = __float2bfloat16(x0 * sn + x1 * c);
  }
}

// rope(q_pe) applied in place on qb[bs][h*192+128 .. +191], all heads/rows.
__global__ __launch_bounds__(256) void rope_q(bf16* __restrict__ qb,
                                              const float* __restrict__ cosb,
                                              const float* __restrict__ sinb) {
  int tx = threadIdx.x & 31, ty = threadIdx.x >> 5;
  long row = (long)blockIdx.x * 8 + ty;     // 0..BS_*H_-1
  long bs = row >> 4; int h = (int)(row & 15); int s = (int)(bs & (S_ - 1));
  bf16* p = qb + bs * (H_ * DQK_) + h * DQK_ + DN_;
  float x0 = __bfloat162float(p[2 * tx]), x1 = __bfloat162float(p[2 * tx + 1]);
  float c = cosb[s * 32 + tx], sn = sinb[s * 32 + tx];
  p[2 * tx]     = __float2bfloat16(x0 * c - x1 * sn);
  p[2 * tx + 1] = __float2bfloat16(x0 * sn + x1 * c);
}

// kvabs[b,h,t,128:192] = kfull[b,t,512:576] (k_pe, already roped)
__global__ __launch_bounds__(256) void kpe_fill(const bf16* __restrict__ kfull, bf16* __restrict__ kvabs) {
  const long n = (long)B_ * H_ * S_ * 64;
  for (long i = (long)blockIdx.x * 256 + threadIdx.x; i < n; i += (long)gridDim.x * 256) {
    int d = (int)(i & 63);
    long t = (i >> 6) & (S_ - 1);
    int h = (int)((i >> 17) & 15);
    int b = (int)(i >> 21);
    kvabs[(((long)(b * H_ + h) * S_) + t) * DQK_ + DN_ + d] =
        kfull[((long)b * S_ + t) * NKV_ + KVL_ + d];
  }
}

// causal softmax, wave-per-row: 4 waves/block, bf16x8 16B loads/stores,
// no LDS/barriers, butterfly reduces; per-element masking only in the
// partial 512-chunk. Zero-pads to wlen=(r&~127)+128, which equals the PV
// K-limit kend=row0+128 exactly.
__global__ __launch_bounds__(256) void softmax_causal(bf16* __restrict__ sc) {
  int wave = threadIdx.x >> 6, lane = threadIdx.x & 63;
  int r = blockIdx.x * 4 + wave, z = blockIdx.y;
  bf16* row = sc + ((long)z * S_ + r) * S_;
  int wlen = (r & ~127) + 128;
  int base0 = lane * 8;

  float v[4][8];
  float mx = -3.0e38f;
#pragma unroll
  for (int c = 0; c < 4; ++c) {
    int cb = c * 512;
    if (cb <= r) {                               // wave-uniform chunk skip
      int base = cb + base0;
      __align__(16) bf16 t8[8];
      *(bf16x8*)t8 = *(const bf16x8*)(row + base);
      if (cb + 511 <= r) {                       // full chunk: no masks
#pragma unroll
        for (int j = 0; j < 8; ++j) {
          float f = __bfloat162float(t8[j]);
          v[c][j] = f; mx = fmaxf(mx, f);
        }
      } else {                                   // partial chunk (has diag)
#pragma unroll
        for (int j = 0; j < 8; ++j) {
          float f = (base + j <= r) ? __bfloat162float(t8[j]) : -3.0e38f;
          v[c][j] = f; mx = fmaxf(mx, f);
        }
      }
    }
  }
#pragma unroll
  for (int o = 32; o > 0; o >>= 1) mx = fmaxf(mx, __shfl_xor(mx, o, 64));

  float s = 0.f;
#pragma unroll
  for (int c = 0; c < 4; ++c) {
    if (c * 512 <= r) {
#pragma unroll
      for (int j = 0; j < 8; ++j) {
        float e = __expf(v[c][j] - mx);          // masked -3e38 -> 0
        v[c][j] = e; s += e;
      }
    }
  }
#pragma unroll
  for (int o = 32; o > 0; o >>= 1) s += __shfl_xor(s, o, 64);
  float inv = 1.f / s;

#pragma unroll
  for (int c = 0; c < 4; ++c) {
    int base = c * 512 + base0;
    if (c * 512 <= r && base < wlen) {           // covers [0, wlen) exactly
      __align__(16) bf16 t8[8];
#pragma unroll
      for (int j = 0; j < 8; ++j) t8[j] = __float2bfloat16(v[c][j] * inv);
      *(bf16x8*)(row + base) = *(const bf16x8*)t8;
    }
  }
}

// ---------------- attention loop (HC = heads per chunk, compile-time) -------
// scores = [q_nope | roped q_pe] @ [kv_abs | k_pe]^T  (K = 192, k-side absorbed)
// PV' (V-side absorbed): o[b,s,h] = P @ VabsT[h]^T directly into ovb.
template <int HC>
static void attn_loop(hipStream_t stream, const bf16* qb, const bf16* kvabs,
                      const bf16* VabsT,
                      bf16* ovb, bf16* scores_c) {
  const int nch = B_ * (H_ / HC);
  for (int ch = 0; ch < nch; ++ch) {
    int b = ch / (H_ / HC), hq = ch % (H_ / HC), h0 = hq * HC;

    // scores (bf16 out scaled by SCALE_, causal block skip), all HC heads in z
    G<DQK_, H_ * DQK_, DQK_, S_, 8 | 2>(stream,
        qb + (long)b * S_ * (H_ * DQK_) + (long)h0 * DQK_, DQK_,
        kvabs + (long)(b * H_ + h0) * S_ * DQK_, (long)S_ * DQK_,
        scores_c, (long)S_ * S_, S_, S_, HC);
    // softmax (in-place bf16, wave-per-row)
    softmax_causal<<<dim3(S_ / 4, HC), 256, 0, stream>>>(scores_c);
    // PV': ovb[b,:,h*128:...] = P @ VabsT[h]^T (causal K-limit + pairing)
    G<S_, S_, S_, H_ * DV_, 4 | 16>(stream,
        scores_c, (long)S_ * S_,
        VabsT + (long)b * S_ * S_ + (long)h0 * DV_ * S_, (long)DV_ * S_,
        ovb + (long)b * S_ * (H_ * DV_) + (long)h0 * DV_, DV_, S_, DV_, HC);
  }
}

// ---------------- host ----------------
extern "C" void kernel_launch(void* const* d_in, const int* in_sizes, int n_in,
                              void* d_out, int out_size, void* d_ws, size_t ws_size,
                              hipStream_t stream) {
  const float* x     = (const float*)d_in[0];
  const float* wq_a  = (const float*)d_in[1];
  const float* qnw   = (const float*)d_in[2];
  const float* wq_b  = (const float*)d_in[3];
  const float* wkv_a = (const float*)d_in[4];
  const float* kvnw  = (const float*)d_in[5];
  const float* wkv_b = (const float*)d_in[6];
  const float* wo    = (const float*)d_in[7];
  const float* cosb  = (const float*)d_in[8];
  const float* sinb  = (const float*)d_in[9];
  float* out = (float*)d_out;
  (void)in_sizes; (void)n_in; (void)out_size;

  // P = 101,187,584; E overlay = 45,088,768; scores overlay = hc*8,388,608.
  // hc=16 needs 235,405,312; hc=8 needs 168,296,448; hc=4 needs 146,276,352.
  int hc;
  if      (ws_size >= 235405312UL) hc = 16;
  else if (ws_size >= 168296448UL) hc = 8;
  else                             hc = 4;

  char* base = (char*)d_ws;
  long off = 0;
  auto at = [&](long bytes) { char* r = base + off; off += bytes; return r; };

  // P region (persistent across the whole call) -- 101,187,584 B
  bf16* qb    = (bf16*)at(25165824L);   // 4096x3072 bf16
  bf16* ovb   = (bf16*)at(16777216L);   // 4096x2048 bf16
  bf16* kfull = (bf16*)at(4718592L);    // 4096x576  bf16
  bf16* wkvbb = (bf16*)at(4194304L);    // 4096x512  bf16
  bf16* wob   = (bf16*)at(8388608L);    // 2048x2048 bf16
  bf16* kvabs = (bf16*)at(25165824L);   // 2x16x2048x192 bf16 [kv_abs | k_pe]
  bf16* VabsT = (bf16*)at(16777216L);   // 2 x [2048 n][2048 t] bf16 (V-absorbed, transposed)
  char* ov = base + off;                // overlay region

  // E overlay (early phase; all dead before the attention loop)
  bf16*  xb    = (bf16*) (ov);                 // 4096x2048 bf16
  bf16*  wqab  = (bf16*) (ov + 16777216L);     // 1536x2048 bf16
  bf16*  wqbb  = (bf16*) (ov + 23068672L);     // 3072x1536 bf16
  bf16*  qa    = (bf16*) (ov + 32505856L);     // 4096x1536 bf16
  float* kvraw = (float*)qa;                   // overlay on qa, qa dead first

  // loop overlay (attention phase): scores only now
  bf16* scores_c = (bf16*)ov;                  // hc x 2048x2048 bf16

  // wkv_a (bf16, padded 576->640 rows) temporarily lives in VabsT, which is
  // only written by the Vabs GEMM AFTER the kv GEMM consumed it.
  bf16* wkvab = VabsT;   // 640*2048*2 = 2.62MB <= 16.8MB

  cvt_all<<<4096, 256, 0, stream>>>(x, wq_a, wq_b, wkv_b, wo, wkv_a,
                                    xb, wqab, wqbb, wkvbb, wob, wkvab);

  // q path: qa = x@wq_a^T -> rmsnorm -> qb = qa@wq_b^T -> rope q_pe in place
  G<DIM_, DIM_, DIM_, QL_, 0>(stream, xb, 0, wqab, 0, qa, 0, BS_, QL_, 1);
  rmsnorm_qa<<<BS_, 256, 0, stream>>>(qa, qnw);
  G<QL_, QL_, QL_, H_ * DQK_, 0>(stream, qa, 0, wqbb, 0, qb, 0, BS_, H_ * DQK_, 1);
  rope_q<<<BS_ * H_ / 8, 256, 0, stream>>>(qb, cosb, sinb);

  // kv path: kvraw = x@wkv_a^T (padded, fp32) -> norm+rope -> kfull
  G<DIM_, DIM_, DIM_, NKVP_, 1>(stream, xb, 0, wkvab, 0, kvraw, 0, BS_, NKVP_, 1);
  kv_post<<<BS_, 256, 0, stream>>>(kvraw, kvnw, cosb, sinb, kfull);

  // k-side absorption: kvabs[b,h,t,0:128] = kv_c[b,t,:] @ w_nope[h]^T
  for (int b = 0; b < B_; ++b)
    G<KVL_, NKV_, KVL_, DQK_, 0>(stream,
        kfull + (long)b * S_ * NKV_, 0, wkvbb, (long)256 * KVL_,
        kvabs + (long)b * H_ * S_ * DQK_, (long)S_ * DQK_, S_, DN_, H_);
  // kvabs[b,h,t,128:192] = k_pe (roped, shared across heads)
  kpe_fill<<<8192, 256, 0, stream>>>(kfull, kvabs);

  // V-side absorption: VabsT[b][h*128+j][t] = kv_c[b,t,:] . w_v[h,j,:]
  // (B head-strided from stacked wkv_b rows; C written transposed)
  G<KVL_, NKV_, KVL_, S_, 32 | 64>(stream,
      kfull, (long)S_ * NKV_, wkvbb, 0,
      VabsT, (long)S_ * S_, S_, H_ * DV_, B_);

  // attention chunks
  if (hc == 16)
    attn_loop<16>(stream, qb, kvabs, VabsT, ovb, scores_c);
  else if (hc == 8)
    attn_loop<8>(stream, qb, kvabs, VabsT, ovb, scores_c);
  else
    attn_loop<4>(stream, qb, kvabs, VabsT, ovb, scores_c);

  // final projection: out = ovb @ wo^T (fp32 out)
  G<H_ * DV_, H_ * DV_, H_ * DV_, DIM_, 1>(stream, ovb, 0, wob, 0, out, 0, BS_, DIM_, 1);
}

// Round 10
// 517.876 us; speedup vs baseline: 1.4818x; 1.0496x over previous
//
#include <hip/hip_runtime.h>
#include <hip/hip_bf16.h>
#include <stdint.h>

// ---------------- problem constants ----------------
#define B_    2
#define S_    2048
#define DIM_  2048
#define H_    16
#define QL_   1536
#define KVL_  512
#define DN_   128
#define DR_   64
#define DV_   128
#define DQK_  192
#define NKV_  576     // KVL_ + DR_
#define NKVP_ 640     // padded to multiple of 128
#define BS_   (B_*S_)
#define SCALE_ 0.07216878364870322f   // 192^-0.5

typedef __hip_bfloat16 bf16;
typedef float f32x4 __attribute__((ext_vector_type(4)));
typedef short bf16x8 __attribute__((ext_vector_type(8)));   // 8 bf16 (4 VGPRs)

// ---------------- GEMM (C = A @ B^T), r1 structure (measured best) ---------
// 512 threads = 8 waves (2Mx4N), per-wave 64x32 (acc[4][2]), 32 KiB LDS,
// sync-stage-sync 2-barrier K-loop. R3(8-phase)/R4(4w dbuf)/R5(8w dbuf)
// all regressed vs this; do not re-pipeline without ablation evidence.
#define BMT 128
#define BNT 128
#define BKT 64

__device__ __forceinline__ void gload_lds16(const void* g, void* l) {
#if __has_builtin(__builtin_amdgcn_global_load_lds)
  __builtin_amdgcn_global_load_lds(
      (const __attribute__((address_space(1))) void*)g,
      (__attribute__((address_space(3))) void*)l, 16, 0, 0);
#else
  *(uint4*)l = *(const uint4*)g;
#endif
}

// A: M x K (row-major, LDA), B: N x K (row-major, LDB) -> C: M x N (LDC)
// FLAGS: 1 = fp32 C, 8 = bf16 C scaled by SCALE_, else bf16 C;
//        2 = causal block skip (scores), 4 = causal K-limit (PV),
//        16 = row-pair balancing: grid.y halved; block processes row-tiles
//             ry and (2*gridDim.y-1-ry) sequentially (uniform causal work
//             per block; fixed the same-tile-per-CU imbalance, R6: -54us),
//        128 = q1+kv split output: cols [0,QL_) -> bf16 Cv (LDC=QL_),
//              cols [QL_,QL_+NKVP_) -> fp32 Cv2 (LDC=NKVP_),
//        256 = absorb+Vabs split: B = wkvbb rows 0..4095 ([h][nope|v]);
//              even 128-col block -> kvabs[b,h,rr,0:128] (bf16, LDC=DQK_),
//              odd  128-col block -> VabsT[b][h*128+j][rr] transposed
//              (8B short4 quad stores).
template <int K, int LDA, int LDB, int LDC, int FLAGS>
__global__ __launch_bounds__(512, 4) void gemm_t(
    const bf16* __restrict__ A, long saz,
    const bf16* __restrict__ Bm, long sbz,
    void* __restrict__ Cv, long scz,
    void* __restrict__ Cv2)
{
  int z = blockIdx.z;
  A  += (long)z * saz;
  Bm += (long)z * sbz;
  long coff = (long)z * scz;

  // XCD-aware chunked swizzle (every grid here has nwg % 8 == 0)
  int gx = gridDim.x;
  int lin = blockIdx.y * gx + blockIdx.x;
  int nwg = gx * gridDim.y;
  int wg = (lin & 7) * (nwg >> 3) + (lin >> 3);
  int ry = wg / gx, col0 = (wg % gx) * BNT;

  int tid = threadIdx.x, lane = tid & 63, wave = tid >> 6;
  int wm = (wave >> 2) * 64, wn = (wave & 3) * 32;
  int quad = lane >> 4, l16 = lane & 15;

  __shared__ __align__(16) bf16 Asm[BMT * BKT];
  __shared__ __align__(16) bf16 Bsm[BNT * BKT];

  const int npass = (FLAGS & 16) ? 2 : 1;
  const int nty = gridDim.y * ((FLAGS & 16) ? 2 : 1);

  for (int p = 0; p < npass; ++p) {
    int rt = (p == 0) ? ry : (nty - 1 - ry);
    int row0 = rt * BMT;

    if (FLAGS & 2) { if (col0 > row0 + (BMT - 1)) continue; }  // fully masked
    int kend = K;
    if (FLAGS & 4) { int lim = row0 + BMT; if (lim < kend) kend = lim; }

    f32x4 acc[4][2] = {};

    for (int k0 = 0; k0 < kend; k0 += BKT) {
      __syncthreads();
#pragma unroll
      for (int t = 0; t < 2; ++t) {
        int c = (wave * 2 + t) * 64 + lane;      // 16B chunk id 0..1023
        int m = c >> 3, jx = c & 7, j = jx ^ (m & 7);
        gload_lds16(A  + (long)((row0 + m) * LDA + k0 + j * 8), Asm + c * 8);
        gload_lds16(Bm + (long)((col0 + m) * LDB + k0 + j * 8), Bsm + c * 8);
      }
      __syncthreads();
#pragma unroll
      for (int kk = 0; kk < BKT; kk += 32) {
        int jl = (kk >> 3) + quad;
        bf16x8 af[4], bfv[2];
#pragma unroll
        for (int i = 0; i < 4; ++i) {
          int m = wm + i * 16 + l16;
          af[i]  = *(const bf16x8*)(Asm + m * 64 + ((jl ^ (m & 7)) * 8));
        }
#pragma unroll
        for (int jn = 0; jn < 2; ++jn) {
          int n = wn + jn * 16 + l16;
          bfv[jn] = *(const bf16x8*)(Bsm + n * 64 + ((jl ^ (n & 7)) * 8));
        }
#pragma unroll
        for (int i = 0; i < 4; ++i)
#pragma unroll
          for (int jn = 0; jn < 2; ++jn)
            acc[i][jn] = __builtin_amdgcn_mfma_f32_16x16x32_bf16(af[i], bfv[jn], acc[i][jn], 0, 0, 0);
      }
    }
    // pass 2's first __syncthreads protects LDS reuse across passes.

    // epilogue: C/D layout col=lane&15, row=quad*4+reg (m89/m91 verified)
    if (FLAGS & 128) {
      // q1+kv split: block cols are entirely on one side (QL_ % 128 == 0)
      if (col0 < QL_) {
        bf16* C = (bf16*)Cv;
#pragma unroll
        for (int i = 0; i < 4; ++i)
#pragma unroll
          for (int jn = 0; jn < 2; ++jn)
#pragma unroll
            for (int r = 0; r < 4; ++r) {
              int rr = row0 + wm + i * 16 + quad * 4 + r;
              int cc = col0 + wn + jn * 16 + l16;
              C[(long)rr * QL_ + cc] = __float2bfloat16(acc[i][jn][r]);
            }
      } else {
        float* C2 = (float*)Cv2;
#pragma unroll
        for (int i = 0; i < 4; ++i)
#pragma unroll
          for (int jn = 0; jn < 2; ++jn)
#pragma unroll
            for (int r = 0; r < 4; ++r) {
              int rr = row0 + wm + i * 16 + quad * 4 + r;
              int cc = col0 + wn + jn * 16 + l16 - QL_;
              C2[(long)rr * NKVP_ + cc] = acc[i][jn][r];
            }
      }
    } else if (FLAGS & 256) {
      // absorb+Vabs split: cb even -> kvabs nope slice; cb odd -> VabsT^T
      int cb = col0 >> 7, h = cb >> 1;
      if ((cb & 1) == 0) {
        bf16* C = (bf16*)Cv + ((long)z * H_ + h) * (long)S_ * DQK_;
#pragma unroll
        for (int i = 0; i < 4; ++i)
#pragma unroll
          for (int jn = 0; jn < 2; ++jn)
#pragma unroll
            for (int r = 0; r < 4; ++r) {
              int rr = row0 + wm + i * 16 + quad * 4 + r;
              int cc = (wn + jn * 16 + l16) & 127;     // col within nope 128
              C[(long)rr * DQK_ + cc] = __float2bfloat16(acc[i][jn][r]);
            }
      } else {
        bf16* C = (bf16*)Cv2 + (long)z * S_ * S_;
#pragma unroll
        for (int i = 0; i < 4; ++i)
#pragma unroll
          for (int jn = 0; jn < 2; ++jn) {
            int rr = row0 + wm + i * 16 + quad * 4;
            int nv = h * 128 + ((wn + jn * 16 + l16) & 127);
            __align__(8) bf16 t4[4];
#pragma unroll
            for (int r = 0; r < 4; ++r) t4[r] = __float2bfloat16(acc[i][jn][r]);
            *(short4*)(C + (long)nv * S_ + rr) = *(const short4*)t4;
          }
      }
    } else if (FLAGS & 1) {
      float* C = (float*)Cv + coff;
#pragma unroll
      for (int i = 0; i < 4; ++i)
#pragma unroll
        for (int jn = 0; jn < 2; ++jn)
#pragma unroll
          for (int r = 0; r < 4; ++r) {
            int rr = row0 + wm + i * 16 + quad * 4 + r;
            int cc = col0 + wn + jn * 16 + l16;
            C[(long)rr * LDC + cc] = acc[i][jn][r];
          }
    } else if (FLAGS & 8) {
      bf16* C = (bf16*)Cv + coff;
#pragma unroll
      for (int i = 0; i < 4; ++i)
#pragma unroll
        for (int jn = 0; jn < 2; ++jn)
#pragma unroll
          for (int r = 0; r < 4; ++r) {
            int rr = row0 + wm + i * 16 + quad * 4 + r;
            int cc = col0 + wn + jn * 16 + l16;
            C[(long)rr * LDC + cc] = __float2bfloat16(acc[i][jn][r] * SCALE_);
          }
    } else {
      bf16* C = (bf16*)Cv + coff;
#pragma unroll
      for (int i = 0; i < 4; ++i)
#pragma unroll
        for (int jn = 0; jn < 2; ++jn)
#pragma unroll
          for (int r = 0; r < 4; ++r) {
            int rr = row0 + wm + i * 16 + quad * 4 + r;
            int cc = col0 + wn + jn * 16 + l16;
            C[(long)rr * LDC + cc] = __float2bfloat16(acc[i][jn][r]);
          }
    }
  }
}

template <int K, int LDA, int LDB, int LDC, int FLAGS>
static inline void G(hipStream_t st, const bf16* A, long saz, const bf16* Bp, long sbz,
                     void* C, long scz, int M, int N, int Z, void* C2 = nullptr) {
  int gy = M / BMT;
  if (FLAGS & 16) gy >>= 1;           // row-pair balancing: half the y-grid
  dim3 g(N / BNT, gy, Z);
  gemm_t<K, LDA, LDB, LDC, FLAGS><<<g, 512, 0, st>>>(A, saz, Bp, sbz, C, scz, C2);
}

// ---------------- helpers ----------------
__device__ __forceinline__ float wsum(float v) {
#pragma unroll
  for (int o = 32; o > 0; o >>= 1) v += __shfl_down(v, o, 64);
  return v;
}

// fused fp32->bf16 conversion pass, vectorized.
// Destination layout note: wkvab must sit CONTIGUOUSLY after wqab (the
// q1+kv merged GEMM uses rows 0..1535=wq_a, 1536..2175=wkv_a-padded).
#define CVT_N0  8388608L    // x -> xb            (4096*2048)
#define CVT_N1 11534336L    // wq_a -> wqab       (+1536*2048)
#define CVT_N2 16252928L    // wq_b -> wqbb       (+3072*1536)
#define CVT_N3 18350080L    // wkv_b -> wkvbb     (+4096*512)
#define CVT_N4 22544384L    // wo -> wob          (+2048*2048)
#define CVT_N5 23855104L    // wkv_a pad -> wkvab (+640*2048, valid 1179648)
__device__ __forceinline__ void cvt8(const float* __restrict__ s, bf16* __restrict__ d) {
  float4 a = ((const float4*)s)[0], b = ((const float4*)s)[1];
  __align__(16) bf16 t[8];
  t[0] = __float2bfloat16(a.x); t[1] = __float2bfloat16(a.y);
  t[2] = __float2bfloat16(a.z); t[3] = __float2bfloat16(a.w);
  t[4] = __float2bfloat16(b.x); t[5] = __float2bfloat16(b.y);
  t[6] = __float2bfloat16(b.z); t[7] = __float2bfloat16(b.w);
  *(uint4*)d = *(const uint4*)t;
}
__global__ __launch_bounds__(256) void cvt_all(
    const float* __restrict__ x, const float* __restrict__ wq_a,
    const float* __restrict__ wq_b, const float* __restrict__ wkv_b,
    const float* __restrict__ wo, const float* __restrict__ wkv_a,
    bf16* __restrict__ xb, bf16* __restrict__ wqab, bf16* __restrict__ wqbb,
    bf16* __restrict__ wkvbb, bf16* __restrict__ wob, bf16* __restrict__ wkvab)
{
  const long ngrp = CVT_N5 / 8;
  for (long v = (long)blockIdx.x * 256 + threadIdx.x; v < ngrp; v += (long)gridDim.x * 256) {
    long i = v * 8;
    if (i < CVT_N0) {
      cvt8(x + i, xb + i);
    } else if (i < CVT_N1) {
      long j = i - CVT_N0; cvt8(wq_a + j, wqab + j);
    } else if (i < CVT_N2) {
      long j = i - CVT_N1; cvt8(wq_b + j, wqbb + j);
    } else if (i < CVT_N3) {
      long j = i - CVT_N2; cvt8(wkv_b + j, wkvbb + j);
    } else if (i < CVT_N4) {
      long j = i - CVT_N3; cvt8(wo + j, wob + j);
    } else {
      long j = i - CVT_N4;
      if (j < (long)NKV_ * DIM_) cvt8(wkv_a + j, wkvab + j);
      else { __align__(16) bf16 t[8] = {}; *(uint4*)(wkvab + j) = *(const uint4*)t; }
    }
  }
}

// in-place RMSNorm of qa rows (1536), bf16
__global__ __launch_bounds__(256) void rmsnorm_qa(bf16* __restrict__ qa, const float* __restrict__ w) {
  long row = blockIdx.x;
  bf16* pr = qa + row * QL_;
  int tid = threadIdx.x, lane = tid & 63, wave = tid >> 6;
  float v[6]; float ss = 0.f;
#pragma unroll
  for (int k = 0; k < 6; ++k) { int c = tid + k * 256; v[k] = __bfloat162float(pr[c]); ss += v[k] * v[k]; }
  ss = wsum(ss);
  __shared__ float sred[4];
  if (lane == 0) sred[wave] = ss;
  __syncthreads();
  float tot = sred[0] + sred[1] + sred[2] + sred[3];
  float scl = rsqrtf(tot / (float)QL_ + 1e-6f);
#pragma unroll
  for (int k = 0; k < 6; ++k) { int c = tid + k * 256; pr[c] = __float2bfloat16(v[k] * scl * w[c]); }
}

// kv row postproc: RMSNorm(kv_c)*w -> k_full[0:512], rope(k_pe) -> k_full[512:576]
__global__ __launch_bounds__(256) void kv_post(const float* __restrict__ kvraw, const float* __restrict__ kvw,
                                               const float* __restrict__ cosb, const float* __restrict__ sinb,
                                               bf16* __restrict__ kfull) {
  int bs = blockIdx.x;
  int s = bs & (S_ - 1);
  const float* rowp = kvraw + (long)bs * NKVP_;
  bf16* outp = kfull + (long)bs * NKV_;
  int tid = threadIdx.x, lane = tid & 63, wave = tid >> 6;
  float v0 = rowp[tid], v1 = rowp[tid + 256];
  float ss = v0 * v0 + v1 * v1;
  ss = wsum(ss);
  __shared__ float sred[4];
  if (lane == 0) sred[wave] = ss;
  __syncthreads();
  float tot = sred[0] + sred[1] + sred[2] + sred[3];
  float scl = rsqrtf(tot / (float)KVL_ + 1e-6f);
  outp[tid]       = __float2bfloat16(v0 * scl * kvw[tid]);
  outp[tid + 256] = __float2bfloat16(v1 * scl * kvw[tid + 256]);
  if (tid < 32) {
    float x0 = rowp[KVL_ + 2 * tid], x1 = rowp[KVL_ + 2 * tid + 1];
    float c = cosb[s * 32 + tid], sn = sinb[s * 32 + tid];
    outp[KVL_ + 2 * tid]     = __float2bfloat16(x0 * c - x1 * sn);
    outp[KVL_ + 2 * tid + 1] = __float2bfloat16(x0 * sn + x1 * c);
  }
}

// rope(q_pe) applied in place on qb[bs][h*192+128 .. +191], all heads/rows.
__global__ __launch_bounds__(256) void rope_q(bf16* __restrict__ qb,
                                              const float* __restrict__ cosb,
                                              const float* __restrict__ sinb) {
  int tx = threadIdx.x & 31, ty = threadIdx.x >> 5;
  long row = (long)blockIdx.x * 8 + ty;     // 0..BS_*H_-1
  long bs = row >> 4; int h = (int)(row & 15); int s = (int)(bs & (S_ - 1));
  bf16* p = qb + bs * (H_ * DQK_) + h * DQK_ + DN_;
  float x0 = __bfloat162float(p[2 * tx]), x1 = __bfloat162float(p[2 * tx + 1]);
  float c = cosb[s * 32 + tx], sn = sinb[s * 32 + tx];
  p[2 * tx]     = __float2bfloat16(x0 * c - x1 * sn);
  p[2 * tx + 1] = __float2bfloat16(x0 * sn + x1 * c);
}

// kvabs[b,h,t,128:192] = kfull[b,t,512:576] (k_pe, already roped)
__global__ __launch_bounds__(256) void kpe_fill(const bf16* __restrict__ kfull, bf16* __restrict__ kvabs) {
  const long n = (long)B_ * H_ * S_ * 64;
  for (long i = (long)blockIdx.x * 256 + threadIdx.x; i < n; i += (long)gridDim.x * 256) {
    int d = (int)(i & 63);
    long t = (i >> 6) & (S_ - 1);
    int h = (int)((i >> 17) & 15);
    int b = (int)(i >> 21);
    kvabs[(((long)(b * H_ + h) * S_) + t) * DQK_ + DN_ + d] =
        kfull[((long)b * S_ + t) * NKV_ + KVL_ + d];
  }
}

// causal softmax, wave-per-row: 4 waves/block, bf16x8 16B loads/stores,
// no LDS/barriers, butterfly reduces; per-element masking only in the
// partial 512-chunk. Zero-pads to wlen=(r&~127)+128, which equals the PV
// K-limit kend=row0+128 exactly.
__global__ __launch_bounds__(256) void softmax_causal(bf16* __restrict__ sc) {
  int wave = threadIdx.x >> 6, lane = threadIdx.x & 63;
  int r = blockIdx.x * 4 + wave, z = blockIdx.y;
  bf16* row = sc + ((long)z * S_ + r) * S_;
  int wlen = (r & ~127) + 128;
  int base0 = lane * 8;

  float v[4][8];
  float mx = -3.0e38f;
#pragma unroll
  for (int c = 0; c < 4; ++c) {
    int cb = c * 512;
    if (cb <= r) {                               // wave-uniform chunk skip
      int base = cb + base0;
      __align__(16) bf16 t8[8];
      *(bf16x8*)t8 = *(const bf16x8*)(row + base);
      if (cb + 511 <= r) {                       // full chunk: no masks
#pragma unroll
        for (int j = 0; j < 8; ++j) {
          float f = __bfloat162float(t8[j]);
          v[c][j] = f; mx = fmaxf(mx, f);
        }
      } else {                                   // partial chunk (has diag)
#pragma unroll
        for (int j = 0; j < 8; ++j) {
          float f = (base + j <= r) ? __bfloat162float(t8[j]) : -3.0e38f;
          v[c][j] = f; mx = fmaxf(mx, f);
        }
      }
    }
  }
#pragma unroll
  for (int o = 32; o > 0; o >>= 1) mx = fmaxf(mx, __shfl_xor(mx, o, 64));

  float s = 0.f;
#pragma unroll
  for (int c = 0; c < 4; ++c) {
    if (c * 512 <= r) {
#pragma unroll
      for (int j = 0; j < 8; ++j) {
        float e = __expf(v[c][j] - mx);          // masked -3e38 -> 0
        v[c][j] = e; s += e;
      }
    }
  }
#pragma unroll
  for (int o = 32; o > 0; o >>= 1) s += __shfl_xor(s, o, 64);
  float inv = 1.f / s;

#pragma unroll
  for (int c = 0; c < 4; ++c) {
    int base = c * 512 + base0;
    if (c * 512 <= r && base < wlen) {           // covers [0, wlen) exactly
      __align__(16) bf16 t8[8];
#pragma unroll
      for (int j = 0; j < 8; ++j) t8[j] = __float2bfloat16(v[c][j] * inv);
      *(bf16x8*)(row + base) = *(const bf16x8*)t8;
    }
  }
}

// ---------------- attention loop (HC = heads per chunk, compile-time) -------
// scores = [q_nope | roped q_pe] @ [kv_abs | k_pe]^T  (K = 192, k-side absorbed)
// PV' (V-side absorbed): o[b,s,h] = P @ VabsT[h]^T directly into ovb.
template <int HC>
static void attn_loop(hipStream_t stream, const bf16* qb, const bf16* kvabs,
                      const bf16* VabsT,
                      bf16* ovb, bf16* scores_c) {
  const int nch = B_ * (H_ / HC);
  for (int ch = 0; ch < nch; ++ch) {
    int b = ch / (H_ / HC), hq = ch % (H_ / HC), h0 = hq * HC;

    // scores (bf16 out scaled by SCALE_, causal block skip), all HC heads in z
    G<DQK_, H_ * DQK_, DQK_, S_, 8 | 2>(stream,
        qb + (long)b * S_ * (H_ * DQK_) + (long)h0 * DQK_, DQK_,
        kvabs + (long)(b * H_ + h0) * S_ * DQK_, (long)S_ * DQK_,
        scores_c, (long)S_ * S_, S_, S_, HC);
    // softmax (in-place bf16, wave-per-row)
    softmax_causal<<<dim3(S_ / 4, HC), 256, 0, stream>>>(scores_c);
    // PV': ovb[b,:,h*128:...] = P @ VabsT[h]^T (causal K-limit + pairing)
    G<S_, S_, S_, H_ * DV_, 4 | 16>(stream,
        scores_c, (long)S_ * S_,
        VabsT + (long)b * S_ * S_ + (long)h0 * DV_ * S_, (long)DV_ * S_,
        ovb + (long)b * S_ * (H_ * DV_) + (long)h0 * DV_, DV_, S_, DV_, HC);
  }
}

// ---------------- host ----------------
extern "C" void kernel_launch(void* const* d_in, const int* in_sizes, int n_in,
                              void* d_out, int out_size, void* d_ws, size_t ws_size,
                              hipStream_t stream) {
  const float* x     = (const float*)d_in[0];
  const float* wq_a  = (const float*)d_in[1];
  const float* qnw   = (const float*)d_in[2];
  const float* wq_b  = (const float*)d_in[3];
  const float* wkv_a = (const float*)d_in[4];
  const float* kvnw  = (const float*)d_in[5];
  const float* wkv_b = (const float*)d_in[6];
  const float* wo    = (const float*)d_in[7];
  const float* cosb  = (const float*)d_in[8];
  const float* sinb  = (const float*)d_in[9];
  float* out = (float*)d_out;
  (void)in_sizes; (void)n_in; (void)out_size;

  // P = 101,187,584; E overlay = 58,195,968; scores overlay = hc*8,388,608.
  // hc=16: 235,405,312; hc=8: 168,296,448; hc=4: 159,383,552.
  int hc;
  if      (ws_size >= 235405312UL) hc = 16;
  else if (ws_size >= 168296448UL) hc = 8;
  else                             hc = 4;

  char* base = (char*)d_ws;
  long off = 0;
  auto at = [&](long bytes) { char* r = base + off; off += bytes; return r; };

  // P region (persistent across the whole call) -- 101,187,584 B
  bf16* qb    = (bf16*)at(25165824L);   // 4096x3072 bf16
  bf16* ovb   = (bf16*)at(16777216L);   // 4096x2048 bf16
  bf16* kfull = (bf16*)at(4718592L);    // 4096x576  bf16
  bf16* wkvbb = (bf16*)at(4194304L);    // 4096x512  bf16
  bf16* wob   = (bf16*)at(8388608L);    // 2048x2048 bf16
  bf16* kvabs = (bf16*)at(25165824L);   // 2x16x2048x192 bf16 [kv_abs | k_pe]
  bf16* VabsT = (bf16*)at(16777216L);   // 2 x [2048 n][2048 t] bf16
  char* ov = base + off;                // overlay region

  // E overlay (early phase; all dead before the attention loop)
  // wqab & wkvab are CONTIGUOUS: merged q1+kv GEMM B rows 0..2175.
  bf16*  xb    = (bf16*) (ov);                 // 4096x2048 bf16  (16,777,216)
  bf16*  wqab  = (bf16*) (ov + 16777216L);     // 1536x2048 bf16  ( 6,291,456)
  bf16*  wkvab = (bf16*) (ov + 23068672L);     //  640x2048 bf16  ( 2,621,440)
  bf16*  wqbb  = (bf16*) (ov + 25690112L);     // 3072x1536 bf16  ( 9,437,184)
  bf16*  qa    = (bf16*) (ov + 35127296L);     // 4096x1536 bf16  (12,582,912)
  float* kvraw = (float*)(ov + 47710208L);     // 4096x640  fp32  (10,485,760)
  // E total = 58,195,968

  // loop overlay (attention phase): scores only
  bf16* scores_c = (bf16*)ov;                  // hc x 2048x2048 bf16

  cvt_all<<<4096, 256, 0, stream>>>(x, wq_a, wq_b, wkv_b, wo, wkv_a,
                                    xb, wqab, wqbb, wkvbb, wob, wkvab);

  // merged q1+kv: [qa | kvraw] = xb @ [wqab ; wkvab]^T  (N=2176, FLAG 128)
  G<DIM_, DIM_, DIM_, QL_, 128>(stream, xb, 0, wqab, 0,
                                qa, 0, BS_, QL_ + NKVP_, 1, kvraw);
  rmsnorm_qa<<<BS_, 256, 0, stream>>>(qa, qnw);
  kv_post<<<BS_, 256, 0, stream>>>(kvraw, kvnw, cosb, sinb, kfull);

  // q2: qb = qa @ wq_b^T -> rope q_pe in place
  G<QL_, QL_, QL_, H_ * DQK_, 0>(stream, qa, 0, wqbb, 0, qb, 0, BS_, H_ * DQK_, 1);
  rope_q<<<BS_ * H_ / 8, 256, 0, stream>>>(qb, cosb, sinb);

  // merged absorb+Vabs: kfull @ wkvbb^T (N=4096, z=B), FLAG 256 epilogue
  // routes even 128-col blocks -> kvabs nope slices, odd -> VabsT transposed.
  G<KVL_, NKV_, KVL_, DQK_, 256>(stream,
      kfull, (long)S_ * NKV_, wkvbb, 0,
      kvabs, 0, S_, H_ * 256, B_, VabsT);
  // kvabs[b,h,t,128:192] = k_pe (roped, shared across heads)
  kpe_fill<<<8192, 256, 0, stream>>>(kfull, kvabs);

  // attention chunks
  if (hc == 16)
    attn_loop<16>(stream, qb, kvabs, VabsT, ovb, scores_c);
  else if (hc == 8)
    attn_loop<8>(stream, qb, kvabs, VabsT, ovb, scores_c);
  else
    attn_loop<4>(stream, qb, kvabs, VabsT, ovb, scores_c);

  // final projection: out = ovb @ wo^T (fp32 out)
  G<H_ * DV_, H_ * DV_, H_ * DV_, DIM_, 1>(stream, ovb, 0, wob, 0, out, 0, BS_, DIM_, 1);
}

// Round 11
// 517.794 us; speedup vs baseline: 1.4820x; 1.0002x over previous
//
#include <hip/hip_runtime.h>
#include <hip/hip_bf16.h>
#include <stdint.h>

// ---------------- problem constants ----------------
#define B_    2
#define S_    2048
#define DIM_  2048
#define H_    16
#define QL_   1536
#define KVL_  512
#define DN_   128
#define DR_   64
#define DV_   128
#define DQK_  192
#define NKV_  576     // KVL_ + DR_
#define NKVP_ 640     // padded to multiple of 128
#define BS_   (B_*S_)
#define SCALE_ 0.07216878364870322f   // 192^-0.5

typedef __hip_bfloat16 bf16;
typedef float f32x4 __attribute__((ext_vector_type(4)));
typedef short bf16x8 __attribute__((ext_vector_type(8)));   // 8 bf16 (4 VGPRs)

// ---------------- GEMM (C = A @ B^T), r1 structure (measured best) ---------
// 512 threads = 8 waves (2Mx4N), per-wave 64x32 (acc[4][2]), 32 KiB LDS,
// sync-stage-sync 2-barrier K-loop. R3(8-phase)/R4(4w dbuf)/R5(8w dbuf)
// all regressed vs this; do not re-pipeline without ablation evidence.
// Envelope at big shapes: ~700-815 TF (q1kv/final/q2, R10 counters).
#define BMT 128
#define BNT 128
#define BKT 64

__device__ __forceinline__ void gload_lds16(const void* g, void* l) {
#if __has_builtin(__builtin_amdgcn_global_load_lds)
  __builtin_amdgcn_global_load_lds(
      (const __attribute__((address_space(1))) void*)g,
      (__attribute__((address_space(3))) void*)l, 16, 0, 0);
#else
  *(uint4*)l = *(const uint4*)g;
#endif
}

// A: M x K (row-major, LDA), B: N x K (row-major, LDB) -> C: M x N (LDC)
// FLAGS: 1 = fp32 C, 8 = bf16 C scaled by SCALE_, else bf16 C;
//        2 = causal block skip (scores), 4 = causal K-limit (PV),
//        16 = row-pair balancing: grid.y halved; block processes row-tiles
//             ry and (2*gridDim.y-1-ry) sequentially (uniform causal work
//             per block; fixed the same-tile-per-CU imbalance, R6: -54us),
//        128 = q1+kv split output: cols [0,QL_) -> bf16 Cv (LDC=QL_),
//              cols [QL_,QL_+NKVP_) -> fp32 Cv2 (LDC=NKVP_),
//        256 = absorb+Vabs split: B = wkvbb rows 0..4095 ([h][nope|v]);
//              even 128-col block -> kvabs[b,h,rr,0:128] (bf16, LDC=DQK_),
//              odd  128-col block -> VabsT[b][h*128+j][rr] transposed
//              (8B short4 quad stores).
template <int K, int LDA, int LDB, int LDC, int FLAGS>
__global__ __launch_bounds__(512, 4) void gemm_t(
    const bf16* __restrict__ A, long saz,
    const bf16* __restrict__ Bm, long sbz,
    void* __restrict__ Cv, long scz,
    void* __restrict__ Cv2)
{
  int z = blockIdx.z;
  A  += (long)z * saz;
  Bm += (long)z * sbz;
  long coff = (long)z * scz;

  // XCD-aware chunked swizzle (every grid here has nwg % 8 == 0)
  int gx = gridDim.x;
  int lin = blockIdx.y * gx + blockIdx.x;
  int nwg = gx * gridDim.y;
  int wg = (lin & 7) * (nwg >> 3) + (lin >> 3);
  int ry = wg / gx, col0 = (wg % gx) * BNT;

  int tid = threadIdx.x, lane = tid & 63, wave = tid >> 6;
  int wm = (wave >> 2) * 64, wn = (wave & 3) * 32;
  int quad = lane >> 4, l16 = lane & 15;

  __shared__ __align__(16) bf16 Asm[BMT * BKT];
  __shared__ __align__(16) bf16 Bsm[BNT * BKT];

  const int npass = (FLAGS & 16) ? 2 : 1;
  const int nty = gridDim.y * ((FLAGS & 16) ? 2 : 1);

  for (int p = 0; p < npass; ++p) {
    int rt = (p == 0) ? ry : (nty - 1 - ry);
    int row0 = rt * BMT;

    if (FLAGS & 2) { if (col0 > row0 + (BMT - 1)) continue; }  // fully masked
    int kend = K;
    if (FLAGS & 4) { int lim = row0 + BMT; if (lim < kend) kend = lim; }

    f32x4 acc[4][2] = {};

    for (int k0 = 0; k0 < kend; k0 += BKT) {
      __syncthreads();
#pragma unroll
      for (int t = 0; t < 2; ++t) {
        int c = (wave * 2 + t) * 64 + lane;      // 16B chunk id 0..1023
        int m = c >> 3, jx = c & 7, j = jx ^ (m & 7);
        gload_lds16(A  + (long)((row0 + m) * LDA + k0 + j * 8), Asm + c * 8);
        gload_lds16(Bm + (long)((col0 + m) * LDB + k0 + j * 8), Bsm + c * 8);
      }
      __syncthreads();
#pragma unroll
      for (int kk = 0; kk < BKT; kk += 32) {
        int jl = (kk >> 3) + quad;
        bf16x8 af[4], bfv[2];
#pragma unroll
        for (int i = 0; i < 4; ++i) {
          int m = wm + i * 16 + l16;
          af[i]  = *(const bf16x8*)(Asm + m * 64 + ((jl ^ (m & 7)) * 8));
        }
#pragma unroll
        for (int jn = 0; jn < 2; ++jn) {
          int n = wn + jn * 16 + l16;
          bfv[jn] = *(const bf16x8*)(Bsm + n * 64 + ((jl ^ (n & 7)) * 8));
        }
#pragma unroll
        for (int i = 0; i < 4; ++i)
#pragma unroll
          for (int jn = 0; jn < 2; ++jn)
            acc[i][jn] = __builtin_amdgcn_mfma_f32_16x16x32_bf16(af[i], bfv[jn], acc[i][jn], 0, 0, 0);
      }
    }
    // pass 2's first __syncthreads protects LDS reuse across passes.

    // epilogue: C/D layout col=lane&15, row=quad*4+reg (m89/m91 verified)
    if (FLAGS & 128) {
      // q1+kv split: block cols are entirely on one side (QL_ % 128 == 0)
      if (col0 < QL_) {
        bf16* C = (bf16*)Cv;
#pragma unroll
        for (int i = 0; i < 4; ++i)
#pragma unroll
          for (int jn = 0; jn < 2; ++jn)
#pragma unroll
            for (int r = 0; r < 4; ++r) {
              int rr = row0 + wm + i * 16 + quad * 4 + r;
              int cc = col0 + wn + jn * 16 + l16;
              C[(long)rr * QL_ + cc] = __float2bfloat16(acc[i][jn][r]);
            }
      } else {
        float* C2 = (float*)Cv2;
#pragma unroll
        for (int i = 0; i < 4; ++i)
#pragma unroll
          for (int jn = 0; jn < 2; ++jn)
#pragma unroll
            for (int r = 0; r < 4; ++r) {
              int rr = row0 + wm + i * 16 + quad * 4 + r;
              int cc = col0 + wn + jn * 16 + l16 - QL_;
              C2[(long)rr * NKVP_ + cc] = acc[i][jn][r];
            }
      }
    } else if (FLAGS & 256) {
      // absorb+Vabs split: cb even -> kvabs nope slice; cb odd -> VabsT^T
      int cb = col0 >> 7, h = cb >> 1;
      if ((cb & 1) == 0) {
        bf16* C = (bf16*)Cv + ((long)z * H_ + h) * (long)S_ * DQK_;
#pragma unroll
        for (int i = 0; i < 4; ++i)
#pragma unroll
          for (int jn = 0; jn < 2; ++jn)
#pragma unroll
            for (int r = 0; r < 4; ++r) {
              int rr = row0 + wm + i * 16 + quad * 4 + r;
              int cc = (wn + jn * 16 + l16) & 127;     // col within nope 128
              C[(long)rr * DQK_ + cc] = __float2bfloat16(acc[i][jn][r]);
            }
      } else {
        bf16* C = (bf16*)Cv2 + (long)z * S_ * S_;
#pragma unroll
        for (int i = 0; i < 4; ++i)
#pragma unroll
          for (int jn = 0; jn < 2; ++jn) {
            int rr = row0 + wm + i * 16 + quad * 4;
            int nv = h * 128 + ((wn + jn * 16 + l16) & 127);
            __align__(8) bf16 t4[4];
#pragma unroll
            for (int r = 0; r < 4; ++r) t4[r] = __float2bfloat16(acc[i][jn][r]);
            *(short4*)(C + (long)nv * S_ + rr) = *(const short4*)t4;
          }
      }
    } else if (FLAGS & 1) {
      float* C = (float*)Cv + coff;
#pragma unroll
      for (int i = 0; i < 4; ++i)
#pragma unroll
        for (int jn = 0; jn < 2; ++jn)
#pragma unroll
          for (int r = 0; r < 4; ++r) {
            int rr = row0 + wm + i * 16 + quad * 4 + r;
            int cc = col0 + wn + jn * 16 + l16;
            C[(long)rr * LDC + cc] = acc[i][jn][r];
          }
    } else if (FLAGS & 8) {
      bf16* C = (bf16*)Cv + coff;
#pragma unroll
      for (int i = 0; i < 4; ++i)
#pragma unroll
        for (int jn = 0; jn < 2; ++jn)
#pragma unroll
          for (int r = 0; r < 4; ++r) {
            int rr = row0 + wm + i * 16 + quad * 4 + r;
            int cc = col0 + wn + jn * 16 + l16;
            C[(long)rr * LDC + cc] = __float2bfloat16(acc[i][jn][r] * SCALE_);
          }
    } else {
      bf16* C = (bf16*)Cv + coff;
#pragma unroll
      for (int i = 0; i < 4; ++i)
#pragma unroll
        for (int jn = 0; jn < 2; ++jn)
#pragma unroll
          for (int r = 0; r < 4; ++r) {
            int rr = row0 + wm + i * 16 + quad * 4 + r;
            int cc = col0 + wn + jn * 16 + l16;
            C[(long)rr * LDC + cc] = __float2bfloat16(acc[i][jn][r]);
          }
    }
  }
}

template <int K, int LDA, int LDB, int LDC, int FLAGS>
static inline void G(hipStream_t st, const bf16* A, long saz, const bf16* Bp, long sbz,
                     void* C, long scz, int M, int N, int Z, void* C2 = nullptr) {
  int gy = M / BMT;
  if (FLAGS & 16) gy >>= 1;           // row-pair balancing: half the y-grid
  dim3 g(N / BNT, gy, Z);
  gemm_t<K, LDA, LDB, LDC, FLAGS><<<g, 512, 0, st>>>(A, saz, Bp, sbz, C, scz, C2);
}

// ---------------- helpers ----------------
__device__ __forceinline__ float wsum(float v) {
#pragma unroll
  for (int o = 32; o > 0; o >>= 1) v += __shfl_down(v, o, 64);
  return v;
}

// fused fp32->bf16 conversion pass, vectorized.
// Destination layout note: wkvab must sit CONTIGUOUSLY after wqab (the
// q1+kv merged GEMM uses rows 0..1535=wq_a, 1536..2175=wkv_a-padded).
#define CVT_N0  8388608L    // x -> xb            (4096*2048)
#define CVT_N1 11534336L    // wq_a -> wqab       (+1536*2048)
#define CVT_N2 16252928L    // wq_b -> wqbb       (+3072*1536)
#define CVT_N3 18350080L    // wkv_b -> wkvbb     (+4096*512)
#define CVT_N4 22544384L    // wo -> wob          (+2048*2048)
#define CVT_N5 23855104L    // wkv_a pad -> wkvab (+640*2048, valid 1179648)
__device__ __forceinline__ void cvt8(const float* __restrict__ s, bf16* __restrict__ d) {
  float4 a = ((const float4*)s)[0], b = ((const float4*)s)[1];
  __align__(16) bf16 t[8];
  t[0] = __float2bfloat16(a.x); t[1] = __float2bfloat16(a.y);
  t[2] = __float2bfloat16(a.z); t[3] = __float2bfloat16(a.w);
  t[4] = __float2bfloat16(b.x); t[5] = __float2bfloat16(b.y);
  t[6] = __float2bfloat16(b.z); t[7] = __float2bfloat16(b.w);
  *(uint4*)d = *(const uint4*)t;
}
__global__ __launch_bounds__(256) void cvt_all(
    const float* __restrict__ x, const float* __restrict__ wq_a,
    const float* __restrict__ wq_b, const float* __restrict__ wkv_b,
    const float* __restrict__ wo, const float* __restrict__ wkv_a,
    bf16* __restrict__ xb, bf16* __restrict__ wqab, bf16* __restrict__ wqbb,
    bf16* __restrict__ wkvbb, bf16* __restrict__ wob, bf16* __restrict__ wkvab)
{
  const long ngrp = CVT_N5 / 8;
  for (long v = (long)blockIdx.x * 256 + threadIdx.x; v < ngrp; v += (long)gridDim.x * 256) {
    long i = v * 8;
    if (i < CVT_N0) {
      cvt8(x + i, xb + i);
    } else if (i < CVT_N1) {
      long j = i - CVT_N0; cvt8(wq_a + j, wqab + j);
    } else if (i < CVT_N2) {
      long j = i - CVT_N1; cvt8(wq_b + j, wqbb + j);
    } else if (i < CVT_N3) {
      long j = i - CVT_N2; cvt8(wkv_b + j, wkvbb + j);
    } else if (i < CVT_N4) {
      long j = i - CVT_N3; cvt8(wo + j, wob + j);
    } else {
      long j = i - CVT_N4;
      if (j < (long)NKV_ * DIM_) cvt8(wkv_a + j, wkvab + j);
      else { __align__(16) bf16 t[8] = {}; *(uint4*)(wkvab + j) = *(const uint4*)t; }
    }
  }
}

// in-place RMSNorm of qa rows (1536), bf16
__global__ __launch_bounds__(256) void rmsnorm_qa(bf16* __restrict__ qa, const float* __restrict__ w) {
  long row = blockIdx.x;
  bf16* pr = qa + row * QL_;
  int tid = threadIdx.x, lane = tid & 63, wave = tid >> 6;
  float v[6]; float ss = 0.f;
#pragma unroll
  for (int k = 0; k < 6; ++k) { int c = tid + k * 256; v[k] = __bfloat162float(pr[c]); ss += v[k] * v[k]; }
  ss = wsum(ss);
  __shared__ float sred[4];
  if (lane == 0) sred[wave] = ss;
  __syncthreads();
  float tot = sred[0] + sred[1] + sred[2] + sred[3];
  float scl = rsqrtf(tot / (float)QL_ + 1e-6f);
#pragma unroll
  for (int k = 0; k < 6; ++k) { int c = tid + k * 256; pr[c] = __float2bfloat16(v[k] * scl * w[c]); }
}

// kv row postproc: RMSNorm(kv_c)*w -> k_full[0:512], rope(k_pe) -> k_full[512:576]
__global__ __launch_bounds__(256) void kv_post(const float* __restrict__ kvraw, const float* __restrict__ kvw,
                                               const float* __restrict__ cosb, const float* __restrict__ sinb,
                                               bf16* __restrict__ kfull) {
  int bs = blockIdx.x;
  int s = bs & (S_ - 1);
  const float* rowp = kvraw + (long)bs * NKVP_;
  bf16* outp = kfull + (long)bs * NKV_;
  int tid = threadIdx.x, lane = tid & 63, wave = tid >> 6;
  float v0 = rowp[tid], v1 = rowp[tid + 256];
  float ss = v0 * v0 + v1 * v1;
  ss = wsum(ss);
  __shared__ float sred[4];
  if (lane == 0) sred[wave] = ss;
  __syncthreads();
  float tot = sred[0] + sred[1] + sred[2] + sred[3];
  float scl = rsqrtf(tot / (float)KVL_ + 1e-6f);
  outp[tid]       = __float2bfloat16(v0 * scl * kvw[tid]);
  outp[tid + 256] = __float2bfloat16(v1 * scl * kvw[tid + 256]);
  if (tid < 32) {
    float x0 = rowp[KVL_ + 2 * tid], x1 = rowp[KVL_ + 2 * tid + 1];
    float c = cosb[s * 32 + tid], sn = sinb[s * 32 + tid];
    outp[KVL_ + 2 * tid]     = __float2bfloat16(x0 * c - x1 * sn);
    outp[KVL_ + 2 * tid + 1] = __float2bfloat16(x0 * sn + x1 * c);
  }
}

// rope(q_pe) applied in place on qb[bs][h*192+128 .. +191], all heads/rows.
__global__ __launch_bounds__(256) void rope_q(bf16* __restrict__ qb,
                                              const float* __restrict__ cosb,
                                              const float* __restrict__ sinb) {
  int tx = threadIdx.x & 31, ty = threadIdx.x >> 5;
  long row = (long)blockIdx.x * 8 + ty;     // 0..BS_*H_-1
  long bs = row >> 4; int h = (int)(row & 15); int s = (int)(bs & (S_ - 1));
  bf16* p = qb + bs * (H_ * DQK_) + h * DQK_ + DN_;
  float x0 = __bfloat162float(p[2 * tx]), x1 = __bfloat162float(p[2 * tx + 1]);
  float c = cosb[s * 32 + tx], sn = sinb[s * 32 + tx];
  p[2 * tx]     = __float2bfloat16(x0 * c - x1 * sn);
  p[2 * tx + 1] = __float2bfloat16(x0 * sn + x1 * c);
}

// kvabs[b,h,t,128:192] = kfull[b,t,512:576] (k_pe, already roped)
__global__ __launch_bounds__(256) void kpe_fill(const bf16* __restrict__ kfull, bf16* __restrict__ kvabs) {
  const long n = (long)B_ * H_ * S_ * 64;
  for (long i = (long)blockIdx.x * 256 + threadIdx.x; i < n; i += (long)gridDim.x * 256) {
    int d = (int)(i & 63);
    long t = (i >> 6) & (S_ - 1);
    int h = (int)((i >> 17) & 15);
    int b = (int)(i >> 21);
    kvabs[(((long)(b * H_ + h) * S_) + t) * DQK_ + DN_ + d] =
        kfull[((long)b * S_ + t) * NKV_ + KVL_ + d];
  }
}

// causal softmax, wave-per-row. R11: balanced row mapping -- wave w of
// block x owns row w*512 + x (NOT 4x+w). Per-block work is then
// ~(4x+3072) elems, flat within 1.7x, vs 1365:1 before; kills the
// dispatch-tail of maximal-work blocks (causal-row imbalance, same
// family as R6's PV fix). bf16x8 16B loads/stores; no LDS/barriers;
// butterfly reduces; per-element masking only in the partial 512-chunk.
// Zero-pads to wlen=(r&~127)+128 == the PV K-limit kend, unchanged.
__global__ __launch_bounds__(256) void softmax_causal(bf16* __restrict__ sc) {
  int wave = threadIdx.x >> 6, lane = threadIdx.x & 63;
  int r = wave * 512 + blockIdx.x, z = blockIdx.y;
  bf16* row = sc + ((long)z * S_ + r) * S_;
  int wlen = (r & ~127) + 128;
  int base0 = lane * 8;

  float v[4][8];
  float mx = -3.0e38f;
#pragma unroll
  for (int c = 0; c < 4; ++c) {
    int cb = c * 512;
    if (cb <= r) {                               // wave-uniform chunk skip
      int base = cb + base0;
      __align__(16) bf16 t8[8];
      *(bf16x8*)t8 = *(const bf16x8*)(row + base);
      if (cb + 511 <= r) {                       // full chunk: no masks
#pragma unroll
        for (int j = 0; j < 8; ++j) {
          float f = __bfloat162float(t8[j]);
          v[c][j] = f; mx = fmaxf(mx, f);
        }
      } else {                                   // partial chunk (has diag)
#pragma unroll
        for (int j = 0; j < 8; ++j) {
          float f = (base + j <= r) ? __bfloat162float(t8[j]) : -3.0e38f;
          v[c][j] = f; mx = fmaxf(mx, f);
        }
      }
    }
  }
#pragma unroll
  for (int o = 32; o > 0; o >>= 1) mx = fmaxf(mx, __shfl_xor(mx, o, 64));

  float s = 0.f;
#pragma unroll
  for (int c = 0; c < 4; ++c) {
    if (c * 512 <= r) {
#pragma unroll
      for (int j = 0; j < 8; ++j) {
        float e = __expf(v[c][j] - mx);          // masked -3e38 -> 0
        v[c][j] = e; s += e;
      }
    }
  }
#pragma unroll
  for (int o = 32; o > 0; o >>= 1) s += __shfl_xor(s, o, 64);
  float inv = 1.f / s;

#pragma unroll
  for (int c = 0; c < 4; ++c) {
    int base = c * 512 + base0;
    if (c * 512 <= r && base < wlen) {           // covers [0, wlen) exactly
      __align__(16) bf16 t8[8];
#pragma unroll
      for (int j = 0; j < 8; ++j) t8[j] = __float2bfloat16(v[c][j] * inv);
      *(bf16x8*)(row + base) = *(const bf16x8*)t8;
    }
  }
}

// ---------------- attention loop (HC = heads per chunk, compile-time) -------
// scores = [q_nope | roped q_pe] @ [kv_abs | k_pe]^T  (K = 192, k-side absorbed)
// PV' (V-side absorbed): o[b,s,h] = P @ VabsT[h]^T directly into ovb.
template <int HC>
static void attn_loop(hipStream_t stream, const bf16* qb, const bf16* kvabs,
                      const bf16* VabsT,
                      bf16* ovb, bf16* scores_c) {
  const int nch = B_ * (H_ / HC);
  for (int ch = 0; ch < nch; ++ch) {
    int b = ch / (H_ / HC), hq = ch % (H_ / HC), h0 = hq * HC;

    // scores (bf16 out scaled by SCALE_, causal block skip), all HC heads in z
    G<DQK_, H_ * DQK_, DQK_, S_, 8 | 2>(stream,
        qb + (long)b * S_ * (H_ * DQK_) + (long)h0 * DQK_, DQK_,
        kvabs + (long)(b * H_ + h0) * S_ * DQK_, (long)S_ * DQK_,
        scores_c, (long)S_ * S_, S_, S_, HC);
    // softmax (in-place bf16, wave-per-row, balanced mapping)
    softmax_causal<<<dim3(S_ / 4, HC), 256, 0, stream>>>(scores_c);
    // PV': ovb[b,:,h*128:...] = P @ VabsT[h]^T (causal K-limit + pairing)
    G<S_, S_, S_, H_ * DV_, 4 | 16>(stream,
        scores_c, (long)S_ * S_,
        VabsT + (long)b * S_ * S_ + (long)h0 * DV_ * S_, (long)DV_ * S_,
        ovb + (long)b * S_ * (H_ * DV_) + (long)h0 * DV_, DV_, S_, DV_, HC);
  }
}

// ---------------- host ----------------
extern "C" void kernel_launch(void* const* d_in, const int* in_sizes, int n_in,
                              void* d_out, int out_size, void* d_ws, size_t ws_size,
                              hipStream_t stream) {
  const float* x     = (const float*)d_in[0];
  const float* wq_a  = (const float*)d_in[1];
  const float* qnw   = (const float*)d_in[2];
  const float* wq_b  = (const float*)d_in[3];
  const float* wkv_a = (const float*)d_in[4];
  const float* kvnw  = (const float*)d_in[5];
  const float* wkv_b = (const float*)d_in[6];
  const float* wo    = (const float*)d_in[7];
  const float* cosb  = (const float*)d_in[8];
  const float* sinb  = (const float*)d_in[9];
  float* out = (float*)d_out;
  (void)in_sizes; (void)n_in; (void)out_size;

  // P = 101,187,584; E overlay = 58,195,968; scores overlay = hc*8,388,608.
  // hc=16: 235,405,312; hc=8: 168,296,448; hc=4: 159,383,552.
  int hc;
  if      (ws_size >= 235405312UL) hc = 16;
  else if (ws_size >= 168296448UL) hc = 8;
  else                             hc = 4;

  char* base = (char*)d_ws;
  long off = 0;
  auto at = [&](long bytes) { char* r = base + off; off += bytes; return r; };

  // P region (persistent across the whole call) -- 101,187,584 B
  bf16* qb    = (bf16*)at(25165824L);   // 4096x3072 bf16
  bf16* ovb   = (bf16*)at(16777216L);   // 4096x2048 bf16
  bf16* kfull = (bf16*)at(4718592L);    // 4096x576  bf16
  bf16* wkvbb = (bf16*)at(4194304L);    // 4096x512  bf16
  bf16* wob   = (bf16*)at(8388608L);    // 2048x2048 bf16
  bf16* kvabs = (bf16*)at(25165824L);   // 2x16x2048x192 bf16 [kv_abs | k_pe]
  bf16* VabsT = (bf16*)at(16777216L);   // 2 x [2048 n][2048 t] bf16
  char* ov = base + off;                // overlay region

  // E overlay (early phase; all dead before the attention loop)
  // wqab & wkvab are CONTIGUOUS: merged q1+kv GEMM B rows 0..2175.
  bf16*  xb    = (bf16*) (ov);                 // 4096x2048 bf16  (16,777,216)
  bf16*  wqab  = (bf16*) (ov + 16777216L);     // 1536x2048 bf16  ( 6,291,456)
  bf16*  wkvab = (bf16*) (ov + 23068672L);     //  640x2048 bf16  ( 2,621,440)
  bf16*  wqbb  = (bf16*) (ov + 25690112L);     // 3072x1536 bf16  ( 9,437,184)
  bf16*  qa    = (bf16*) (ov + 35127296L);     // 4096x1536 bf16  (12,582,912)
  float* kvraw = (float*)(ov + 47710208L);     // 4096x640  fp32  (10,485,760)
  // E total = 58,195,968

  // loop overlay (attention phase): scores only
  bf16* scores_c = (bf16*)ov;                  // hc x 2048x2048 bf16

  cvt_all<<<4096, 256, 0, stream>>>(x, wq_a, wq_b, wkv_b, wo, wkv_a,
                                    xb, wqab, wqbb, wkvbb, wob, wkvab);

  // merged q1+kv: [qa | kvraw] = xb @ [wqab ; wkvab]^T  (N=2176, FLAG 128)
  G<DIM_, DIM_, DIM_, QL_, 128>(stream, xb, 0, wqab, 0,
                                qa, 0, BS_, QL_ + NKVP_, 1, kvraw);
  rmsnorm_qa<<<BS_, 256, 0, stream>>>(qa, qnw);
  kv_post<<<BS_, 256, 0, stream>>>(kvraw, kvnw, cosb, sinb, kfull);

  // q2: qb = qa @ wq_b^T -> rope q_pe in place
  G<QL_, QL_, QL_, H_ * DQK_, 0>(stream, qa, 0, wqbb, 0, qb, 0, BS_, H_ * DQK_, 1);
  rope_q<<<BS_ * H_ / 8, 256, 0, stream>>>(qb, cosb, sinb);

  // merged absorb+Vabs: kfull @ wkvbb^T (N=4096, z=B), FLAG 256 epilogue
  // routes even 128-col blocks -> kvabs nope slices, odd -> VabsT transposed.
  G<KVL_, NKV_, KVL_, DQK_, 256>(stream,
      kfull, (long)S_ * NKV_, wkvbb, 0,
      kvabs, 0, S_, H_ * 256, B_, VabsT);
  // kvabs[b,h,t,128:192] = k_pe (roped, shared across heads)
  kpe_fill<<<8192, 256, 0, stream>>>(kfull, kvabs);

  // attention chunks
  if (hc == 16)
    attn_loop<16>(stream, qb, kvabs, VabsT, ovb, scores_c);
  else if (hc == 8)
    attn_loop<8>(stream, qb, kvabs, VabsT, ovb, scores_c);
  else
    attn_loop<4>(stream, qb, kvabs, VabsT, ovb, scores_c);

  // final projection: out = ovb @ wo^T (fp32 out)
  G<H_ * DV_, H_ * DV_, H_ * DV_, DIM_, 1>(stream, ovb, 0, wob, 0, out, 0, BS_, DIM_, 1);
}

// Round 12
// 513.833 us; speedup vs baseline: 1.4935x; 1.0077x over previous
//
#include <hip/hip_runtime.h>
#include <hip/hip_bf16.h>
#include <stdint.h>

// ---------------- problem constants ----------------
#define B_    2
#define S_    2048
#define DIM_  2048
#define H_    16
#define QL_   1536
#define KVL_  512
#define DN_   128
#define DR_   64
#define DV_   128
#define DQK_  192
#define NKV_  576     // KVL_ + DR_
#define NKVP_ 640     // padded to multiple of 128
#define BS_   (B_*S_)
#define SCALE_ 0.07216878364870322f   // 192^-0.5

typedef __hip_bfloat16 bf16;
typedef float f32x4 __attribute__((ext_vector_type(4)));
typedef short bf16x8 __attribute__((ext_vector_type(8)));   // 8 bf16 (4 VGPRs)

// ---------------- GEMM (C = A @ B^T), r1 structure (measured best) ---------
// 512 threads = 8 waves (2Mx4N), per-wave 64x32 (acc[4][2]), 32 KiB LDS,
// sync-stage-sync 2-barrier K-loop. R3(8-phase)/R4(4w dbuf)/R5(8w dbuf)
// all regressed vs this; do not re-pipeline without ablation evidence.
// Envelope at big shapes: ~700-815 TF (q1kv/final/q2, R10 counters).
#define BMT 128
#define BNT 128
#define BKT 64

__device__ __forceinline__ void gload_lds16(const void* g, void* l) {
#if __has_builtin(__builtin_amdgcn_global_load_lds)
  __builtin_amdgcn_global_load_lds(
      (const __attribute__((address_space(1))) void*)g,
      (__attribute__((address_space(3))) void*)l, 16, 0, 0);
#else
  *(uint4*)l = *(const uint4*)g;
#endif
}

// A: M x K (row-major, LDA), B: N x K (row-major, LDB) -> C: M x N (LDC)
// FLAGS: 1 = fp32 C, 8 = bf16 C scaled by SCALE_, else bf16 C;
//        2 = causal block skip (scores), 4 = causal K-limit (PV),
//        16 = row-pair balancing: grid.y halved; block processes row-tiles
//             ry and (2*gridDim.y-1-ry) sequentially,
//        128 = q1+kv split output: cols [0,QL_) -> bf16 Cv (LDC=QL_),
//              cols [QL_,QL_+NKVP_) -> fp32 Cv2 (LDC=NKVP_),
//        256 = absorb+Vabs split: B = wkvbb rows 0..4095 ([h][nope|v]);
//              even 128-col block -> kvabs[b,h,rr,0:128] (bf16, LDC=DQK_),
//              odd  128-col block -> VabsT[b][h*128+j][rr] transposed
//              (8B short4 quad stores).
template <int K, int LDA, int LDB, int LDC, int FLAGS>
__global__ __launch_bounds__(512, 4) void gemm_t(
    const bf16* __restrict__ A, long saz,
    const bf16* __restrict__ Bm, long sbz,
    void* __restrict__ Cv, long scz,
    void* __restrict__ Cv2)
{
  int z = blockIdx.z;
  A  += (long)z * saz;
  Bm += (long)z * sbz;
  long coff = (long)z * scz;

  // XCD-aware chunked swizzle (every grid here has nwg % 8 == 0)
  int gx = gridDim.x;
  int lin = blockIdx.y * gx + blockIdx.x;
  int nwg = gx * gridDim.y;
  int wg = (lin & 7) * (nwg >> 3) + (lin >> 3);
  int ry = wg / gx, col0 = (wg % gx) * BNT;

  int tid = threadIdx.x, lane = tid & 63, wave = tid >> 6;
  int wm = (wave >> 2) * 64, wn = (wave & 3) * 32;
  int quad = lane >> 4, l16 = lane & 15;

  __shared__ __align__(16) bf16 Asm[BMT * BKT];
  __shared__ __align__(16) bf16 Bsm[BNT * BKT];

  const int npass = (FLAGS & 16) ? 2 : 1;
  const int nty = gridDim.y * ((FLAGS & 16) ? 2 : 1);

  for (int p = 0; p < npass; ++p) {
    int rt = (p == 0) ? ry : (nty - 1 - ry);
    int row0 = rt * BMT;

    if (FLAGS & 2) { if (col0 > row0 + (BMT - 1)) continue; }  // fully masked
    int kend = K;
    if (FLAGS & 4) { int lim = row0 + BMT; if (lim < kend) kend = lim; }

    f32x4 acc[4][2] = {};

    for (int k0 = 0; k0 < kend; k0 += BKT) {
      __syncthreads();
#pragma unroll
      for (int t = 0; t < 2; ++t) {
        int c = (wave * 2 + t) * 64 + lane;      // 16B chunk id 0..1023
        int m = c >> 3, jx = c & 7, j = jx ^ (m & 7);
        gload_lds16(A  + (long)((row0 + m) * LDA + k0 + j * 8), Asm + c * 8);
        gload_lds16(Bm + (long)((col0 + m) * LDB + k0 + j * 8), Bsm + c * 8);
      }
      __syncthreads();
#pragma unroll
      for (int kk = 0; kk < BKT; kk += 32) {
        int jl = (kk >> 3) + quad;
        bf16x8 af[4], bfv[2];
#pragma unroll
        for (int i = 0; i < 4; ++i) {
          int m = wm + i * 16 + l16;
          af[i]  = *(const bf16x8*)(Asm + m * 64 + ((jl ^ (m & 7)) * 8));
        }
#pragma unroll
        for (int jn = 0; jn < 2; ++jn) {
          int n = wn + jn * 16 + l16;
          bfv[jn] = *(const bf16x8*)(Bsm + n * 64 + ((jl ^ (n & 7)) * 8));
        }
#pragma unroll
        for (int i = 0; i < 4; ++i)
#pragma unroll
          for (int jn = 0; jn < 2; ++jn)
            acc[i][jn] = __builtin_amdgcn_mfma_f32_16x16x32_bf16(af[i], bfv[jn], acc[i][jn], 0, 0, 0);
      }
    }
    // pass 2's first __syncthreads protects LDS reuse across passes.

    // epilogue: C/D layout col=lane&15, row=quad*4+reg (m89/m91 verified)
    if (FLAGS & 128) {
      // q1+kv split: block cols are entirely on one side (QL_ % 128 == 0)
      if (col0 < QL_) {
        bf16* C = (bf16*)Cv;
#pragma unroll
        for (int i = 0; i < 4; ++i)
#pragma unroll
          for (int jn = 0; jn < 2; ++jn)
#pragma unroll
            for (int r = 0; r < 4; ++r) {
              int rr = row0 + wm + i * 16 + quad * 4 + r;
              int cc = col0 + wn + jn * 16 + l16;
              C[(long)rr * QL_ + cc] = __float2bfloat16(acc[i][jn][r]);
            }
      } else {
        float* C2 = (float*)Cv2;
#pragma unroll
        for (int i = 0; i < 4; ++i)
#pragma unroll
          for (int jn = 0; jn < 2; ++jn)
#pragma unroll
            for (int r = 0; r < 4; ++r) {
              int rr = row0 + wm + i * 16 + quad * 4 + r;
              int cc = col0 + wn + jn * 16 + l16 - QL_;
              C2[(long)rr * NKVP_ + cc] = acc[i][jn][r];
            }
      }
    } else if (FLAGS & 256) {
      // absorb+Vabs split: cb even -> kvabs nope slice; cb odd -> VabsT^T
      int cb = col0 >> 7, h = cb >> 1;
      if ((cb & 1) == 0) {
        bf16* C = (bf16*)Cv + ((long)z * H_ + h) * (long)S_ * DQK_;
#pragma unroll
        for (int i = 0; i < 4; ++i)
#pragma unroll
          for (int jn = 0; jn < 2; ++jn)
#pragma unroll
            for (int r = 0; r < 4; ++r) {
              int rr = row0 + wm + i * 16 + quad * 4 + r;
              int cc = (wn + jn * 16 + l16) & 127;     // col within nope 128
              C[(long)rr * DQK_ + cc] = __float2bfloat16(acc[i][jn][r]);
            }
      } else {
        bf16* C = (bf16*)Cv2 + (long)z * S_ * S_;
#pragma unroll
        for (int i = 0; i < 4; ++i)
#pragma unroll
          for (int jn = 0; jn < 2; ++jn) {
            int rr = row0 + wm + i * 16 + quad * 4;
            int nv = h * 128 + ((wn + jn * 16 + l16) & 127);
            __align__(8) bf16 t4[4];
#pragma unroll
            for (int r = 0; r < 4; ++r) t4[r] = __float2bfloat16(acc[i][jn][r]);
            *(short4*)(C + (long)nv * S_ + rr) = *(const short4*)t4;
          }
      }
    } else if (FLAGS & 1) {
      float* C = (float*)Cv + coff;
#pragma unroll
      for (int i = 0; i < 4; ++i)
#pragma unroll
        for (int jn = 0; jn < 2; ++jn)
#pragma unroll
          for (int r = 0; r < 4; ++r) {
            int rr = row0 + wm + i * 16 + quad * 4 + r;
            int cc = col0 + wn + jn * 16 + l16;
            C[(long)rr * LDC + cc] = acc[i][jn][r];
          }
    } else if (FLAGS & 8) {
      bf16* C = (bf16*)Cv + coff;
#pragma unroll
      for (int i = 0; i < 4; ++i)
#pragma unroll
        for (int jn = 0; jn < 2; ++jn)
#pragma unroll
          for (int r = 0; r < 4; ++r) {
            int rr = row0 + wm + i * 16 + quad * 4 + r;
            int cc = col0 + wn + jn * 16 + l16;
            C[(long)rr * LDC + cc] = __float2bfloat16(acc[i][jn][r] * SCALE_);
          }
    } else {
      bf16* C = (bf16*)Cv + coff;
#pragma unroll
      for (int i = 0; i < 4; ++i)
#pragma unroll
        for (int jn = 0; jn < 2; ++jn)
#pragma unroll
          for (int r = 0; r < 4; ++r) {
            int rr = row0 + wm + i * 16 + quad * 4 + r;
            int cc = col0 + wn + jn * 16 + l16;
            C[(long)rr * LDC + cc] = __float2bfloat16(acc[i][jn][r]);
          }
    }
  }
}

template <int K, int LDA, int LDB, int LDC, int FLAGS>
static inline void G(hipStream_t st, const bf16* A, long saz, const bf16* Bp, long sbz,
                     void* C, long scz, int M, int N, int Z, void* C2 = nullptr) {
  int gy = M / BMT;
  if (FLAGS & 16) gy >>= 1;           // row-pair balancing: half the y-grid
  dim3 g(N / BNT, gy, Z);
  gemm_t<K, LDA, LDB, LDC, FLAGS><<<g, 512, 0, st>>>(A, saz, Bp, sbz, C, scz, C2);
}

// ---------------- PV-specialized 64x128 GEMM (R12) -------------------------
// ovb[s, h*128+j] = sum_t P_h[s][t] * VabsT[h*128+j][t], causal kend=row0+64.
// Why not gemm_t: PV per-head N=128 -> gx=1 -> 128 paired blocks = 0.5/CU
// (half the GPU idle, ~34 K-tile units serial per active CU, est ~40us/b).
// Here: heads are grid-x via head-strided A (P is [h][S][S]; V rows are
// head-stacked in VabsT), BMT=64 -> 32 row-tiles paired (ry,31-ry) ->
// uniform 33 half-size K-tiles; grid (HC,16) = 256 blocks = 1/CU, all CUs
// busy, per-CU path ~16.5 units. Softmax zero-pad to (r&~127)+128 still
// covers all read cols for both row0 mod 128 cases.
__global__ __launch_bounds__(512, 4) void pv64_t(
    const bf16* __restrict__ P,     // scores_c: [HC][S][S]
    const bf16* __restrict__ Vt,    // VabsT[b] + h0*DV*S: [n][t], n local
    bf16* __restrict__ C)           // ovb[b] + h0*DV, LDC = H_*DV_
{
  int gx = gridDim.x;                  // HC
  int lin = blockIdx.y * gx + blockIdx.x;
  int nwg = gx * gridDim.y;            // HC*16, % 8 == 0 for HC>=4
  int wg = (lin & 7) * (nwg >> 3) + (lin >> 3);
  int ry = wg / gx;                    // 0..15 pair id
  int col0 = (wg % gx) * 128;          // head-col block
  const bf16* A0 = P + (long)(col0 >> 7) * S_ * S_;   // head-strided A

  int tid = threadIdx.x, lane = tid & 63, wave = tid >> 6;
  int wm = (wave >> 2) * 32, wn = (wave & 3) * 32;    // 2M x 4N of 32x32
  int quad = lane >> 4, l16 = lane & 15;

  __shared__ __align__(16) bf16 Asm[64 * 64];    // 8 KiB
  __shared__ __align__(16) bf16 Bsm[128 * 64];   // 16 KiB

  for (int p = 0; p < 2; ++p) {
    int rt = (p == 0) ? ry : (31 - ry);          // pair sums to 33 K-tiles
    int row0 = rt * 64;
    int kend = row0 + 64;                        // causal K-limit (64-gran)

    f32x4 acc[2][2] = {};

    for (int k0 = 0; k0 < kend; k0 += 64) {
      __syncthreads();
      // 1536 16B chunks: 0..511 -> A (64x64), 512..1535 -> B (128x64);
      // same row-XOR chunk swizzle as gemm_t.
#pragma unroll
      for (int t = 0; t < 3; ++t) {
        int c = tid + t * 512;
        if (c < 512) {
          int m = c >> 3, j = (c & 7) ^ (m & 7);
          gload_lds16(A0 + (long)(row0 + m) * S_ + k0 + j * 8, Asm + c * 8);
        } else {
          int cb = c - 512;
          int m = cb >> 3, j = (cb & 7) ^ (m & 7);
          gload_lds16(Vt + (long)(col0 + m) * S_ + k0 + j * 8, Bsm + cb * 8);
        }
      }
      __syncthreads();
#pragma unroll
      for (int kk = 0; kk < 64; kk += 32) {
        int jl = (kk >> 3) + quad;
        bf16x8 af[2], bfv[2];
#pragma unroll
        for (int i = 0; i < 2; ++i) {
          int m = wm + i * 16 + l16;
          af[i] = *(const bf16x8*)(Asm + m * 64 + ((jl ^ (m & 7)) * 8));
        }
#pragma unroll
        for (int jn = 0; jn < 2; ++jn) {
          int n = wn + jn * 16 + l16;
          bfv[jn] = *(const bf16x8*)(Bsm + n * 64 + ((jl ^ (n & 7)) * 8));
        }
#pragma unroll
        for (int i = 0; i < 2; ++i)
#pragma unroll
          for (int jn = 0; jn < 2; ++jn)
            acc[i][jn] = __builtin_amdgcn_mfma_f32_16x16x32_bf16(af[i], bfv[jn], acc[i][jn], 0, 0, 0);
      }
    }
    // pass 2's first __syncthreads protects LDS reuse across passes.

#pragma unroll
    for (int i = 0; i < 2; ++i)
#pragma unroll
      for (int jn = 0; jn < 2; ++jn)
#pragma unroll
        for (int r = 0; r < 4; ++r) {
          int rr = row0 + wm + i * 16 + quad * 4 + r;
          int cc = col0 + wn + jn * 16 + l16;
          C[(long)rr * (H_ * DV_) + cc] = __float2bfloat16(acc[i][jn][r]);
        }
  }
}

// ---------------- helpers ----------------
__device__ __forceinline__ float wsum(float v) {
#pragma unroll
  for (int o = 32; o > 0; o >>= 1) v += __shfl_down(v, o, 64);
  return v;
}

// fused fp32->bf16 conversion pass, vectorized.
// Destination layout note: wkvab must sit CONTIGUOUSLY after wqab (the
// q1+kv merged GEMM uses rows 0..1535=wq_a, 1536..2175=wkv_a-padded).
#define CVT_N0  8388608L    // x -> xb            (4096*2048)
#define CVT_N1 11534336L    // wq_a -> wqab       (+1536*2048)
#define CVT_N2 16252928L    // wq_b -> wqbb       (+3072*1536)
#define CVT_N3 18350080L    // wkv_b -> wkvbb     (+4096*512)
#define CVT_N4 22544384L    // wo -> wob          (+2048*2048)
#define CVT_N5 23855104L    // wkv_a pad -> wkvab (+640*2048, valid 1179648)
__device__ __forceinline__ void cvt8(const float* __restrict__ s, bf16* __restrict__ d) {
  float4 a = ((const float4*)s)[0], b = ((const float4*)s)[1];
  __align__(16) bf16 t[8];
  t[0] = __float2bfloat16(a.x); t[1] = __float2bfloat16(a.y);
  t[2] = __float2bfloat16(a.z); t[3] = __float2bfloat16(a.w);
  t[4] = __float2bfloat16(b.x); t[5] = __float2bfloat16(b.y);
  t[6] = __float2bfloat16(b.z); t[7] = __float2bfloat16(b.w);
  *(uint4*)d = *(const uint4*)t;
}
__global__ __launch_bounds__(256) void cvt_all(
    const float* __restrict__ x, const float* __restrict__ wq_a,
    const float* __restrict__ wq_b, const float* __restrict__ wkv_b,
    const float* __restrict__ wo, const float* __restrict__ wkv_a,
    bf16* __restrict__ xb, bf16* __restrict__ wqab, bf16* __restrict__ wqbb,
    bf16* __restrict__ wkvbb, bf16* __restrict__ wob, bf16* __restrict__ wkvab)
{
  const long ngrp = CVT_N5 / 8;
  for (long v = (long)blockIdx.x * 256 + threadIdx.x; v < ngrp; v += (long)gridDim.x * 256) {
    long i = v * 8;
    if (i < CVT_N0) {
      cvt8(x + i, xb + i);
    } else if (i < CVT_N1) {
      long j = i - CVT_N0; cvt8(wq_a + j, wqab + j);
    } else if (i < CVT_N2) {
      long j = i - CVT_N1; cvt8(wq_b + j, wqbb + j);
    } else if (i < CVT_N3) {
      long j = i - CVT_N2; cvt8(wkv_b + j, wkvbb + j);
    } else if (i < CVT_N4) {
      long j = i - CVT_N3; cvt8(wo + j, wob + j);
    } else {
      long j = i - CVT_N4;
      if (j < (long)NKV_ * DIM_) cvt8(wkv_a + j, wkvab + j);
      else { __align__(16) bf16 t[8] = {}; *(uint4*)(wkvab + j) = *(const uint4*)t; }
    }
  }
}

// in-place RMSNorm of qa rows (1536), bf16
__global__ __launch_bounds__(256) void rmsnorm_qa(bf16* __restrict__ qa, const float* __restrict__ w) {
  long row = blockIdx.x;
  bf16* pr = qa + row * QL_;
  int tid = threadIdx.x, lane = tid & 63, wave = tid >> 6;
  float v[6]; float ss = 0.f;
#pragma unroll
  for (int k = 0; k < 6; ++k) { int c = tid + k * 256; v[k] = __bfloat162float(pr[c]); ss += v[k] * v[k]; }
  ss = wsum(ss);
  __shared__ float sred[4];
  if (lane == 0) sred[wave] = ss;
  __syncthreads();
  float tot = sred[0] + sred[1] + sred[2] + sred[3];
  float scl = rsqrtf(tot / (float)QL_ + 1e-6f);
#pragma unroll
  for (int k = 0; k < 6; ++k) { int c = tid + k * 256; pr[c] = __float2bfloat16(v[k] * scl * w[c]); }
}

// kv row postproc: RMSNorm(kv_c)*w -> k_full[0:512], rope(k_pe) -> k_full[512:576]
__global__ __launch_bounds__(256) void kv_post(const float* __restrict__ kvraw, const float* __restrict__ kvw,
                                               const float* __restrict__ cosb, const float* __restrict__ sinb,
                                               bf16* __restrict__ kfull) {
  int bs = blockIdx.x;
  int s = bs & (S_ - 1);
  const float* rowp = kvraw + (long)bs * NKVP_;
  bf16* outp = kfull + (long)bs * NKV_;
  int tid = threadIdx.x, lane = tid & 63, wave = tid >> 6;
  float v0 = rowp[tid], v1 = rowp[tid + 256];
  float ss = v0 * v0 + v1 * v1;
  ss = wsum(ss);
  __shared__ float sred[4];
  if (lane == 0) sred[wave] = ss;
  __syncthreads();
  float tot = sred[0] + sred[1] + sred[2] + sred[3];
  float scl = rsqrtf(tot / (float)KVL_ + 1e-6f);
  outp[tid]       = __float2bfloat16(v0 * scl * kvw[tid]);
  outp[tid + 256] = __float2bfloat16(v1 * scl * kvw[tid + 256]);
  if (tid < 32) {
    float x0 = rowp[KVL_ + 2 * tid], x1 = rowp[KVL_ + 2 * tid + 1];
    float c = cosb[s * 32 + tid], sn = sinb[s * 32 + tid];
    outp[KVL_ + 2 * tid]     = __float2bfloat16(x0 * c - x1 * sn);
    outp[KVL_ + 2 * tid + 1] = __float2bfloat16(x0 * sn + x1 * c);
  }
}

// rope(q_pe) applied in place on qb[bs][h*192+128 .. +191], all heads/rows.
__global__ __launch_bounds__(256) void rope_q(bf16* __restrict__ qb,
                                              const float* __restrict__ cosb,
                                              const float* __restrict__ sinb) {
  int tx = threadIdx.x & 31, ty = threadIdx.x >> 5;
  long row = (long)blockIdx.x * 8 + ty;     // 0..BS_*H_-1
  long bs = row >> 4; int h = (int)(row & 15); int s = (int)(bs & (S_ - 1));
  bf16* p = qb + bs * (H_ * DQK_) + h * DQK_ + DN_;
  float x0 = __bfloat162float(p[2 * tx]), x1 = __bfloat162float(p[2 * tx + 1]);
  float c = cosb[s * 32 + tx], sn = sinb[s * 32 + tx];
  p[2 * tx]     = __float2bfloat16(x0 * c - x1 * sn);
  p[2 * tx + 1] = __float2bfloat16(x0 * sn + x1 * c);
}

// kvabs[b,h,t,128:192] = kfull[b,t,512:576] (k_pe, already roped)
__global__ __launch_bounds__(256) void kpe_fill(const bf16* __restrict__ kfull, bf16* __restrict__ kvabs) {
  const long n = (long)B_ * H_ * S_ * 64;
  for (long i = (long)blockIdx.x * 256 + threadIdx.x; i < n; i += (long)gridDim.x * 256) {
    int d = (int)(i & 63);
    long t = (i >> 6) & (S_ - 1);
    int h = (int)((i >> 17) & 15);
    int b = (int)(i >> 21);
    kvabs[(((long)(b * H_ + h) * S_) + t) * DQK_ + DN_ + d] =
        kfull[((long)b * S_ + t) * NKV_ + KVL_ + d];
  }
}

// causal softmax, wave-per-row (balanced mapping r = w*512 + x; R11-neutral
// but harmless). bf16x8 16B loads/stores; no LDS/barriers; butterfly
// reduces; per-element masking only in the partial 512-chunk. Zero-pads to
// wlen=(r&~127)+128 >= any pv64 read column (kend=row0+64 <= wlen).
__global__ __launch_bounds__(256) void softmax_causal(bf16* __restrict__ sc) {
  int wave = threadIdx.x >> 6, lane = threadIdx.x & 63;
  int r = wave * 512 + blockIdx.x, z = blockIdx.y;
  bf16* row = sc + ((long)z * S_ + r) * S_;
  int wlen = (r & ~127) + 128;
  int base0 = lane * 8;

  float v[4][8];
  float mx = -3.0e38f;
#pragma unroll
  for (int c = 0; c < 4; ++c) {
    int cb = c * 512;
    if (cb <= r) {                               // wave-uniform chunk skip
      int base = cb + base0;
      __align__(16) bf16 t8[8];
      *(bf16x8*)t8 = *(const bf16x8*)(row + base);
      if (cb + 511 <= r) {                       // full chunk: no masks
#pragma unroll
        for (int j = 0; j < 8; ++j) {
          float f = __bfloat162float(t8[j]);
          v[c][j] = f; mx = fmaxf(mx, f);
        }
      } else {                                   // partial chunk (has diag)
#pragma unroll
        for (int j = 0; j < 8; ++j) {
          float f = (base + j <= r) ? __bfloat162float(t8[j]) : -3.0e38f;
          v[c][j] = f; mx = fmaxf(mx, f);
        }
      }
    }
  }
#pragma unroll
  for (int o = 32; o > 0; o >>= 1) mx = fmaxf(mx, __shfl_xor(mx, o, 64));

  float s = 0.f;
#pragma unroll
  for (int c = 0; c < 4; ++c) {
    if (c * 512 <= r) {
#pragma unroll
      for (int j = 0; j < 8; ++j) {
        float e = __expf(v[c][j] - mx);          // masked -3e38 -> 0
        v[c][j] = e; s += e;
      }
    }
  }
#pragma unroll
  for (int o = 32; o > 0; o >>= 1) s += __shfl_xor(s, o, 64);
  float inv = 1.f / s;

#pragma unroll
  for (int c = 0; c < 4; ++c) {
    int base = c * 512 + base0;
    if (c * 512 <= r && base < wlen) {           // covers [0, wlen) exactly
      __align__(16) bf16 t8[8];
#pragma unroll
      for (int j = 0; j < 8; ++j) t8[j] = __float2bfloat16(v[c][j] * inv);
      *(bf16x8*)(row + base) = *(const bf16x8*)t8;
    }
  }
}

// ---------------- attention loop (HC = heads per chunk, compile-time) -------
// scores = [q_nope | roped q_pe] @ [kv_abs | k_pe]^T  (K = 192, k-side absorbed)
// PV' via pv64_t: all HC heads in grid-x, 256 blocks uniform.
template <int HC>
static void attn_loop(hipStream_t stream, const bf16* qb, const bf16* kvabs,
                      const bf16* VabsT,
                      bf16* ovb, bf16* scores_c) {
  const int nch = B_ * (H_ / HC);
  for (int ch = 0; ch < nch; ++ch) {
    int b = ch / (H_ / HC), hq = ch % (H_ / HC), h0 = hq * HC;

    // scores (bf16 out scaled by SCALE_, causal block skip), all HC heads in z
    G<DQK_, H_ * DQK_, DQK_, S_, 8 | 2>(stream,
        qb + (long)b * S_ * (H_ * DQK_) + (long)h0 * DQK_, DQK_,
        kvabs + (long)(b * H_ + h0) * S_ * DQK_, (long)S_ * DQK_,
        scores_c, (long)S_ * S_, S_, S_, HC);
    // softmax (in-place bf16, wave-per-row)
    softmax_causal<<<dim3(S_ / 4, HC), 256, 0, stream>>>(scores_c);
    // PV' (64-row tiles, heads in grid-x, paired rows -> uniform 33 K-tiles)
    pv64_t<<<dim3(HC, 16, 1), 512, 0, stream>>>(
        scores_c,
        VabsT + (long)b * S_ * S_ + (long)h0 * DV_ * S_,
        ovb + (long)b * S_ * (H_ * DV_) + (long)h0 * DV_);
  }
}

// ---------------- host ----------------
extern "C" void kernel_launch(void* const* d_in, const int* in_sizes, int n_in,
                              void* d_out, int out_size, void* d_ws, size_t ws_size,
                              hipStream_t stream) {
  const float* x     = (const float*)d_in[0];
  const float* wq_a  = (const float*)d_in[1];
  const float* qnw   = (const float*)d_in[2];
  const float* wq_b  = (const float*)d_in[3];
  const float* wkv_a = (const float*)d_in[4];
  const float* kvnw  = (const float*)d_in[5];
  const float* wkv_b = (const float*)d_in[6];
  const float* wo    = (const float*)d_in[7];
  const float* cosb  = (const float*)d_in[8];
  const float* sinb  = (const float*)d_in[9];
  float* out = (float*)d_out;
  (void)in_sizes; (void)n_in; (void)out_size;

  // P = 101,187,584; E overlay = 58,195,968; scores overlay = hc*8,388,608.
  // hc=16: 235,405,312; hc=8: 168,296,448; hc=4: 159,383,552.
  int hc;
  if      (ws_size >= 235405312UL) hc = 16;
  else if (ws_size >= 168296448UL) hc = 8;
  else                             hc = 4;

  char* base = (char*)d_ws;
  long off = 0;
  auto at = [&](long bytes) { char* r = base + off; off += bytes; return r; };

  // P region (persistent across the whole call) -- 101,187,584 B
  bf16* qb    = (bf16*)at(25165824L);   // 4096x3072 bf16
  bf16* ovb   = (bf16*)at(16777216L);   // 4096x2048 bf16
  bf16* kfull = (bf16*)at(4718592L);    // 4096x576  bf16
  bf16* wkvbb = (bf16*)at(4194304L);    // 4096x512  bf16
  bf16* wob   = (bf16*)at(8388608L);    // 2048x2048 bf16
  bf16* kvabs = (bf16*)at(25165824L);   // 2x16x2048x192 bf16 [kv_abs | k_pe]
  bf16* VabsT = (bf16*)at(16777216L);   // 2 x [2048 n][2048 t] bf16
  char* ov = base + off;                // overlay region

  // E overlay (early phase; all dead before the attention loop)
  // wqab & wkvab are CONTIGUOUS: merged q1+kv GEMM B rows 0..2175.
  bf16*  xb    = (bf16*) (ov);                 // 4096x2048 bf16  (16,777,216)
  bf16*  wqab  = (bf16*) (ov + 16777216L);     // 1536x2048 bf16  ( 6,291,456)
  bf16*  wkvab = (bf16*) (ov + 23068672L);     //  640x2048 bf16  ( 2,621,440)
  bf16*  wqbb  = (bf16*) (ov + 25690112L);     // 3072x1536 bf16  ( 9,437,184)
  bf16*  qa    = (bf16*) (ov + 35127296L);     // 4096x1536 bf16  (12,582,912)
  float* kvraw = (float*)(ov + 47710208L);     // 4096x640  fp32  (10,485,760)
  // E total = 58,195,968

  // loop overlay (attention phase): scores only
  bf16* scores_c = (bf16*)ov;                  // hc x 2048x2048 bf16

  cvt_all<<<4096, 256, 0, stream>>>(x, wq_a, wq_b, wkv_b, wo, wkv_a,
                                    xb, wqab, wqbb, wkvbb, wob, wkvab);

  // merged q1+kv: [qa | kvraw] = xb @ [wqab ; wkvab]^T  (N=2176, FLAG 128)
  G<DIM_, DIM_, DIM_, QL_, 128>(stream, xb, 0, wqab, 0,
                                qa, 0, BS_, QL_ + NKVP_, 1, kvraw);
  rmsnorm_qa<<<BS_, 256, 0, stream>>>(qa, qnw);
  kv_post<<<BS_, 256, 0, stream>>>(kvraw, kvnw, cosb, sinb, kfull);

  // q2: qb = qa @ wq_b^T -> rope q_pe in place
  G<QL_, QL_, QL_, H_ * DQK_, 0>(stream, qa, 0, wqbb, 0, qb, 0, BS_, H_ * DQK_, 1);
  rope_q<<<BS_ * H_ / 8, 256, 0, stream>>>(qb, cosb, sinb);

  // merged absorb+Vabs: kfull @ wkvbb^T (N=4096, z=B), FLAG 256 epilogue
  // routes even 128-col blocks -> kvabs nope slices, odd -> VabsT transposed.
  G<KVL_, NKV_, KVL_, DQK_, 256>(stream,
      kfull, (long)S_ * NKV_, wkvbb, 0,
      kvabs, 0, S_, H_ * 256, B_, VabsT);
  // kvabs[b,h,t,128:192] = k_pe (roped, shared across heads)
  kpe_fill<<<8192, 256, 0, stream>>>(kfull, kvabs);

  // attention chunks
  if (hc == 16)
    attn_loop<16>(stream, qb, kvabs, VabsT, ovb, scores_c);
  else if (hc == 8)
    attn_loop<8>(stream, qb, kvabs, VabsT, ovb, scores_c);
  else
    attn_loop<4>(stream, qb, kvabs, VabsT, ovb, scores_c);

  // final projection: out = ovb @ wo^T (fp32 out)
  G<H_ * DV_, H_ * DV_, H_ * DV_, DIM_, 1>(stream, ovb, 0, wob, 0, out, 0, BS_, DIM_, 1);
}